// Round 3
// baseline (399.711 us; speedup 1.0000x reference)
//
#include <hip/hip_runtime.h>
#include <math.h>

#define NT 2
#define BSZ 4
#define NAT 512
#define NATOMS 2048
#define NNEI 200
#define EMB 100
#define FITH 240
#define DDIM 1600
#define TBK 1024

// ---- ws layout ----
// float region: [0..8) table ranges; [16..1552) concat biases; [1552..2064) w3c;
// int   region: [2064..4112) perm, [4112..4114) counts
#define BIAS_F  16
#define W3C_F   (BIAS_F + 3 * 512)
#define PERM_I  2064
#define CNT_I   (PERM_I + 2048)
#define USH_BYTE 16512
#define TBL_U   0                          // 4*1024*100 = 409600
#define W0T_U   409600                     // [512][1600] = 819200
#define W1T_U   (W0T_U + 819200)           // [512][512]  = 262144
#define W2T_U   (W1T_U + 262144)           // 262144
#define D_U     (W2T_U + 262144)           // [2048][1600] = 3276800
#define H0_U    (D_U + 3276800)            // kept for ws sizing
#define H1_U    (H0_U + 1048576)
#define USH_END (H1_U + 1048576)
#define WS_NEED ((size_t)USH_BYTE + (size_t)USH_END * 2)   // ~12.2 MB

#define N_W0 819200
#define N_W1 262144
#define N_W2 262144
#define N_B  1536
#define N_W3 512
#define N_EI 2048
#define N_WT (N_W0 + N_W1 + N_W2 + N_B + N_W3 + N_EI)      // 1347584
#define WT_BLK ((N_WT + 255) / 256)                        // 5264
#define TB_BLK 512

// H rows padded to 264 ushorts (528 B) -> consecutive rows land on rotated
// 16B slots, spreading ds_read_b128 A-fragment reads across banks.
#define HPAD 264
// fit layer-0 register-prefetch depth (5 loads/stage, 16B each)
#define PF 6
// embed table-gather prefetch depth (4 ushort loads/stage)
#define PFE 6

typedef short s8v __attribute__((ext_vector_type(8)));
typedef float f4v __attribute__((ext_vector_type(4)));

__device__ __forceinline__ float ftanh(float x) {
    float ax = fabsf(x);
    float e = __expf(2.0f * ax);
    float t = 1.0f - __fdividef(2.0f, e + 1.0f);
    return (x < 0.0f) ? -t : t;
}
__device__ __forceinline__ unsigned short f2bf(float f) {
    unsigned u = __float_as_uint(f);
    u += 0x7FFFu + ((u >> 16) & 1u);
    return (unsigned short)(u >> 16);
}
__device__ __forceinline__ float bf2f(unsigned short s) {
    return __uint_as_float(((unsigned)s) << 16);
}
__device__ __forceinline__ float calc_S(float R) {
    float Rsafe = (R > 1e-5f) ? R : 1.0f;
    float u = (R - 0.5f) * (1.0f / 5.5f);
    float uu = u * u;
    float mid = (u * uu * (-6.0f * uu + 15.0f * u - 10.0f) + 1.0f) / Rsafe;
    float S = 0.0f;
    if (R > 0.0f && R < 0.5f)      S = 1.0f / Rsafe;
    else if (R > 0.5f && R < 6.0f) S = mid;
    return S;
}

// ---------- K1: prep = wtrans + table build + type-perm ----------
__global__ void __launch_bounds__(256) prep_kernel(
    const float* __restrict__ fW0, const float* __restrict__ fW1,
    const float* __restrict__ fW2,
    const float* __restrict__ fb0, const float* __restrict__ fb1,
    const float* __restrict__ fb2,
    const float* __restrict__ fW3, const float* __restrict__ fb3,
    const float* __restrict__ eshift,
    const float* __restrict__ davg, const float* __restrict__ dstd,
    const float* __restrict__ eW0, const float* __restrict__ eb0,
    const float* __restrict__ eW1, const float* __restrict__ eb1,
    const float* __restrict__ eW2, const float* __restrict__ eb2,
    const int* __restrict__ itype,
    float* __restrict__ ws, float* __restrict__ out)
{
    __shared__ float los[100], his[100];
    __shared__ float rng[2];
    __shared__ float h0s[8][25];
    __shared__ float h1s[8][50];
    __shared__ int pcnt, poff0, poff1;
    const int tid = threadIdx.x;
    int bxg = blockIdx.x;
    unsigned short* u0 = (unsigned short*)((char*)ws + USH_BYTE);

    if (bxg < WT_BLK) {
        // ---- weight transform ----
        int id = bxg * 256 + tid;
        if (id < N_W0) {
            int n = id / 1600, k = id - n * 1600;
            float v = 0.0f;
            if (n < 240)                  v = fW0[(size_t)k * 240 + n];
            else if (n >= 256 && n < 496) v = fW0[(size_t)(1600 + k) * 240 + (n - 256)];
            u0[W0T_U + id] = f2bf(v);
            return;
        }
        id -= N_W0;
        if (id < N_W1) {
            int n = id / 512, k = id - n * 512;
            float v = 0.0f;
            if (n < 240 && k < 240)       v = fW1[(size_t)k * 240 + n];
            else if (n >= 256 && n < 496 && k >= 256 && k < 496)
                                          v = fW1[(size_t)(240 + (k - 256)) * 240 + (n - 256)];
            u0[W1T_U + id] = f2bf(v);
            return;
        }
        id -= N_W1;
        if (id < N_W2) {
            int n = id / 512, k = id - n * 512;
            float v = 0.0f;
            if (n < 240 && k < 240)       v = fW2[(size_t)k * 240 + n];
            else if (n >= 256 && n < 496 && k >= 256 && k < 496)
                                          v = fW2[(size_t)(240 + (k - 256)) * 240 + (n - 256)];
            u0[W2T_U + id] = f2bf(v);
            return;
        }
        id -= N_W2;
        if (id < N_B) {
            int l = id / 512, n = id - l * 512;
            const float* fb = (l == 0) ? fb0 : (l == 1) ? fb1 : fb2;
            float v = 0.0f;
            if (n < 240)                  v = fb[n];
            else if (n >= 256 && n < 496) v = fb[240 + (n - 256)];
            ws[BIAS_F + l * 512 + n] = v;
            return;
        }
        id -= N_B;
        if (id < N_W3) {
            int n = id;
            float v = 0.0f;
            if (n < 240)                  v = fW3[n];
            else if (n >= 256 && n < 496) v = fW3[240 + (n - 256)];
            ws[W3C_F + n] = v;
            return;
        }
        id -= N_W3;
        if (id < N_EI) {
            int t = itype[id & (NAT - 1)];
            out[4 + id] = fb3[t] + eshift[t];
        }
        return;
    }
    bxg -= WT_BLK;
    if (bxg < TB_BLK) {
        // ---- embedding table build ----
        const int nid = bxg >> 7;
        const int kb  = (bxg & 127) * 8;
        const int t = nid >> 1, j = nid & 1;
        if (tid < 100) {
            int m = j * 100 + tid;
            float av = davg[(t * NNEI + m) * 4];
            float sd = dstd[(t * NNEI + m) * 4];
            float inv = __fdividef(1.0f, sd);
            float a = (0.0f - av) * inv;         // S in [0,2] for this data
            float b = (2.0f - av) * inv;
            los[tid] = fminf(a, b);
            his[tid] = fmaxf(a, b);
        }
        __syncthreads();
        if (tid == 0) {
            float lo = los[0], hi = his[0];
            for (int i = 1; i < 100; ++i) { lo = fminf(lo, los[i]); hi = fmaxf(hi, his[i]); }
            rng[0] = lo; rng[1] = hi - lo;
            if (kb == 0) {
                ws[nid * 2] = lo;
                ws[nid * 2 + 1] = (float)(TBK - 1) / (hi - lo);
            }
        }
        __syncthreads();
        const float smin = rng[0], span = rng[1];
        const float* W0 = eW0 + nid * 25;
        const float* B0 = eb0 + nid * 25;
        if (tid < 200) {
            int q = tid / 25, a = tid % 25;
            float s = smin + span * ((float)(kb + q) * (1.0f / (TBK - 1)));
            h0s[q][a] = ftanh(fmaf(s, W0[a], B0[a]));
        }
        __syncthreads();
        const float* W1 = eW1 + nid * 1250;
        const float* B1 = eb1 + nid * 50;
        for (int idx = tid; idx < 400; idx += 256) {
            int q = idx / 50, cc = idx % 50;
            float acc = B1[cc];
#pragma unroll
            for (int a = 0; a < 25; ++a) acc = fmaf(h0s[q][a], W1[a * 50 + cc], acc);
            h1s[q][cc] = ftanh(acc) + h0s[q][(cc < 25) ? cc : cc - 25];
        }
        __syncthreads();
        const float* W2 = eW2 + nid * 5000;
        const float* B2 = eb2 + nid * 100;
        unsigned short* tblu = u0 + TBL_U;
        for (int idx = tid; idx < 800; idx += 256) {
            int q = idx / 100, c = idx % 100;
            float acc = B2[c];
#pragma unroll
            for (int a = 0; a < 50; ++a) acc = fmaf(h1s[q][a], W2[a * 100 + c], acc);
            float g = ftanh(acc) + h1s[q][(c < 50) ? c : c - 50];
            tblu[(size_t)(nid * TBK + kb + q) * 100 + c] = f2bf(g);
        }
        return;
    }
    // ---- type partition perm ----
    if (tid == 0) { pcnt = 0; poff0 = 0; poff1 = 0; }
    __syncthreads();
    int* wsi = (int*)ws;
    int local0 = 0;
    for (int i = tid; i < NATOMS; i += 256) local0 += (itype[i & (NAT - 1)] == 0);
    atomicAdd(&pcnt, local0);
    __syncthreads();
    const int c0 = pcnt;
    for (int i = tid; i < NATOMS; i += 256) {
        int t = itype[i & (NAT - 1)];
        int pos = (t == 0) ? atomicAdd(&poff0, 1) : (c0 + atomicAdd(&poff1, 1));
        wsi[PERM_I + pos] = i;
    }
    if (tid == 0) { wsi[CNT_I] = c0; wsi[CNT_I + 1] = NATOMS - c0; }
}

// ---------- K2: embed (table interp) -> D bf16 [2048][1600] ----------
// Depth-PFE register prefetch on the table gather chain (it was a serial
// 100 x L2-round-trip chain; loads for mi+PFE issue before FMAs of mi).
__global__ void __launch_bounds__(128) embed_kernel(
    const int* __restrict__ itype, const float* __restrict__ imagedr,
    const float* __restrict__ davg, const float* __restrict__ dstd,
    float* __restrict__ ws)
{
    __shared__ __align__(16) float4 srn[NNEI];
    __shared__ float sx[NNEI];
    __shared__ float part[2][400];
    const int atom = blockIdx.x;
    const int n = atom & (NAT - 1);
    const int tid = threadIdx.x;
    const int t = itype[n];
    unsigned short* u0 = (unsigned short*)((char*)ws + USH_BYTE);

    const float sm0 = ws[(t * 2 + 0) * 2], sc0 = ws[(t * 2 + 0) * 2 + 1];
    const float sm1 = ws[(t * 2 + 1) * 2], sc1 = ws[(t * 2 + 1) * 2 + 1];

    for (int m = tid; m < NNEI; m += 128) {
        float4 dr = ((const float4*)imagedr)[(size_t)atom * NNEI + m];
        float R = dr.x;
        float S = calc_S(R);
        float Rsafe = (R > 1e-5f) ? R : 1.0f;
        float sr = (fabsf(R) > 1e-5f) ? (S / Rsafe) : 0.0f;
        float4 av = ((const float4*)davg)[t * NNEI + m];
        float4 sd = ((const float4*)dstd)[t * NNEI + m];
        float4 rv;
        rv.x = (S         - av.x) / sd.x;
        rv.y = (sr * dr.y - av.y) / sd.y;
        rv.z = (sr * dr.z - av.z) / sd.z;
        rv.w = (sr * dr.w - av.w) / sd.w;
        srn[m] = rv;
        float smin = (m >= 100) ? sm1 : sm0;
        float scal = (m >= 100) ? sc1 : sc0;
        sx[m] = fminf(fmaxf((rv.x - smin) * scal, 0.0f), (float)(TBK - 2) + 0.9999f);
    }
    __syncthreads();

    const int w = tid >> 6, lane = tid & 63;
    const unsigned short* T = u0 + TBL_U + (size_t)(t * 2 + w) * TBK * EMB;
    const bool hi = (lane < 36);
    float xA0 = 0, xA1 = 0, xA2 = 0, xA3 = 0;
    float xB0 = 0, xB1 = 0, xB2 = 0, xB3 = 0;

    float ff[PFE];
    unsigned short cb[PFE][4];
#pragma unroll
    for (int p = 0; p < PFE; ++p) {
        float x = sx[w * 100 + p];
        int i = (int)x;
        ff[p] = x - (float)i;
        const unsigned short* Tr = T + (size_t)i * EMB;
        cb[p][0] = Tr[lane];
        cb[p][1] = Tr[EMB + lane];
        cb[p][2] = Tr[64 + lane];          // unconditional: harmless in-ws read
        cb[p][3] = Tr[EMB + 64 + lane];
    }
#pragma unroll
    for (int mi = 0; mi < 100; ++mi) {
        const int s = mi % PFE;
        float4 rv = srn[w * 100 + mi];
        float f  = ff[s];
        float g0 = bf2f(cb[s][0]), g1 = bf2f(cb[s][1]);
        float h0v = bf2f(cb[s][2]), h1v = bf2f(cb[s][3]);
        if (mi + PFE < 100) {
            float x = sx[w * 100 + mi + PFE];
            int i = (int)x;
            ff[s] = x - (float)i;
            const unsigned short* Tr = T + (size_t)i * EMB;
            cb[s][0] = Tr[lane];
            cb[s][1] = Tr[EMB + lane];
            cb[s][2] = Tr[64 + lane];
            cb[s][3] = Tr[EMB + 64 + lane];
        }
        float g = fmaf(f, g1 - g0, g0);
        xA0 = fmaf(rv.x, g, xA0); xA1 = fmaf(rv.y, g, xA1);
        xA2 = fmaf(rv.z, g, xA2); xA3 = fmaf(rv.w, g, xA3);
        if (hi) {
            float g2 = fmaf(f, h1v - h0v, h0v);
            xB0 = fmaf(rv.x, g2, xB0); xB1 = fmaf(rv.y, g2, xB1);
            xB2 = fmaf(rv.z, g2, xB2); xB3 = fmaf(rv.w, g2, xB3);
        }
    }
    part[w][0 * 100 + lane] = xA0; part[w][1 * 100 + lane] = xA1;
    part[w][2 * 100 + lane] = xA2; part[w][3 * 100 + lane] = xA3;
    if (hi) {
        part[w][0 * 100 + 64 + lane] = xB0; part[w][1 * 100 + 64 + lane] = xB1;
        part[w][2 * 100 + 64 + lane] = xB2; part[w][3 * 100 + 64 + lane] = xB3;
    }
    __syncthreads();
    const float inv = 1.0f / 200.0f;
    for (int idx = tid; idx < 400; idx += 128)
        part[0][idx] = (part[0][idx] + part[1][idx]) * inv;   // xyz[4][100]
    __syncthreads();
    unsigned short* Drow = u0 + D_U + (size_t)atom * DDIM;
    const float* xt = part[0];
    for (int idx = tid; idx < DDIM; idx += 128) {
        int c = idx >> 4, d = idx & 15;
        float s = xt[c] * xt[d] + xt[100 + c] * xt[100 + d]
                + xt[200 + c] * xt[200 + d] + xt[300 + c] * xt[300 + d];
        Drow[idx] = f2bf(s);
    }
}

// ---------- K3: fused fitting net ----------
// 8 rows/block (MFMA rows duplicated via mr&7 -> 256+ useful blocks, every CU
// busy), depth-PF register pipeline on layer-0 loads, next-layer B panels
// prefetched before the previous layer's epilogue barriers.
__global__ void __launch_bounds__(512) fit_kernel(
    const unsigned short* __restrict__ A,     // D [2048][1600]
    const unsigned short* __restrict__ W0T,   // [512][1600]
    const unsigned short* __restrict__ W1T,   // [512][512]
    const unsigned short* __restrict__ W2T,   // [512][512]
    const float* __restrict__ biases,         // [3][512]
    const float* __restrict__ w3c,            // [512]
    const int* __restrict__ wsi,
    float* __restrict__ out)
{
    __shared__ float lred[4][64][17];             // k-split reduce (17: bank pad)
    __shared__ unsigned short Hs0[8 * HPAD];      // H0 bf16, padded rows
    __shared__ unsigned short Hs1[8 * HPAD];      // H1 bf16
    __shared__ float red2[8][4];                  // per-row partial dots per col-tile

    const int z = blockIdx.y;
    const int cnt = wsi[CNT_I + z];
    const int my = blockIdx.x;
    if (my * 8 >= cnt) return;
    const int base = z ? wsi[CNT_I] : 0;
    const int tid = threadIdx.x;
    const int w = tid >> 6, lane = tid & 63;
    const int mr = lane & 15, q = lane >> 4;
    const int wc = w & 3, h = w >> 2;             // col-tile, k-half
    const int n0 = z * 256 + wc * 64;
    const int m0 = my * 8;
    const int arow = wsi[PERM_I + base + min(m0 + (mr & 7), cnt - 1)];

    s8v abuf[PF];
    s8v bbuf[PF][4];

    // ================= layer 0: K=1600, 2-way k-split, depth-PF pipeline =================
    f4v a0 = {0,0,0,0}, a1 = {0,0,0,0}, a2 = {0,0,0,0}, a3 = {0,0,0,0};
    {
        const unsigned short* Ap = A   + (size_t)arow * DDIM + h * 800 + q * 8;
        const unsigned short* Bp = W0T + (size_t)(n0 + mr) * DDIM + h * 800 + q * 8;
#pragma unroll
        for (int p = 0; p < PF; ++p) {
            abuf[p] = *(const s8v*)(Ap + p * 32);
#pragma unroll
            for (int j = 0; j < 4; ++j)
                bbuf[p][j] = *(const s8v*)(Bp + j * 16 * DDIM + p * 32);
        }
#pragma unroll
        for (int kt = 0; kt < 25; ++kt) {
            const int s = kt % PF;
            s8v av = abuf[s];
            s8v b0 = bbuf[s][0], b1 = bbuf[s][1], b2 = bbuf[s][2], b3 = bbuf[s][3];
            if (kt + PF < 25) {
                abuf[s] = *(const s8v*)(Ap + (kt + PF) * 32);
#pragma unroll
                for (int j = 0; j < 4; ++j)
                    bbuf[s][j] = *(const s8v*)(Bp + j * 16 * DDIM + (kt + PF) * 32);
            }
            a0 = __builtin_amdgcn_mfma_f32_16x16x32_bf16(av, b0, a0, 0, 0, 0);
            a1 = __builtin_amdgcn_mfma_f32_16x16x32_bf16(av, b1, a1, 0, 0, 0);
            a2 = __builtin_amdgcn_mfma_f32_16x16x32_bf16(av, b2, a2, 0, 0, 0);
            a3 = __builtin_amdgcn_mfma_f32_16x16x32_bf16(av, b3, a3, 0, 0, 0);
        }
    }
    // prefetch layer-1 B panel (overlaps layer-0 epilogue + barriers)
    {
        const unsigned short* Bp1 = W1T + (size_t)(n0 + mr) * 512 + z * 256 + h * 128 + q * 8;
#pragma unroll
        for (int kt = 0; kt < 4; ++kt)
#pragma unroll
            for (int j = 0; j < 4; ++j)
                bbuf[kt][j] = *(const s8v*)(Bp1 + j * 16 * 512 + kt * 32);
    }
    // layer-0 epilogue
    if (h == 1) {
#pragma unroll
        for (int r = 0; r < 4; ++r) {
            lred[wc][lane][r]      = a0[r];
            lred[wc][lane][4 + r]  = a1[r];
            lred[wc][lane][8 + r]  = a2[r];
            lred[wc][lane][12 + r] = a3[r];
        }
    }
    __syncthreads();
    if (h == 0) {
#pragma unroll
        for (int j = 0; j < 4; ++j) {
            const float bv = biases[n0 + j * 16 + mr];
            f4v* ap = (j == 0) ? &a0 : (j == 1) ? &a1 : (j == 2) ? &a2 : &a3;
#pragma unroll
            for (int r = 0; r < 4; ++r) {
                int row = q * 4 + r;
                if (row < 8) {
                    float s = (*ap)[r] + lred[wc][lane][j * 4 + r] + bv;
                    int col = wc * 64 + j * 16 + mr;
                    Hs0[row * HPAD + col] = f2bf(ftanh(s));
                }
            }
        }
    }
    __syncthreads();

    // ================= layer 1: K=256, residual =================
    {
        f4v acc[4] = {{0,0,0,0},{0,0,0,0},{0,0,0,0},{0,0,0,0}};
#pragma unroll
        for (int kt = 0; kt < 4; ++kt) {
            s8v av = *(const s8v*)((const char*)Hs0
                     + (size_t)(mr & 7) * (HPAD * 2) + h * 256 + q * 16 + kt * 64);
#pragma unroll
            for (int j = 0; j < 4; ++j)
                acc[j] = __builtin_amdgcn_mfma_f32_16x16x32_bf16(av, bbuf[kt][j], acc[j], 0, 0, 0);
        }
        // prefetch layer-2 B panel (overlaps layer-1 epilogue + barriers)
        {
            const unsigned short* Bp2 = W2T + (size_t)(n0 + mr) * 512 + z * 256 + h * 128 + q * 8;
#pragma unroll
            for (int kt = 0; kt < 4; ++kt)
#pragma unroll
                for (int j = 0; j < 4; ++j)
                    bbuf[kt][j] = *(const s8v*)(Bp2 + j * 16 * 512 + kt * 32);
        }
        if (h == 1) {
#pragma unroll
            for (int j = 0; j < 4; ++j)
#pragma unroll
                for (int r = 0; r < 4; ++r) lred[wc][lane][j * 4 + r] = acc[j][r];
        }
        __syncthreads();
        if (h == 0) {
#pragma unroll
            for (int j = 0; j < 4; ++j) {
                const float bv = biases[512 + n0 + j * 16 + mr];
#pragma unroll
                for (int r = 0; r < 4; ++r) {
                    int row = q * 4 + r;
                    if (row < 8) {
                        float s = acc[j][r] + lred[wc][lane][j * 4 + r] + bv;
                        int col = wc * 64 + j * 16 + mr;
                        float hv = bf2f(Hs0[row * HPAD + col]) + ftanh(s);
                        Hs1[row * HPAD + col] = f2bf(hv);
                    }
                }
            }
        }
        __syncthreads();
    }

    // ================= layer 2 + w3 dot =================
    {
        f4v acc[4] = {{0,0,0,0},{0,0,0,0},{0,0,0,0},{0,0,0,0}};
#pragma unroll
        for (int kt = 0; kt < 4; ++kt) {
            s8v av = *(const s8v*)((const char*)Hs1
                     + (size_t)(mr & 7) * (HPAD * 2) + h * 256 + q * 16 + kt * 64);
#pragma unroll
            for (int j = 0; j < 4; ++j)
                acc[j] = __builtin_amdgcn_mfma_f32_16x16x32_bf16(av, bbuf[kt][j], acc[j], 0, 0, 0);
        }
        if (h == 1) {
#pragma unroll
            for (int j = 0; j < 4; ++j)
#pragma unroll
                for (int r = 0; r < 4; ++r) lred[wc][lane][j * 4 + r] = acc[j][r];
        }
        __syncthreads();
        if (h == 0 && q < 2) {
            float pr[4] = {0, 0, 0, 0};
#pragma unroll
            for (int j = 0; j < 4; ++j) {
                const int col = n0 + j * 16 + mr;
                const float bv = biases[1024 + col];
                const float wv = w3c[col];
#pragma unroll
                for (int r = 0; r < 4; ++r) {
                    float s = acc[j][r] + lred[wc][lane][j * 4 + r] + bv;
                    int row = q * 4 + r, coll = wc * 64 + j * 16 + mr;
                    float hv = bf2f(Hs1[row * HPAD + coll]) + ftanh(s);
                    pr[r] = fmaf(hv, wv, pr[r]);
                }
            }
#pragma unroll
            for (int r = 0; r < 4; ++r) {
                float p = pr[r];
                p += __shfl_xor(p, 1, 16);
                p += __shfl_xor(p, 2, 16);
                p += __shfl_xor(p, 4, 16);
                p += __shfl_xor(p, 8, 16);
                if (mr == 0) red2[q * 4 + r][wc] = p;
            }
        }
        __syncthreads();
        if (tid < 8 && m0 + tid < cnt) {
            const int orow = wsi[PERM_I + base + m0 + tid];
            out[4 + orow] += red2[tid][0] + red2[tid][1] + red2[tid][2] + red2[tid][3];
        }
    }
}

// ---------- K4: Etot over Ei ----------
__global__ void etot_kernel(float* __restrict__ out) {
    const int b = blockIdx.x;
    float s = 0.0f;
    for (int n = threadIdx.x; n < NAT; n += 256) s += out[4 + b * NAT + n];
#pragma unroll
    for (int off = 32; off > 0; off >>= 1) s += __shfl_down(s, off, 64);
    __shared__ float rr[4];
    if ((threadIdx.x & 63) == 0) rr[threadIdx.x >> 6] = s;
    __syncthreads();
    if (threadIdx.x == 0) out[b] = rr[0] + rr[1] + rr[2] + rr[3];
}

// ================= fallback (small ws): monolithic per-atom =================
__global__ void dp_atom_kernel(
    const int* __restrict__ itype, const float* __restrict__ imagedr,
    const float* __restrict__ davg, const float* __restrict__ dstd,
    const float* __restrict__ eW0, const float* __restrict__ eb0,
    const float* __restrict__ eW1, const float* __restrict__ eb1,
    const float* __restrict__ eW2, const float* __restrict__ eb2,
    const float* __restrict__ fW0, const float* __restrict__ fb0,
    const float* __restrict__ fW1, const float* __restrict__ fb1,
    const float* __restrict__ fW2, const float* __restrict__ fb2,
    const float* __restrict__ fW3, const float* __restrict__ fb3,
    const float* __restrict__ eshift, float* __restrict__ out)
{
    __shared__ __align__(16) float4 rn4[NNEI];
    __shared__ __align__(16) float  xyz[4 * EMB];
    __shared__ __align__(16) float  h0s[100 * 25];
    __shared__ __align__(16) float  smem[100 * 52];
    const int atom = blockIdx.x;
    const int n = atom & (NAT - 1);
    const int tid = threadIdx.x;
    const int t = itype[n];
    for (int m = tid; m < NNEI; m += 256) {
        float4 dr = ((const float4*)imagedr)[(size_t)atom * NNEI + m];
        float R = dr.x;
        float S = calc_S(R);
        float Rsafe = (R > 1e-5f) ? R : 1.0f;
        float sr = (fabsf(R) > 1e-5f) ? (S / Rsafe) : 0.0f;
        float4 av = ((const float4*)davg)[t * NNEI + m];
        float4 sd = ((const float4*)dstd)[t * NNEI + m];
        float4 rv;
        rv.x = (S - av.x) / sd.x; rv.y = (sr * dr.y - av.y) / sd.y;
        rv.z = (sr * dr.z - av.z) / sd.z; rv.w = (sr * dr.w - av.w) / sd.w;
        rn4[m] = rv;
    }
    const int c = tid & 127; const int mh = tid >> 7;
    float xp0 = 0, xp1 = 0, xp2 = 0, xp3 = 0;
    for (int j = 0; j < NT; ++j) {
        const int wb = t * NT + j;
        const float* W0 = eW0 + wb * 25; const float* B0 = eb0 + wb * 25;
        const float* W1 = eW1 + wb * 1250; const float* B1 = eb1 + wb * 50;
        const float* W2 = eW2 + wb * 5000; const float* B2 = eb2 + wb * 100;
        __syncthreads();
        for (int idx = tid; idx < 2500; idx += 256) {
            int m = idx / 25, a = idx - m * 25;
            h0s[idx] = ftanh(fmaf(rn4[j * 100 + m].x, W0[a], B0[a]));
        }
        __syncthreads();
        for (int idx = tid; idx < 5000; idx += 256) {
            int m = idx / 50, cc = idx - m * 50;
            const float* h0m = h0s + m * 25;
            float acc = B1[cc];
#pragma unroll
            for (int a = 0; a < 25; ++a) acc = fmaf(h0m[a], W1[a * 50 + cc], acc);
            smem[m * 52 + cc] = ftanh(acc) + h0m[(cc < 25) ? cc : cc - 25];
        }
        for (int idx = tid; idx < 200; idx += 256)
            smem[(idx >> 1) * 52 + 50 + (idx & 1)] = 0.0f;
        __syncthreads();
        if (c < EMB) {
            float w2c[52];
#pragma unroll
            for (int a = 0; a < 50; ++a) w2c[a] = W2[a * EMB + c];
            w2c[50] = 0; w2c[51] = 0;
            const float bc = B2[c];
            const int sk = (c < 50) ? c : c - 50;
            for (int i = 0; i < 50; ++i) {
                int m = mh * 50 + i;
                const float* h1m = smem + m * 52;
                float acc = bc;
#pragma unroll
                for (int q = 0; q < 13; ++q) {
                    float4 hv = ((const float4*)h1m)[q];
                    acc = fmaf(hv.x, w2c[4 * q], acc); acc = fmaf(hv.y, w2c[4 * q + 1], acc);
                    acc = fmaf(hv.z, w2c[4 * q + 2], acc); acc = fmaf(hv.w, w2c[4 * q + 3], acc);
                }
                float g = ftanh(acc) + h1m[sk];
                float4 rm = rn4[j * 100 + m];
                xp0 = fmaf(rm.x, g, xp0); xp1 = fmaf(rm.y, g, xp1);
                xp2 = fmaf(rm.z, g, xp2); xp3 = fmaf(rm.w, g, xp3);
            }
        }
    }
    __syncthreads();
    const float inv = 1.0f / 200.0f;
    if (mh == 0 && c < EMB) {
        xyz[c] = xp0 * inv; xyz[EMB + c] = xp1 * inv;
        xyz[2 * EMB + c] = xp2 * inv; xyz[3 * EMB + c] = xp3 * inv;
    }
    __syncthreads();
    if (mh == 1 && c < EMB) {
        xyz[c] += xp0 * inv; xyz[EMB + c] += xp1 * inv;
        xyz[2 * EMB + c] += xp2 * inv; xyz[3 * EMB + c] += xp3 * inv;
    }
    __syncthreads();
    float* Dld = smem;
    for (int idx = tid; idx < DDIM; idx += 256) {
        int cc = idx >> 4, d = idx & 15;
        Dld[idx] = xyz[cc] * xyz[d] + xyz[EMB + cc] * xyz[EMB + d]
                 + xyz[2 * EMB + cc] * xyz[2 * EMB + d] + xyz[3 * EMB + cc] * xyz[3 * EMB + d];
    }
    __syncthreads();
    float* hA = smem + DDIM; float* hB = hA + FITH; float* h2 = hB + FITH; float* red = h2 + FITH;
    if (tid < FITH) {
        const float* W = fW0 + (size_t)t * DDIM * FITH;
        float acc = fb0[t * FITH + tid];
        for (int f = 0; f < DDIM; f += 4) {
            float4 dv = *(const float4*)(Dld + f);
            acc = fmaf(dv.x, W[f * FITH + tid], acc); acc = fmaf(dv.y, W[(f + 1) * FITH + tid], acc);
            acc = fmaf(dv.z, W[(f + 2) * FITH + tid], acc); acc = fmaf(dv.w, W[(f + 3) * FITH + tid], acc);
        }
        hA[tid] = ftanh(acc);
    }
    __syncthreads();
    if (tid < FITH) {
        const float* W = fW1 + t * FITH * FITH;
        float acc = fb1[t * FITH + tid];
        for (int f = 0; f < FITH; f += 4) {
            float4 hv = *(const float4*)(hA + f);
            acc = fmaf(hv.x, W[f * FITH + tid], acc); acc = fmaf(hv.y, W[(f + 1) * FITH + tid], acc);
            acc = fmaf(hv.z, W[(f + 2) * FITH + tid], acc); acc = fmaf(hv.w, W[(f + 3) * FITH + tid], acc);
        }
        hB[tid] = hA[tid] + ftanh(acc);
    }
    __syncthreads();
    if (tid < FITH) {
        const float* W = fW2 + t * FITH * FITH;
        float acc = fb2[t * FITH + tid];
        for (int f = 0; f < FITH; f += 4) {
            float4 hv = *(const float4*)(hB + f);
            acc = fmaf(hv.x, W[f * FITH + tid], acc); acc = fmaf(hv.y, W[(f + 1) * FITH + tid], acc);
            acc = fmaf(hv.z, W[(f + 2) * FITH + tid], acc); acc = fmaf(hv.w, W[(f + 3) * FITH + tid], acc);
        }
        h2[tid] = hB[tid] + ftanh(acc);
    }
    __syncthreads();
    float p = (tid < FITH) ? h2[tid] * fW3[t * FITH + tid] : 0.0f;
#pragma unroll
    for (int off = 32; off > 0; off >>= 1) p += __shfl_down(p, off, 64);
    if ((tid & 63) == 0) red[tid >> 6] = p;
    __syncthreads();
    if (tid == 0) out[4 + atom] = red[0] + red[1] + red[2] + red[3] + fb3[t] + eshift[t];
}

extern "C" void kernel_launch(void* const* d_in, const int* in_sizes, int n_in,
                              void* d_out, int out_size, void* d_ws, size_t ws_size,
                              hipStream_t stream) {
    const int*   itype   = (const int*)  d_in[1];
    const float* imagedr = (const float*)d_in[3];
    const float* davg    = (const float*)d_in[5];
    const float* dstd    = (const float*)d_in[6];
    const float* eW0     = (const float*)d_in[7];
    const float* eb0     = (const float*)d_in[8];
    const float* eW1     = (const float*)d_in[9];
    const float* eb1     = (const float*)d_in[10];
    const float* eW2     = (const float*)d_in[11];
    const float* eb2     = (const float*)d_in[12];
    const float* fW0     = (const float*)d_in[13];
    const float* fb0     = (const float*)d_in[14];
    const float* fW1     = (const float*)d_in[15];
    const float* fb1     = (const float*)d_in[16];
    const float* fW2     = (const float*)d_in[17];
    const float* fb2     = (const float*)d_in[18];
    const float* fW3     = (const float*)d_in[19];
    const float* fb3     = (const float*)d_in[20];
    const float* eshift  = (const float*)d_in[21];
    float* out = (float*)d_out;
    float* ws  = (float*)d_ws;

    if (ws_size >= WS_NEED) {
        unsigned short* u0 = (unsigned short*)((char*)ws + USH_BYTE);
        const int* wsi = (const int*)ws;
        prep_kernel<<<WT_BLK + TB_BLK + 1, 256, 0, stream>>>(
            fW0, fW1, fW2, fb0, fb1, fb2, fW3, fb3, eshift,
            davg, dstd, eW0, eb0, eW1, eb1, eW2, eb2, itype, ws, out);
        embed_kernel<<<NATOMS, 128, 0, stream>>>(itype, imagedr, davg, dstd, ws);
        fit_kernel<<<dim3(256, 2), 512, 0, stream>>>(
            u0 + D_U, u0 + W0T_U, u0 + W1T_U, u0 + W2T_U,
            ws + BIAS_F, ws + W3C_F, wsi, out);
        etot_kernel<<<BSZ, 256, 0, stream>>>(out);
    } else {
        dp_atom_kernel<<<NATOMS, 256, 0, stream>>>(itype, imagedr, davg, dstd,
            eW0, eb0, eW1, eb1, eW2, eb2,
            fW0, fb0, fW1, fb1, fW2, fb2, fW3, fb3, eshift, out);
        etot_kernel<<<BSZ, 256, 0, stream>>>(out);
    }
}

// Round 4
// 228.475 us; speedup vs baseline: 1.7495x; 1.7495x over previous
//
#include <hip/hip_runtime.h>
#include <math.h>

#define NT 2
#define BSZ 4
#define NAT 512
#define NATOMS 2048
#define NNEI 200
#define EMB 100
#define FITH 240
#define DDIM 1600
#define TBK 1024

// ---- ws layout ----
// float region: [0..8) table ranges; [16..1552) concat biases; [1552..2064) w3c;
// int   region: [2064..4112) perm, [4112..4114) counts
#define BIAS_F  16
#define W3C_F   (BIAS_F + 3 * 512)
#define PERM_I  2064
#define CNT_I   (PERM_I + 2048)
#define USH_BYTE 16512
#define TBL_U   0                          // 4*1024*100 = 409600
#define W0T_U   409600                     // [512][1600] = 819200
#define W1T_U   (W0T_U + 819200)           // [512][512]  = 262144
#define W2T_U   (W1T_U + 262144)           // 262144
#define D_U     (W2T_U + 262144)           // [2048][1600] = 3276800
#define H0_U    (D_U + 3276800)            // kept for ws sizing
#define H1_U    (H0_U + 1048576)
#define USH_END (H1_U + 1048576)
#define WS_NEED ((size_t)USH_BYTE + (size_t)USH_END * 2)   // ~12.2 MB

#define N_W0 819200
#define N_W1 262144
#define N_W2 262144
#define N_B  1536
#define N_W3 512
#define N_EI 2048
#define N_WT (N_W0 + N_W1 + N_W2 + N_B + N_W3 + N_EI)      // 1347584
#define WT_BLK ((N_WT + 255) / 256)                        // 5264
#define TB_BLK 512

// H rows padded to 264 ushorts (528 B) -> consecutive rows land on rotated
// 16B slots, spreading ds_read_b128 A-fragment reads across banks.
#define HPAD 264
// fit layer-0 register-prefetch depth (5 loads/stage, 16B each)
#define PF 6

typedef short s8v __attribute__((ext_vector_type(8)));
typedef float f4v __attribute__((ext_vector_type(4)));

__device__ __forceinline__ float ftanh(float x) {
    float ax = fabsf(x);
    float e = __expf(2.0f * ax);
    float t = 1.0f - __fdividef(2.0f, e + 1.0f);
    return (x < 0.0f) ? -t : t;
}
__device__ __forceinline__ unsigned short f2bf(float f) {
    unsigned u = __float_as_uint(f);
    u += 0x7FFFu + ((u >> 16) & 1u);
    return (unsigned short)(u >> 16);
}
__device__ __forceinline__ float bf2f(unsigned short s) {
    return __uint_as_float(((unsigned)s) << 16);
}
__device__ __forceinline__ float calc_S(float R) {
    float Rsafe = (R > 1e-5f) ? R : 1.0f;
    float u = (R - 0.5f) * (1.0f / 5.5f);
    float uu = u * u;
    float mid = (u * uu * (-6.0f * uu + 15.0f * u - 10.0f) + 1.0f) / Rsafe;
    float S = 0.0f;
    if (R > 0.0f && R < 0.5f)      S = 1.0f / Rsafe;
    else if (R > 0.5f && R < 6.0f) S = mid;
    return S;
}

// ---------- K1: prep = wtrans + table build + type-perm ----------
__global__ void __launch_bounds__(256) prep_kernel(
    const float* __restrict__ fW0, const float* __restrict__ fW1,
    const float* __restrict__ fW2,
    const float* __restrict__ fb0, const float* __restrict__ fb1,
    const float* __restrict__ fb2,
    const float* __restrict__ fW3, const float* __restrict__ fb3,
    const float* __restrict__ eshift,
    const float* __restrict__ davg, const float* __restrict__ dstd,
    const float* __restrict__ eW0, const float* __restrict__ eb0,
    const float* __restrict__ eW1, const float* __restrict__ eb1,
    const float* __restrict__ eW2, const float* __restrict__ eb2,
    const int* __restrict__ itype,
    float* __restrict__ ws, float* __restrict__ out)
{
    __shared__ float los[100], his[100];
    __shared__ float rng[2];
    __shared__ float h0s[8][25];
    __shared__ float h1s[8][50];
    __shared__ int pcnt, poff0, poff1;
    const int tid = threadIdx.x;
    int bxg = blockIdx.x;
    unsigned short* u0 = (unsigned short*)((char*)ws + USH_BYTE);

    if (bxg < WT_BLK) {
        // ---- weight transform ----
        int id = bxg * 256 + tid;
        if (id < N_W0) {
            int n = id / 1600, k = id - n * 1600;
            float v = 0.0f;
            if (n < 240)                  v = fW0[(size_t)k * 240 + n];
            else if (n >= 256 && n < 496) v = fW0[(size_t)(1600 + k) * 240 + (n - 256)];
            u0[W0T_U + id] = f2bf(v);
            return;
        }
        id -= N_W0;
        if (id < N_W1) {
            int n = id / 512, k = id - n * 512;
            float v = 0.0f;
            if (n < 240 && k < 240)       v = fW1[(size_t)k * 240 + n];
            else if (n >= 256 && n < 496 && k >= 256 && k < 496)
                                          v = fW1[(size_t)(240 + (k - 256)) * 240 + (n - 256)];
            u0[W1T_U + id] = f2bf(v);
            return;
        }
        id -= N_W1;
        if (id < N_W2) {
            int n = id / 512, k = id - n * 512;
            float v = 0.0f;
            if (n < 240 && k < 240)       v = fW2[(size_t)k * 240 + n];
            else if (n >= 256 && n < 496 && k >= 256 && k < 496)
                                          v = fW2[(size_t)(240 + (k - 256)) * 240 + (n - 256)];
            u0[W2T_U + id] = f2bf(v);
            return;
        }
        id -= N_W2;
        if (id < N_B) {
            int l = id / 512, n = id - l * 512;
            const float* fb = (l == 0) ? fb0 : (l == 1) ? fb1 : fb2;
            float v = 0.0f;
            if (n < 240)                  v = fb[n];
            else if (n >= 256 && n < 496) v = fb[240 + (n - 256)];
            ws[BIAS_F + l * 512 + n] = v;
            return;
        }
        id -= N_B;
        if (id < N_W3) {
            int n = id;
            float v = 0.0f;
            if (n < 240)                  v = fW3[n];
            else if (n >= 256 && n < 496) v = fW3[240 + (n - 256)];
            ws[W3C_F + n] = v;
            return;
        }
        id -= N_W3;
        if (id < N_EI) {
            int t = itype[id & (NAT - 1)];
            out[4 + id] = fb3[t] + eshift[t];
        }
        return;
    }
    bxg -= WT_BLK;
    if (bxg < TB_BLK) {
        // ---- embedding table build ----
        const int nid = bxg >> 7;
        const int kb  = (bxg & 127) * 8;
        const int t = nid >> 1, j = nid & 1;
        if (tid < 100) {
            int m = j * 100 + tid;
            float av = davg[(t * NNEI + m) * 4];
            float sd = dstd[(t * NNEI + m) * 4];
            float inv = __fdividef(1.0f, sd);
            float a = (0.0f - av) * inv;         // S in [0,2] for this data
            float b = (2.0f - av) * inv;
            los[tid] = fminf(a, b);
            his[tid] = fmaxf(a, b);
        }
        __syncthreads();
        if (tid == 0) {
            float lo = los[0], hi = his[0];
            for (int i = 1; i < 100; ++i) { lo = fminf(lo, los[i]); hi = fmaxf(hi, his[i]); }
            rng[0] = lo; rng[1] = hi - lo;
            if (kb == 0) {
                ws[nid * 2] = lo;
                ws[nid * 2 + 1] = (float)(TBK - 1) / (hi - lo);
            }
        }
        __syncthreads();
        const float smin = rng[0], span = rng[1];
        const float* W0 = eW0 + nid * 25;
        const float* B0 = eb0 + nid * 25;
        if (tid < 200) {
            int q = tid / 25, a = tid % 25;
            float s = smin + span * ((float)(kb + q) * (1.0f / (TBK - 1)));
            h0s[q][a] = ftanh(fmaf(s, W0[a], B0[a]));
        }
        __syncthreads();
        const float* W1 = eW1 + nid * 1250;
        const float* B1 = eb1 + nid * 50;
        for (int idx = tid; idx < 400; idx += 256) {
            int q = idx / 50, cc = idx % 50;
            float acc = B1[cc];
#pragma unroll
            for (int a = 0; a < 25; ++a) acc = fmaf(h0s[q][a], W1[a * 50 + cc], acc);
            h1s[q][cc] = ftanh(acc) + h0s[q][(cc < 25) ? cc : cc - 25];
        }
        __syncthreads();
        const float* W2 = eW2 + nid * 5000;
        const float* B2 = eb2 + nid * 100;
        unsigned short* tblu = u0 + TBL_U;
        for (int idx = tid; idx < 800; idx += 256) {
            int q = idx / 100, c = idx % 100;
            float acc = B2[c];
#pragma unroll
            for (int a = 0; a < 50; ++a) acc = fmaf(h1s[q][a], W2[a * 100 + c], acc);
            float g = ftanh(acc) + h1s[q][(c < 50) ? c : c - 50];
            tblu[(size_t)(nid * TBK + kb + q) * 100 + c] = f2bf(g);
        }
        return;
    }
    // ---- type partition perm ----
    if (tid == 0) { pcnt = 0; poff0 = 0; poff1 = 0; }
    __syncthreads();
    int* wsi = (int*)ws;
    int local0 = 0;
    for (int i = tid; i < NATOMS; i += 256) local0 += (itype[i & (NAT - 1)] == 0);
    atomicAdd(&pcnt, local0);
    __syncthreads();
    const int c0 = pcnt;
    for (int i = tid; i < NATOMS; i += 256) {
        int t = itype[i & (NAT - 1)];
        int pos = (t == 0) ? atomicAdd(&poff0, 1) : (c0 + atomicAdd(&poff1, 1));
        wsi[PERM_I + pos] = i;
    }
    if (tid == 0) { wsi[CNT_I] = c0; wsi[CNT_I + 1] = NATOMS - c0; }
}

// ---------- K2: embed (table interp) -> D bf16 [2048][1600] ----------
// (round-0 proven version: moderate unroll, no manual register pipeline --
//  the PFE=6 fully-unrolled pipeline blew VGPR to 256 and 5x'd the kernel)
__global__ void __launch_bounds__(128) embed_kernel(
    const int* __restrict__ itype, const float* __restrict__ imagedr,
    const float* __restrict__ davg, const float* __restrict__ dstd,
    float* __restrict__ ws)
{
    __shared__ __align__(16) float4 srn[NNEI];
    __shared__ float sx[NNEI];
    __shared__ float part[2][400];
    const int atom = blockIdx.x;
    const int n = atom & (NAT - 1);
    const int tid = threadIdx.x;
    const int t = itype[n];
    unsigned short* u0 = (unsigned short*)((char*)ws + USH_BYTE);

    const float sm0 = ws[(t * 2 + 0) * 2], sc0 = ws[(t * 2 + 0) * 2 + 1];
    const float sm1 = ws[(t * 2 + 1) * 2], sc1 = ws[(t * 2 + 1) * 2 + 1];

    for (int m = tid; m < NNEI; m += 128) {
        float4 dr = ((const float4*)imagedr)[(size_t)atom * NNEI + m];
        float R = dr.x;
        float S = calc_S(R);
        float Rsafe = (R > 1e-5f) ? R : 1.0f;
        float sr = (fabsf(R) > 1e-5f) ? (S / Rsafe) : 0.0f;
        float4 av = ((const float4*)davg)[t * NNEI + m];
        float4 sd = ((const float4*)dstd)[t * NNEI + m];
        float4 rv;
        rv.x = (S         - av.x) / sd.x;
        rv.y = (sr * dr.y - av.y) / sd.y;
        rv.z = (sr * dr.z - av.z) / sd.z;
        rv.w = (sr * dr.w - av.w) / sd.w;
        srn[m] = rv;
        float smin = (m >= 100) ? sm1 : sm0;
        float scal = (m >= 100) ? sc1 : sc0;
        sx[m] = fminf(fmaxf((rv.x - smin) * scal, 0.0f), (float)(TBK - 2) + 0.9999f);
    }
    __syncthreads();

    const int w = tid >> 6, lane = tid & 63;
    const unsigned short* T = u0 + TBL_U + (size_t)(t * 2 + w) * TBK * EMB;
    const bool hi = (lane < 36);
    float xA0 = 0, xA1 = 0, xA2 = 0, xA3 = 0;
    float xB0 = 0, xB1 = 0, xB2 = 0, xB3 = 0;
#pragma unroll 4
    for (int mi = 0; mi < 100; ++mi) {
        int m = w * 100 + mi;
        float4 rv = srn[m];
        float x = sx[m];
        int i = (int)x;
        float f = x - (float)i;
        const unsigned short* Tr = T + (size_t)i * EMB;
        float g0 = bf2f(Tr[lane]);
        float g1 = bf2f(Tr[EMB + lane]);
        float g = fmaf(f, g1 - g0, g0);
        xA0 = fmaf(rv.x, g, xA0); xA1 = fmaf(rv.y, g, xA1);
        xA2 = fmaf(rv.z, g, xA2); xA3 = fmaf(rv.w, g, xA3);
        if (hi) {
            float h0v = bf2f(Tr[64 + lane]);
            float h1v = bf2f(Tr[EMB + 64 + lane]);
            float g2 = fmaf(f, h1v - h0v, h0v);
            xB0 = fmaf(rv.x, g2, xB0); xB1 = fmaf(rv.y, g2, xB1);
            xB2 = fmaf(rv.z, g2, xB2); xB3 = fmaf(rv.w, g2, xB3);
        }
    }
    part[w][0 * 100 + lane] = xA0; part[w][1 * 100 + lane] = xA1;
    part[w][2 * 100 + lane] = xA2; part[w][3 * 100 + lane] = xA3;
    if (hi) {
        part[w][0 * 100 + 64 + lane] = xB0; part[w][1 * 100 + 64 + lane] = xB1;
        part[w][2 * 100 + 64 + lane] = xB2; part[w][3 * 100 + 64 + lane] = xB3;
    }
    __syncthreads();
    const float inv = 1.0f / 200.0f;
    for (int idx = tid; idx < 400; idx += 128)
        part[0][idx] = (part[0][idx] + part[1][idx]) * inv;   // xyz[4][100]
    __syncthreads();
    unsigned short* Drow = u0 + D_U + (size_t)atom * DDIM;
    const float* xt = part[0];
    for (int idx = tid; idx < DDIM; idx += 128) {
        int c = idx >> 4, d = idx & 15;
        float s = xt[c] * xt[d] + xt[100 + c] * xt[100 + d]
                + xt[200 + c] * xt[200 + d] + xt[300 + c] * xt[300 + d];
        Drow[idx] = f2bf(s);
    }
}

// ---------- K3: fused fitting net ----------
// 8 rows/block (MFMA rows duplicated via mr&7 -> 256+ useful blocks, every CU
// busy), depth-PF register pipeline on layer-0 loads, next-layer B panels
// prefetched before the previous layer's epilogue barriers.
__global__ void __launch_bounds__(512) fit_kernel(
    const unsigned short* __restrict__ A,     // D [2048][1600]
    const unsigned short* __restrict__ W0T,   // [512][1600]
    const unsigned short* __restrict__ W1T,   // [512][512]
    const unsigned short* __restrict__ W2T,   // [512][512]
    const float* __restrict__ biases,         // [3][512]
    const float* __restrict__ w3c,            // [512]
    const int* __restrict__ wsi,
    float* __restrict__ out)
{
    __shared__ float lred[4][64][17];             // k-split reduce (17: bank pad)
    __shared__ unsigned short Hs0[8 * HPAD];      // H0 bf16, padded rows
    __shared__ unsigned short Hs1[8 * HPAD];      // H1 bf16
    __shared__ float red2[8][4];                  // per-row partial dots per col-tile

    const int z = blockIdx.y;
    const int cnt = wsi[CNT_I + z];
    const int my = blockIdx.x;
    if (my * 8 >= cnt) return;
    const int base = z ? wsi[CNT_I] : 0;
    const int tid = threadIdx.x;
    const int w = tid >> 6, lane = tid & 63;
    const int mr = lane & 15, q = lane >> 4;
    const int wc = w & 3, h = w >> 2;             // col-tile, k-half
    const int n0 = z * 256 + wc * 64;
    const int m0 = my * 8;
    const int arow = wsi[PERM_I + base + min(m0 + (mr & 7), cnt - 1)];

    s8v abuf[PF];
    s8v bbuf[PF][4];

    // ================= layer 0: K=1600, 2-way k-split, depth-PF pipeline =================
    f4v a0 = {0,0,0,0}, a1 = {0,0,0,0}, a2 = {0,0,0,0}, a3 = {0,0,0,0};
    {
        const unsigned short* Ap = A   + (size_t)arow * DDIM + h * 800 + q * 8;
        const unsigned short* Bp = W0T + (size_t)(n0 + mr) * DDIM + h * 800 + q * 8;
#pragma unroll
        for (int p = 0; p < PF; ++p) {
            abuf[p] = *(const s8v*)(Ap + p * 32);
#pragma unroll
            for (int j = 0; j < 4; ++j)
                bbuf[p][j] = *(const s8v*)(Bp + j * 16 * DDIM + p * 32);
        }
#pragma unroll
        for (int kt = 0; kt < 25; ++kt) {
            const int s = kt % PF;
            s8v av = abuf[s];
            s8v b0 = bbuf[s][0], b1 = bbuf[s][1], b2 = bbuf[s][2], b3 = bbuf[s][3];
            if (kt + PF < 25) {
                abuf[s] = *(const s8v*)(Ap + (kt + PF) * 32);
#pragma unroll
                for (int j = 0; j < 4; ++j)
                    bbuf[s][j] = *(const s8v*)(Bp + j * 16 * DDIM + (kt + PF) * 32);
            }
            a0 = __builtin_amdgcn_mfma_f32_16x16x32_bf16(av, b0, a0, 0, 0, 0);
            a1 = __builtin_amdgcn_mfma_f32_16x16x32_bf16(av, b1, a1, 0, 0, 0);
            a2 = __builtin_amdgcn_mfma_f32_16x16x32_bf16(av, b2, a2, 0, 0, 0);
            a3 = __builtin_amdgcn_mfma_f32_16x16x32_bf16(av, b3, a3, 0, 0, 0);
        }
    }
    // prefetch layer-1 B panel (overlaps layer-0 epilogue + barriers)
    {
        const unsigned short* Bp1 = W1T + (size_t)(n0 + mr) * 512 + z * 256 + h * 128 + q * 8;
#pragma unroll
        for (int kt = 0; kt < 4; ++kt)
#pragma unroll
            for (int j = 0; j < 4; ++j)
                bbuf[kt][j] = *(const s8v*)(Bp1 + j * 16 * 512 + kt * 32);
    }
    // layer-0 epilogue
    if (h == 1) {
#pragma unroll
        for (int r = 0; r < 4; ++r) {
            lred[wc][lane][r]      = a0[r];
            lred[wc][lane][4 + r]  = a1[r];
            lred[wc][lane][8 + r]  = a2[r];
            lred[wc][lane][12 + r] = a3[r];
        }
    }
    __syncthreads();
    if (h == 0) {
#pragma unroll
        for (int j = 0; j < 4; ++j) {
            const float bv = biases[n0 + j * 16 + mr];
            f4v* ap = (j == 0) ? &a0 : (j == 1) ? &a1 : (j == 2) ? &a2 : &a3;
#pragma unroll
            for (int r = 0; r < 4; ++r) {
                int row = q * 4 + r;
                if (row < 8) {
                    float s = (*ap)[r] + lred[wc][lane][j * 4 + r] + bv;
                    int col = wc * 64 + j * 16 + mr;
                    Hs0[row * HPAD + col] = f2bf(ftanh(s));
                }
            }
        }
    }
    __syncthreads();

    // ================= layer 1: K=256, residual =================
    {
        f4v acc[4] = {{0,0,0,0},{0,0,0,0},{0,0,0,0},{0,0,0,0}};
#pragma unroll
        for (int kt = 0; kt < 4; ++kt) {
            s8v av = *(const s8v*)((const char*)Hs0
                     + (size_t)(mr & 7) * (HPAD * 2) + h * 256 + q * 16 + kt * 64);
#pragma unroll
            for (int j = 0; j < 4; ++j)
                acc[j] = __builtin_amdgcn_mfma_f32_16x16x32_bf16(av, bbuf[kt][j], acc[j], 0, 0, 0);
        }
        // prefetch layer-2 B panel (overlaps layer-1 epilogue + barriers)
        {
            const unsigned short* Bp2 = W2T + (size_t)(n0 + mr) * 512 + z * 256 + h * 128 + q * 8;
#pragma unroll
            for (int kt = 0; kt < 4; ++kt)
#pragma unroll
                for (int j = 0; j < 4; ++j)
                    bbuf[kt][j] = *(const s8v*)(Bp2 + j * 16 * 512 + kt * 32);
        }
        if (h == 1) {
#pragma unroll
            for (int j = 0; j < 4; ++j)
#pragma unroll
                for (int r = 0; r < 4; ++r) lred[wc][lane][j * 4 + r] = acc[j][r];
        }
        __syncthreads();
        if (h == 0) {
#pragma unroll
            for (int j = 0; j < 4; ++j) {
                const float bv = biases[512 + n0 + j * 16 + mr];
#pragma unroll
                for (int r = 0; r < 4; ++r) {
                    int row = q * 4 + r;
                    if (row < 8) {
                        float s = acc[j][r] + lred[wc][lane][j * 4 + r] + bv;
                        int col = wc * 64 + j * 16 + mr;
                        float hv = bf2f(Hs0[row * HPAD + col]) + ftanh(s);
                        Hs1[row * HPAD + col] = f2bf(hv);
                    }
                }
            }
        }
        __syncthreads();
    }

    // ================= layer 2 + w3 dot =================
    {
        f4v acc[4] = {{0,0,0,0},{0,0,0,0},{0,0,0,0},{0,0,0,0}};
#pragma unroll
        for (int kt = 0; kt < 4; ++kt) {
            s8v av = *(const s8v*)((const char*)Hs1
                     + (size_t)(mr & 7) * (HPAD * 2) + h * 256 + q * 16 + kt * 64);
#pragma unroll
            for (int j = 0; j < 4; ++j)
                acc[j] = __builtin_amdgcn_mfma_f32_16x16x32_bf16(av, bbuf[kt][j], acc[j], 0, 0, 0);
        }
        if (h == 1) {
#pragma unroll
            for (int j = 0; j < 4; ++j)
#pragma unroll
                for (int r = 0; r < 4; ++r) lred[wc][lane][j * 4 + r] = acc[j][r];
        }
        __syncthreads();
        if (h == 0 && q < 2) {
            float pr[4] = {0, 0, 0, 0};
#pragma unroll
            for (int j = 0; j < 4; ++j) {
                const int col = n0 + j * 16 + mr;
                const float bv = biases[1024 + col];
                const float wv = w3c[col];
#pragma unroll
                for (int r = 0; r < 4; ++r) {
                    float s = acc[j][r] + lred[wc][lane][j * 4 + r] + bv;
                    int row = q * 4 + r, coll = wc * 64 + j * 16 + mr;
                    float hv = bf2f(Hs1[row * HPAD + coll]) + ftanh(s);
                    pr[r] = fmaf(hv, wv, pr[r]);
                }
            }
#pragma unroll
            for (int r = 0; r < 4; ++r) {
                float p = pr[r];
                p += __shfl_xor(p, 1, 16);
                p += __shfl_xor(p, 2, 16);
                p += __shfl_xor(p, 4, 16);
                p += __shfl_xor(p, 8, 16);
                if (mr == 0) red2[q * 4 + r][wc] = p;
            }
        }
        __syncthreads();
        if (tid < 8 && m0 + tid < cnt) {
            const int orow = wsi[PERM_I + base + m0 + tid];
            out[4 + orow] += red2[tid][0] + red2[tid][1] + red2[tid][2] + red2[tid][3];
        }
    }
}

// ---------- K4: Etot over Ei ----------
__global__ void etot_kernel(float* __restrict__ out) {
    const int b = blockIdx.x;
    float s = 0.0f;
    for (int n = threadIdx.x; n < NAT; n += 256) s += out[4 + b * NAT + n];
#pragma unroll
    for (int off = 32; off > 0; off >>= 1) s += __shfl_down(s, off, 64);
    __shared__ float rr[4];
    if ((threadIdx.x & 63) == 0) rr[threadIdx.x >> 6] = s;
    __syncthreads();
    if (threadIdx.x == 0) out[b] = rr[0] + rr[1] + rr[2] + rr[3];
}

// ================= fallback (small ws): monolithic per-atom =================
__global__ void dp_atom_kernel(
    const int* __restrict__ itype, const float* __restrict__ imagedr,
    const float* __restrict__ davg, const float* __restrict__ dstd,
    const float* __restrict__ eW0, const float* __restrict__ eb0,
    const float* __restrict__ eW1, const float* __restrict__ eb1,
    const float* __restrict__ eW2, const float* __restrict__ eb2,
    const float* __restrict__ fW0, const float* __restrict__ fb0,
    const float* __restrict__ fW1, const float* __restrict__ fb1,
    const float* __restrict__ fW2, const float* __restrict__ fb2,
    const float* __restrict__ fW3, const float* __restrict__ fb3,
    const float* __restrict__ eshift, float* __restrict__ out)
{
    __shared__ __align__(16) float4 rn4[NNEI];
    __shared__ __align__(16) float  xyz[4 * EMB];
    __shared__ __align__(16) float  h0s[100 * 25];
    __shared__ __align__(16) float  smem[100 * 52];
    const int atom = blockIdx.x;
    const int n = atom & (NAT - 1);
    const int tid = threadIdx.x;
    const int t = itype[n];
    for (int m = tid; m < NNEI; m += 256) {
        float4 dr = ((const float4*)imagedr)[(size_t)atom * NNEI + m];
        float R = dr.x;
        float S = calc_S(R);
        float Rsafe = (R > 1e-5f) ? R : 1.0f;
        float sr = (fabsf(R) > 1e-5f) ? (S / Rsafe) : 0.0f;
        float4 av = ((const float4*)davg)[t * NNEI + m];
        float4 sd = ((const float4*)dstd)[t * NNEI + m];
        float4 rv;
        rv.x = (S - av.x) / sd.x; rv.y = (sr * dr.y - av.y) / sd.y;
        rv.z = (sr * dr.z - av.z) / sd.z; rv.w = (sr * dr.w - av.w) / sd.w;
        rn4[m] = rv;
    }
    const int c = tid & 127; const int mh = tid >> 7;
    float xp0 = 0, xp1 = 0, xp2 = 0, xp3 = 0;
    for (int j = 0; j < NT; ++j) {
        const int wb = t * NT + j;
        const float* W0 = eW0 + wb * 25; const float* B0 = eb0 + wb * 25;
        const float* W1 = eW1 + wb * 1250; const float* B1 = eb1 + wb * 50;
        const float* W2 = eW2 + wb * 5000; const float* B2 = eb2 + wb * 100;
        __syncthreads();
        for (int idx = tid; idx < 2500; idx += 256) {
            int m = idx / 25, a = idx - m * 25;
            h0s[idx] = ftanh(fmaf(rn4[j * 100 + m].x, W0[a], B0[a]));
        }
        __syncthreads();
        for (int idx = tid; idx < 5000; idx += 256) {
            int m = idx / 50, cc = idx - m * 50;
            const float* h0m = h0s + m * 25;
            float acc = B1[cc];
#pragma unroll
            for (int a = 0; a < 25; ++a) acc = fmaf(h0m[a], W1[a * 50 + cc], acc);
            smem[m * 52 + cc] = ftanh(acc) + h0m[(cc < 25) ? cc : cc - 25];
        }
        for (int idx = tid; idx < 200; idx += 256)
            smem[(idx >> 1) * 52 + 50 + (idx & 1)] = 0.0f;
        __syncthreads();
        if (c < EMB) {
            float w2c[52];
#pragma unroll
            for (int a = 0; a < 50; ++a) w2c[a] = W2[a * EMB + c];
            w2c[50] = 0; w2c[51] = 0;
            const float bc = B2[c];
            const int sk = (c < 50) ? c : c - 50;
            for (int i = 0; i < 50; ++i) {
                int m = mh * 50 + i;
                const float* h1m = smem + m * 52;
                float acc = bc;
#pragma unroll
                for (int q = 0; q < 13; ++q) {
                    float4 hv = ((const float4*)h1m)[q];
                    acc = fmaf(hv.x, w2c[4 * q], acc); acc = fmaf(hv.y, w2c[4 * q + 1], acc);
                    acc = fmaf(hv.z, w2c[4 * q + 2], acc); acc = fmaf(hv.w, w2c[4 * q + 3], acc);
                }
                float g = ftanh(acc) + h1m[sk];
                float4 rm = rn4[j * 100 + m];
                xp0 = fmaf(rm.x, g, xp0); xp1 = fmaf(rm.y, g, xp1);
                xp2 = fmaf(rm.z, g, xp2); xp3 = fmaf(rm.w, g, xp3);
            }
        }
    }
    __syncthreads();
    const float inv = 1.0f / 200.0f;
    if (mh == 0 && c < EMB) {
        xyz[c] = xp0 * inv; xyz[EMB + c] = xp1 * inv;
        xyz[2 * EMB + c] = xp2 * inv; xyz[3 * EMB + c] = xp3 * inv;
    }
    __syncthreads();
    if (mh == 1 && c < EMB) {
        xyz[c] += xp0 * inv; xyz[EMB + c] += xp1 * inv;
        xyz[2 * EMB + c] += xp2 * inv; xyz[3 * EMB + c] += xp3 * inv;
    }
    __syncthreads();
    float* Dld = smem;
    for (int idx = tid; idx < DDIM; idx += 256) {
        int cc = idx >> 4, d = idx & 15;
        Dld[idx] = xyz[cc] * xyz[d] + xyz[EMB + cc] * xyz[EMB + d]
                 + xyz[2 * EMB + cc] * xyz[2 * EMB + d] + xyz[3 * EMB + cc] * xyz[3 * EMB + d];
    }
    __syncthreads();
    float* hA = smem + DDIM; float* hB = hA + FITH; float* h2 = hB + FITH; float* red = h2 + FITH;
    if (tid < FITH) {
        const float* W = fW0 + (size_t)t * DDIM * FITH;
        float acc = fb0[t * FITH + tid];
        for (int f = 0; f < DDIM; f += 4) {
            float4 dv = *(const float4*)(Dld + f);
            acc = fmaf(dv.x, W[f * FITH + tid], acc); acc = fmaf(dv.y, W[(f + 1) * FITH + tid], acc);
            acc = fmaf(dv.z, W[(f + 2) * FITH + tid], acc); acc = fmaf(dv.w, W[(f + 3) * FITH + tid], acc);
        }
        hA[tid] = ftanh(acc);
    }
    __syncthreads();
    if (tid < FITH) {
        const float* W = fW1 + t * FITH * FITH;
        float acc = fb1[t * FITH + tid];
        for (int f = 0; f < FITH; f += 4) {
            float4 hv = *(const float4*)(hA + f);
            acc = fmaf(hv.x, W[f * FITH + tid], acc); acc = fmaf(hv.y, W[(f + 1) * FITH + tid], acc);
            acc = fmaf(hv.z, W[(f + 2) * FITH + tid], acc); acc = fmaf(hv.w, W[(f + 3) * FITH + tid], acc);
        }
        hB[tid] = hA[tid] + ftanh(acc);
    }
    __syncthreads();
    if (tid < FITH) {
        const float* W = fW2 + t * FITH * FITH;
        float acc = fb2[t * FITH + tid];
        for (int f = 0; f < FITH; f += 4) {
            float4 hv = *(const float4*)(hB + f);
            acc = fmaf(hv.x, W[f * FITH + tid], acc); acc = fmaf(hv.y, W[(f + 1) * FITH + tid], acc);
            acc = fmaf(hv.z, W[(f + 2) * FITH + tid], acc); acc = fmaf(hv.w, W[(f + 3) * FITH + tid], acc);
        }
        h2[tid] = hB[tid] + ftanh(acc);
    }
    __syncthreads();
    float p = (tid < FITH) ? h2[tid] * fW3[t * FITH + tid] : 0.0f;
#pragma unroll
    for (int off = 32; off > 0; off >>= 1) p += __shfl_down(p, off, 64);
    if ((tid & 63) == 0) red[tid >> 6] = p;
    __syncthreads();
    if (tid == 0) out[4 + atom] = red[0] + red[1] + red[2] + red[3] + fb3[t] + eshift[t];
}

extern "C" void kernel_launch(void* const* d_in, const int* in_sizes, int n_in,
                              void* d_out, int out_size, void* d_ws, size_t ws_size,
                              hipStream_t stream) {
    const int*   itype   = (const int*)  d_in[1];
    const float* imagedr = (const float*)d_in[3];
    const float* davg    = (const float*)d_in[5];
    const float* dstd    = (const float*)d_in[6];
    const float* eW0     = (const float*)d_in[7];
    const float* eb0     = (const float*)d_in[8];
    const float* eW1     = (const float*)d_in[9];
    const float* eb1     = (const float*)d_in[10];
    const float* eW2     = (const float*)d_in[11];
    const float* eb2     = (const float*)d_in[12];
    const float* fW0     = (const float*)d_in[13];
    const float* fb0     = (const float*)d_in[14];
    const float* fW1     = (const float*)d_in[15];
    const float* fb1     = (const float*)d_in[16];
    const float* fW2     = (const float*)d_in[17];
    const float* fb2     = (const float*)d_in[18];
    const float* fW3     = (const float*)d_in[19];
    const float* fb3     = (const float*)d_in[20];
    const float* eshift  = (const float*)d_in[21];
    float* out = (float*)d_out;
    float* ws  = (float*)d_ws;

    if (ws_size >= WS_NEED) {
        unsigned short* u0 = (unsigned short*)((char*)ws + USH_BYTE);
        const int* wsi = (const int*)ws;
        prep_kernel<<<WT_BLK + TB_BLK + 1, 256, 0, stream>>>(
            fW0, fW1, fW2, fb0, fb1, fb2, fW3, fb3, eshift,
            davg, dstd, eW0, eb0, eW1, eb1, eW2, eb2, itype, ws, out);
        embed_kernel<<<NATOMS, 128, 0, stream>>>(itype, imagedr, davg, dstd, ws);
        fit_kernel<<<dim3(256, 2), 512, 0, stream>>>(
            u0 + D_U, u0 + W0T_U, u0 + W1T_U, u0 + W2T_U,
            ws + BIAS_F, ws + W3C_F, wsi, out);
        etot_kernel<<<BSZ, 256, 0, stream>>>(out);
    } else {
        dp_atom_kernel<<<NATOMS, 256, 0, stream>>>(itype, imagedr, davg, dstd,
            eW0, eb0, eW1, eb1, eW2, eb2,
            fW0, fb0, fW1, fb1, fW2, fb2, fW3, fb3, eshift, out);
        etot_kernel<<<BSZ, 256, 0, stream>>>(out);
    }
}

// Round 5
// 205.117 us; speedup vs baseline: 1.9487x; 1.1139x over previous
//
#include <hip/hip_runtime.h>
#include <math.h>

#define NT 2
#define BSZ 4
#define NAT 512
#define NATOMS 2048
#define NNEI 200
#define EMB 100
#define FITH 240
#define DDIM 1600
#define TBK 1024

// ---- ws layout ----
#define BIAS_F  16
#define W3C_F   (BIAS_F + 3 * 512)
#define PERM_I  2064
#define CNT_I   (PERM_I + 2048)
#define USH_BYTE 16512
#define TBL_U   0
#define W0T_U   409600
#define W1T_U   (W0T_U + 819200)
#define W2T_U   (W1T_U + 262144)
#define D_U     (W2T_U + 262144)
#define H0_U    (D_U + 3276800)
#define H1_U    (H0_U + 1048576)
#define USH_END (H1_U + 1048576)
#define WS_NEED ((size_t)USH_BYTE + (size_t)USH_END * 2)

#define N_W0 819200
#define N_W1 262144
#define N_W2 262144
#define N_B  1536
#define N_W3 512
#define N_EI 2048
#define N_WT (N_W0 + N_W1 + N_W2 + N_B + N_W3 + N_EI)
#define WT_BLK ((N_WT + 255) / 256)
#define TB_BLK 512

#define HPAD 264

typedef short s8v __attribute__((ext_vector_type(8)));
typedef float f4v __attribute__((ext_vector_type(4)));

__device__ __forceinline__ float ftanh(float x) {
    float ax = fabsf(x);
    float e = __expf(2.0f * ax);
    float t = 1.0f - __fdividef(2.0f, e + 1.0f);
    return (x < 0.0f) ? -t : t;
}
__device__ __forceinline__ unsigned short f2bf(float f) {
    unsigned u = __float_as_uint(f);
    u += 0x7FFFu + ((u >> 16) & 1u);
    return (unsigned short)(u >> 16);
}
__device__ __forceinline__ float bf2f(unsigned short s) {
    return __uint_as_float(((unsigned)s) << 16);
}
__device__ __forceinline__ float calc_S(float R) {
    float Rsafe = (R > 1e-5f) ? R : 1.0f;
    float u = (R - 0.5f) * (1.0f / 5.5f);
    float uu = u * u;
    float mid = (u * uu * (-6.0f * uu + 15.0f * u - 10.0f) + 1.0f) / Rsafe;
    float S = 0.0f;
    if (R > 0.0f && R < 0.5f)      S = 1.0f / Rsafe;
    else if (R > 0.5f && R < 6.0f) S = mid;
    return S;
}

// ---------- K1: prep = wtrans + table build + type-perm ----------
__global__ void __launch_bounds__(256) prep_kernel(
    const float* __restrict__ fW0, const float* __restrict__ fW1,
    const float* __restrict__ fW2,
    const float* __restrict__ fb0, const float* __restrict__ fb1,
    const float* __restrict__ fb2,
    const float* __restrict__ fW3, const float* __restrict__ fb3,
    const float* __restrict__ eshift,
    const float* __restrict__ davg, const float* __restrict__ dstd,
    const float* __restrict__ eW0, const float* __restrict__ eb0,
    const float* __restrict__ eW1, const float* __restrict__ eb1,
    const float* __restrict__ eW2, const float* __restrict__ eb2,
    const int* __restrict__ itype,
    float* __restrict__ ws, float* __restrict__ out)
{
    __shared__ float los[100], his[100];
    __shared__ float rng[2];
    __shared__ float h0s[8][25];
    __shared__ float h1s[8][50];
    __shared__ int pcnt, poff0, poff1;
    const int tid = threadIdx.x;
    int bxg = blockIdx.x;
    unsigned short* u0 = (unsigned short*)((char*)ws + USH_BYTE);

    if (bxg < WT_BLK) {
        int id = bxg * 256 + tid;
        if (id < N_W0) {
            int n = id / 1600, k = id - n * 1600;
            float v = 0.0f;
            if (n < 240)                  v = fW0[(size_t)k * 240 + n];
            else if (n >= 256 && n < 496) v = fW0[(size_t)(1600 + k) * 240 + (n - 256)];
            u0[W0T_U + id] = f2bf(v);
            return;
        }
        id -= N_W0;
        if (id < N_W1) {
            int n = id / 512, k = id - n * 512;
            float v = 0.0f;
            if (n < 240 && k < 240)       v = fW1[(size_t)k * 240 + n];
            else if (n >= 256 && n < 496 && k >= 256 && k < 496)
                                          v = fW1[(size_t)(240 + (k - 256)) * 240 + (n - 256)];
            u0[W1T_U + id] = f2bf(v);
            return;
        }
        id -= N_W1;
        if (id < N_W2) {
            int n = id / 512, k = id - n * 512;
            float v = 0.0f;
            if (n < 240 && k < 240)       v = fW2[(size_t)k * 240 + n];
            else if (n >= 256 && n < 496 && k >= 256 && k < 496)
                                          v = fW2[(size_t)(240 + (k - 256)) * 240 + (n - 256)];
            u0[W2T_U + id] = f2bf(v);
            return;
        }
        id -= N_W2;
        if (id < N_B) {
            int l = id / 512, n = id - l * 512;
            const float* fb = (l == 0) ? fb0 : (l == 1) ? fb1 : fb2;
            float v = 0.0f;
            if (n < 240)                  v = fb[n];
            else if (n >= 256 && n < 496) v = fb[240 + (n - 256)];
            ws[BIAS_F + l * 512 + n] = v;
            return;
        }
        id -= N_B;
        if (id < N_W3) {
            int n = id;
            float v = 0.0f;
            if (n < 240)                  v = fW3[n];
            else if (n >= 256 && n < 496) v = fW3[240 + (n - 256)];
            ws[W3C_F + n] = v;
            return;
        }
        id -= N_W3;
        if (id < N_EI) {
            int t = itype[id & (NAT - 1)];
            out[4 + id] = fb3[t] + eshift[t];
        }
        return;
    }
    bxg -= WT_BLK;
    if (bxg < TB_BLK) {
        const int nid = bxg >> 7;
        const int kb  = (bxg & 127) * 8;
        const int t = nid >> 1, j = nid & 1;
        if (tid < 100) {
            int m = j * 100 + tid;
            float av = davg[(t * NNEI + m) * 4];
            float sd = dstd[(t * NNEI + m) * 4];
            float inv = __fdividef(1.0f, sd);
            float a = (0.0f - av) * inv;
            float b = (2.0f - av) * inv;
            los[tid] = fminf(a, b);
            his[tid] = fmaxf(a, b);
        }
        __syncthreads();
        if (tid == 0) {
            float lo = los[0], hi = his[0];
            for (int i = 1; i < 100; ++i) { lo = fminf(lo, los[i]); hi = fmaxf(hi, his[i]); }
            rng[0] = lo; rng[1] = hi - lo;
            if (kb == 0) {
                ws[nid * 2] = lo;
                ws[nid * 2 + 1] = (float)(TBK - 1) / (hi - lo);
            }
        }
        __syncthreads();
        const float smin = rng[0], span = rng[1];
        const float* W0 = eW0 + nid * 25;
        const float* B0 = eb0 + nid * 25;
        if (tid < 200) {
            int q = tid / 25, a = tid % 25;
            float s = smin + span * ((float)(kb + q) * (1.0f / (TBK - 1)));
            h0s[q][a] = ftanh(fmaf(s, W0[a], B0[a]));
        }
        __syncthreads();
        const float* W1 = eW1 + nid * 1250;
        const float* B1 = eb1 + nid * 50;
        for (int idx = tid; idx < 400; idx += 256) {
            int q = idx / 50, cc = idx % 50;
            float acc = B1[cc];
#pragma unroll
            for (int a = 0; a < 25; ++a) acc = fmaf(h0s[q][a], W1[a * 50 + cc], acc);
            h1s[q][cc] = ftanh(acc) + h0s[q][(cc < 25) ? cc : cc - 25];
        }
        __syncthreads();
        const float* W2 = eW2 + nid * 5000;
        const float* B2 = eb2 + nid * 100;
        unsigned short* tblu = u0 + TBL_U;
        for (int idx = tid; idx < 800; idx += 256) {
            int q = idx / 100, c = idx % 100;
            float acc = B2[c];
#pragma unroll
            for (int a = 0; a < 50; ++a) acc = fmaf(h1s[q][a], W2[a * 100 + c], acc);
            float g = ftanh(acc) + h1s[q][(c < 50) ? c : c - 50];
            tblu[(size_t)(nid * TBK + kb + q) * 100 + c] = f2bf(g);
        }
        return;
    }
    if (tid == 0) { pcnt = 0; poff0 = 0; poff1 = 0; }
    __syncthreads();
    int* wsi = (int*)ws;
    int local0 = 0;
    for (int i = tid; i < NATOMS; i += 256) local0 += (itype[i & (NAT - 1)] == 0);
    atomicAdd(&pcnt, local0);
    __syncthreads();
    const int c0 = pcnt;
    for (int i = tid; i < NATOMS; i += 256) {
        int t = itype[i & (NAT - 1)];
        int pos = (t == 0) ? atomicAdd(&poff0, 1) : (c0 + atomicAdd(&poff1, 1));
        wsi[PERM_I + pos] = i;
    }
    if (tid == 0) { wsi[CNT_I] = c0; wsi[CNT_I + 1] = NATOMS - c0; }
}

// ---------- K2: embed (table interp) -> D bf16 [2048][1600] (round-0 proven) ----------
__global__ void __launch_bounds__(128) embed_kernel(
    const int* __restrict__ itype, const float* __restrict__ imagedr,
    const float* __restrict__ davg, const float* __restrict__ dstd,
    float* __restrict__ ws)
{
    __shared__ __align__(16) float4 srn[NNEI];
    __shared__ float sx[NNEI];
    __shared__ float part[2][400];
    const int atom = blockIdx.x;
    const int n = atom & (NAT - 1);
    const int tid = threadIdx.x;
    const int t = itype[n];
    unsigned short* u0 = (unsigned short*)((char*)ws + USH_BYTE);

    const float sm0 = ws[(t * 2 + 0) * 2], sc0 = ws[(t * 2 + 0) * 2 + 1];
    const float sm1 = ws[(t * 2 + 1) * 2], sc1 = ws[(t * 2 + 1) * 2 + 1];

    for (int m = tid; m < NNEI; m += 128) {
        float4 dr = ((const float4*)imagedr)[(size_t)atom * NNEI + m];
        float R = dr.x;
        float S = calc_S(R);
        float Rsafe = (R > 1e-5f) ? R : 1.0f;
        float sr = (fabsf(R) > 1e-5f) ? (S / Rsafe) : 0.0f;
        float4 av = ((const float4*)davg)[t * NNEI + m];
        float4 sd = ((const float4*)dstd)[t * NNEI + m];
        float4 rv;
        rv.x = (S         - av.x) / sd.x;
        rv.y = (sr * dr.y - av.y) / sd.y;
        rv.z = (sr * dr.z - av.z) / sd.z;
        rv.w = (sr * dr.w - av.w) / sd.w;
        srn[m] = rv;
        float smin = (m >= 100) ? sm1 : sm0;
        float scal = (m >= 100) ? sc1 : sc0;
        sx[m] = fminf(fmaxf((rv.x - smin) * scal, 0.0f), (float)(TBK - 2) + 0.9999f);
    }
    __syncthreads();

    const int w = tid >> 6, lane = tid & 63;
    const unsigned short* T = u0 + TBL_U + (size_t)(t * 2 + w) * TBK * EMB;
    const bool hi = (lane < 36);
    float xA0 = 0, xA1 = 0, xA2 = 0, xA3 = 0;
    float xB0 = 0, xB1 = 0, xB2 = 0, xB3 = 0;
#pragma unroll 4
    for (int mi = 0; mi < 100; ++mi) {
        int m = w * 100 + mi;
        float4 rv = srn[m];
        float x = sx[m];
        int i = (int)x;
        float f = x - (float)i;
        const unsigned short* Tr = T + (size_t)i * EMB;
        float g0 = bf2f(Tr[lane]);
        float g1 = bf2f(Tr[EMB + lane]);
        float g = fmaf(f, g1 - g0, g0);
        xA0 = fmaf(rv.x, g, xA0); xA1 = fmaf(rv.y, g, xA1);
        xA2 = fmaf(rv.z, g, xA2); xA3 = fmaf(rv.w, g, xA3);
        if (hi) {
            float h0v = bf2f(Tr[64 + lane]);
            float h1v = bf2f(Tr[EMB + 64 + lane]);
            float g2 = fmaf(f, h1v - h0v, h0v);
            xB0 = fmaf(rv.x, g2, xB0); xB1 = fmaf(rv.y, g2, xB1);
            xB2 = fmaf(rv.z, g2, xB2); xB3 = fmaf(rv.w, g2, xB3);
        }
    }
    part[w][0 * 100 + lane] = xA0; part[w][1 * 100 + lane] = xA1;
    part[w][2 * 100 + lane] = xA2; part[w][3 * 100 + lane] = xA3;
    if (hi) {
        part[w][0 * 100 + 64 + lane] = xB0; part[w][1 * 100 + 64 + lane] = xB1;
        part[w][2 * 100 + 64 + lane] = xB2; part[w][3 * 100 + 64 + lane] = xB3;
    }
    __syncthreads();
    const float inv = 1.0f / 200.0f;
    for (int idx = tid; idx < 400; idx += 128)
        part[0][idx] = (part[0][idx] + part[1][idx]) * inv;
    __syncthreads();
    unsigned short* Drow = u0 + D_U + (size_t)atom * DDIM;
    const float* xt = part[0];
    for (int idx = tid; idx < DDIM; idx += 128) {
        int c = idx >> 4, d = idx & 15;
        float s = xt[c] * xt[d] + xt[100 + c] * xt[100 + d]
                + xt[200 + c] * xt[200 + d] + xt[300 + c] * xt[300 + d];
        Drow[idx] = f2bf(s);
    }
}

// ---------- K3: fused fitting net, 32 rows/block ----------
// Round-1 structure (simple inline loads, no manual pipeline). 32 rows/block
// halves #blocks -> halves total B-panel traffic through L2 (the round-1->4
// A/B showed duration tracks total traffic, not per-block latency).
// Single Hs buffer: layer-1 residual update is elementwise + barrier-separated,
// so it runs in place.
__global__ void __launch_bounds__(512) fit_kernel(
    const unsigned short* __restrict__ A,     // D [2048][1600]
    const unsigned short* __restrict__ W0T,   // [512][1600]
    const unsigned short* __restrict__ W1T,   // [512][512]
    const unsigned short* __restrict__ W2T,   // [512][512]
    const float* __restrict__ biases,         // [3][512]
    const float* __restrict__ w3c,            // [512]
    const int* __restrict__ wsi,
    float* __restrict__ out)
{
    __shared__ float lred[4][64][33];             // 2 groups x 16 vals, odd pad
    __shared__ unsigned short Hs[32 * HPAD];      // H (in-place across layers)
    __shared__ float red2[32][4];

    const int z = blockIdx.y;
    const int cnt = wsi[CNT_I + z];
    const int my = blockIdx.x;
    if (my * 32 >= cnt) return;
    const int base = z ? wsi[CNT_I] : 0;
    const int tid = threadIdx.x;
    const int w = tid >> 6, lane = tid & 63;
    const int mr = lane & 15, q = lane >> 4;
    const int wc = w & 3, h = w >> 2;             // col-tile, k-half
    const int n0 = z * 256 + wc * 64;
    const int m0 = my * 32;
    const int ar0 = wsi[PERM_I + base + min(m0 + mr, cnt - 1)];
    const int ar1 = wsi[PERM_I + base + min(m0 + 16 + mr, cnt - 1)];

    // ================= layer 0: K=1600, 2-way k-split =================
    f4v acc[2][4] = {{{0,0,0,0},{0,0,0,0},{0,0,0,0},{0,0,0,0}},
                     {{0,0,0,0},{0,0,0,0},{0,0,0,0},{0,0,0,0}}};
    {
        const unsigned short* Ap0 = A + (size_t)ar0 * DDIM + h * 800 + q * 8;
        const unsigned short* Ap1 = A + (size_t)ar1 * DDIM + h * 800 + q * 8;
        const unsigned short* Bp = W0T + (size_t)(n0 + mr) * DDIM + h * 800 + q * 8;
#pragma unroll 5
        for (int kt = 0; kt < 25; ++kt) {
            s8v av0 = *(const s8v*)(Ap0 + kt * 32);
            s8v av1 = *(const s8v*)(Ap1 + kt * 32);
            s8v b0 = *(const s8v*)(Bp + kt * 32);
            s8v b1 = *(const s8v*)(Bp + 16 * DDIM + kt * 32);
            s8v b2 = *(const s8v*)(Bp + 32 * DDIM + kt * 32);
            s8v b3 = *(const s8v*)(Bp + 48 * DDIM + kt * 32);
            acc[0][0] = __builtin_amdgcn_mfma_f32_16x16x32_bf16(av0, b0, acc[0][0], 0, 0, 0);
            acc[0][1] = __builtin_amdgcn_mfma_f32_16x16x32_bf16(av0, b1, acc[0][1], 0, 0, 0);
            acc[0][2] = __builtin_amdgcn_mfma_f32_16x16x32_bf16(av0, b2, acc[0][2], 0, 0, 0);
            acc[0][3] = __builtin_amdgcn_mfma_f32_16x16x32_bf16(av0, b3, acc[0][3], 0, 0, 0);
            acc[1][0] = __builtin_amdgcn_mfma_f32_16x16x32_bf16(av1, b0, acc[1][0], 0, 0, 0);
            acc[1][1] = __builtin_amdgcn_mfma_f32_16x16x32_bf16(av1, b1, acc[1][1], 0, 0, 0);
            acc[1][2] = __builtin_amdgcn_mfma_f32_16x16x32_bf16(av1, b2, acc[1][2], 0, 0, 0);
            acc[1][3] = __builtin_amdgcn_mfma_f32_16x16x32_bf16(av1, b3, acc[1][3], 0, 0, 0);
        }
    }
    // k-split reduce + bias + tanh -> Hs
    if (h == 1) {
#pragma unroll
        for (int g = 0; g < 2; ++g)
#pragma unroll
            for (int j = 0; j < 4; ++j)
#pragma unroll
                for (int r = 0; r < 4; ++r)
                    lred[wc][lane][g * 16 + j * 4 + r] = acc[g][j][r];
    }
    __syncthreads();
    if (h == 0) {
#pragma unroll
        for (int j = 0; j < 4; ++j) {
            const float bv = biases[n0 + j * 16 + mr];
            const int col = wc * 64 + j * 16 + mr;
#pragma unroll
            for (int g = 0; g < 2; ++g)
#pragma unroll
                for (int r = 0; r < 4; ++r) {
                    float s = acc[g][j][r] + lred[wc][lane][g * 16 + j * 4 + r] + bv;
                    int row = g * 16 + q * 4 + r;
                    Hs[row * HPAD + col] = f2bf(ftanh(s));
                }
        }
    }
    __syncthreads();

    // ================= layer 1: K=256, residual (in place) =================
    {
        const unsigned short* Bp = W1T + (size_t)(n0 + mr) * 512 + z * 256 + h * 128 + q * 8;
        f4v ac1[2][4] = {{{0,0,0,0},{0,0,0,0},{0,0,0,0},{0,0,0,0}},
                         {{0,0,0,0},{0,0,0,0},{0,0,0,0},{0,0,0,0}}};
#pragma unroll
        for (int kt = 0; kt < 4; ++kt) {
            s8v av0 = *(const s8v*)((const char*)Hs + (size_t)mr * (HPAD * 2) + h * 256 + q * 16 + kt * 64);
            s8v av1 = *(const s8v*)((const char*)Hs + (size_t)(16 + mr) * (HPAD * 2) + h * 256 + q * 16 + kt * 64);
            s8v b0 = *(const s8v*)(Bp + kt * 32);
            s8v b1 = *(const s8v*)(Bp + 16 * 512 + kt * 32);
            s8v b2 = *(const s8v*)(Bp + 32 * 512 + kt * 32);
            s8v b3 = *(const s8v*)(Bp + 48 * 512 + kt * 32);
            ac1[0][0] = __builtin_amdgcn_mfma_f32_16x16x32_bf16(av0, b0, ac1[0][0], 0, 0, 0);
            ac1[0][1] = __builtin_amdgcn_mfma_f32_16x16x32_bf16(av0, b1, ac1[0][1], 0, 0, 0);
            ac1[0][2] = __builtin_amdgcn_mfma_f32_16x16x32_bf16(av0, b2, ac1[0][2], 0, 0, 0);
            ac1[0][3] = __builtin_amdgcn_mfma_f32_16x16x32_bf16(av0, b3, ac1[0][3], 0, 0, 0);
            ac1[1][0] = __builtin_amdgcn_mfma_f32_16x16x32_bf16(av1, b0, ac1[1][0], 0, 0, 0);
            ac1[1][1] = __builtin_amdgcn_mfma_f32_16x16x32_bf16(av1, b1, ac1[1][1], 0, 0, 0);
            ac1[1][2] = __builtin_amdgcn_mfma_f32_16x16x32_bf16(av1, b2, ac1[1][2], 0, 0, 0);
            ac1[1][3] = __builtin_amdgcn_mfma_f32_16x16x32_bf16(av1, b3, ac1[1][3], 0, 0, 0);
        }
        if (h == 1) {
#pragma unroll
            for (int g = 0; g < 2; ++g)
#pragma unroll
                for (int j = 0; j < 4; ++j)
#pragma unroll
                    for (int r = 0; r < 4; ++r)
                        lred[wc][lane][g * 16 + j * 4 + r] = ac1[g][j][r];
        }
        __syncthreads();
        if (h == 0) {
#pragma unroll
            for (int j = 0; j < 4; ++j) {
                const float bv = biases[512 + n0 + j * 16 + mr];
                const int col = wc * 64 + j * 16 + mr;
#pragma unroll
                for (int g = 0; g < 2; ++g)
#pragma unroll
                    for (int r = 0; r < 4; ++r) {
                        float s = ac1[g][j][r] + lred[wc][lane][g * 16 + j * 4 + r] + bv;
                        int row = g * 16 + q * 4 + r;
                        float hv = bf2f(Hs[row * HPAD + col]) + ftanh(s);
                        Hs[row * HPAD + col] = f2bf(hv);
                    }
            }
        }
        __syncthreads();
    }

    // ================= layer 2 + w3 dot =================
    {
        const unsigned short* Bp = W2T + (size_t)(n0 + mr) * 512 + z * 256 + h * 128 + q * 8;
        f4v ac2[2][4] = {{{0,0,0,0},{0,0,0,0},{0,0,0,0},{0,0,0,0}},
                         {{0,0,0,0},{0,0,0,0},{0,0,0,0},{0,0,0,0}}};
#pragma unroll
        for (int kt = 0; kt < 4; ++kt) {
            s8v av0 = *(const s8v*)((const char*)Hs + (size_t)mr * (HPAD * 2) + h * 256 + q * 16 + kt * 64);
            s8v av1 = *(const s8v*)((const char*)Hs + (size_t)(16 + mr) * (HPAD * 2) + h * 256 + q * 16 + kt * 64);
            s8v b0 = *(const s8v*)(Bp + kt * 32);
            s8v b1 = *(const s8v*)(Bp + 16 * 512 + kt * 32);
            s8v b2 = *(const s8v*)(Bp + 32 * 512 + kt * 32);
            s8v b3 = *(const s8v*)(Bp + 48 * 512 + kt * 32);
            ac2[0][0] = __builtin_amdgcn_mfma_f32_16x16x32_bf16(av0, b0, ac2[0][0], 0, 0, 0);
            ac2[0][1] = __builtin_amdgcn_mfma_f32_16x16x32_bf16(av0, b1, ac2[0][1], 0, 0, 0);
            ac2[0][2] = __builtin_amdgcn_mfma_f32_16x16x32_bf16(av0, b2, ac2[0][2], 0, 0, 0);
            ac2[0][3] = __builtin_amdgcn_mfma_f32_16x16x32_bf16(av0, b3, ac2[0][3], 0, 0, 0);
            ac2[1][0] = __builtin_amdgcn_mfma_f32_16x16x32_bf16(av1, b0, ac2[1][0], 0, 0, 0);
            ac2[1][1] = __builtin_amdgcn_mfma_f32_16x16x32_bf16(av1, b1, ac2[1][1], 0, 0, 0);
            ac2[1][2] = __builtin_amdgcn_mfma_f32_16x16x32_bf16(av1, b2, ac2[1][2], 0, 0, 0);
            ac2[1][3] = __builtin_amdgcn_mfma_f32_16x16x32_bf16(av1, b3, ac2[1][3], 0, 0, 0);
        }
        if (h == 1) {
#pragma unroll
            for (int g = 0; g < 2; ++g)
#pragma unroll
                for (int j = 0; j < 4; ++j)
#pragma unroll
                    for (int r = 0; r < 4; ++r)
                        lred[wc][lane][g * 16 + j * 4 + r] = ac2[g][j][r];
        }
        __syncthreads();
        if (h == 0) {
            float pr[2][4] = {{0, 0, 0, 0}, {0, 0, 0, 0}};
#pragma unroll
            for (int j = 0; j < 4; ++j) {
                const int col = n0 + j * 16 + mr;
                const float bv = biases[1024 + col];
                const float wv = w3c[col];
                const int coll = wc * 64 + j * 16 + mr;
#pragma unroll
                for (int g = 0; g < 2; ++g)
#pragma unroll
                    for (int r = 0; r < 4; ++r) {
                        float s = ac2[g][j][r] + lred[wc][lane][g * 16 + j * 4 + r] + bv;
                        int row = g * 16 + q * 4 + r;
                        float hv = bf2f(Hs[row * HPAD + coll]) + ftanh(s);
                        pr[g][r] = fmaf(hv, wv, pr[g][r]);
                    }
            }
#pragma unroll
            for (int g = 0; g < 2; ++g)
#pragma unroll
                for (int r = 0; r < 4; ++r) {
                    float p = pr[g][r];
                    p += __shfl_xor(p, 1, 16);
                    p += __shfl_xor(p, 2, 16);
                    p += __shfl_xor(p, 4, 16);
                    p += __shfl_xor(p, 8, 16);
                    if (mr == 0) red2[g * 16 + q * 4 + r][wc] = p;
                }
        }
        __syncthreads();
        if (tid < 32 && m0 + tid < cnt) {
            const int orow = wsi[PERM_I + base + m0 + tid];
            out[4 + orow] += red2[tid][0] + red2[tid][1] + red2[tid][2] + red2[tid][3];
        }
    }
}

// ---------- K4: Etot over Ei ----------
__global__ void etot_kernel(float* __restrict__ out) {
    const int b = blockIdx.x;
    float s = 0.0f;
    for (int n = threadIdx.x; n < NAT; n += 256) s += out[4 + b * NAT + n];
#pragma unroll
    for (int off = 32; off > 0; off >>= 1) s += __shfl_down(s, off, 64);
    __shared__ float rr[4];
    if ((threadIdx.x & 63) == 0) rr[threadIdx.x >> 6] = s;
    __syncthreads();
    if (threadIdx.x == 0) out[b] = rr[0] + rr[1] + rr[2] + rr[3];
}

// ================= fallback (small ws): monolithic per-atom =================
__global__ void dp_atom_kernel(
    const int* __restrict__ itype, const float* __restrict__ imagedr,
    const float* __restrict__ davg, const float* __restrict__ dstd,
    const float* __restrict__ eW0, const float* __restrict__ eb0,
    const float* __restrict__ eW1, const float* __restrict__ eb1,
    const float* __restrict__ eW2, const float* __restrict__ eb2,
    const float* __restrict__ fW0, const float* __restrict__ fb0,
    const float* __restrict__ fW1, const float* __restrict__ fb1,
    const float* __restrict__ fW2, const float* __restrict__ fb2,
    const float* __restrict__ fW3, const float* __restrict__ fb3,
    const float* __restrict__ eshift, float* __restrict__ out)
{
    __shared__ __align__(16) float4 rn4[NNEI];
    __shared__ __align__(16) float  xyz[4 * EMB];
    __shared__ __align__(16) float  h0s[100 * 25];
    __shared__ __align__(16) float  smem[100 * 52];
    const int atom = blockIdx.x;
    const int n = atom & (NAT - 1);
    const int tid = threadIdx.x;
    const int t = itype[n];
    for (int m = tid; m < NNEI; m += 256) {
        float4 dr = ((const float4*)imagedr)[(size_t)atom * NNEI + m];
        float R = dr.x;
        float S = calc_S(R);
        float Rsafe = (R > 1e-5f) ? R : 1.0f;
        float sr = (fabsf(R) > 1e-5f) ? (S / Rsafe) : 0.0f;
        float4 av = ((const float4*)davg)[t * NNEI + m];
        float4 sd = ((const float4*)dstd)[t * NNEI + m];
        float4 rv;
        rv.x = (S - av.x) / sd.x; rv.y = (sr * dr.y - av.y) / sd.y;
        rv.z = (sr * dr.z - av.z) / sd.z; rv.w = (sr * dr.w - av.w) / sd.w;
        rn4[m] = rv;
    }
    const int c = tid & 127; const int mh = tid >> 7;
    float xp0 = 0, xp1 = 0, xp2 = 0, xp3 = 0;
    for (int j = 0; j < NT; ++j) {
        const int wb = t * NT + j;
        const float* W0 = eW0 + wb * 25; const float* B0 = eb0 + wb * 25;
        const float* W1 = eW1 + wb * 1250; const float* B1 = eb1 + wb * 50;
        const float* W2 = eW2 + wb * 5000; const float* B2 = eb2 + wb * 100;
        __syncthreads();
        for (int idx = tid; idx < 2500; idx += 256) {
            int m = idx / 25, a = idx - m * 25;
            h0s[idx] = ftanh(fmaf(rn4[j * 100 + m].x, W0[a], B0[a]));
        }
        __syncthreads();
        for (int idx = tid; idx < 5000; idx += 256) {
            int m = idx / 50, cc = idx - m * 50;
            const float* h0m = h0s + m * 25;
            float acc = B1[cc];
#pragma unroll
            for (int a = 0; a < 25; ++a) acc = fmaf(h0m[a], W1[a * 50 + cc], acc);
            smem[m * 52 + cc] = ftanh(acc) + h0m[(cc < 25) ? cc : cc - 25];
        }
        for (int idx = tid; idx < 200; idx += 256)
            smem[(idx >> 1) * 52 + 50 + (idx & 1)] = 0.0f;
        __syncthreads();
        if (c < EMB) {
            float w2c[52];
#pragma unroll
            for (int a = 0; a < 50; ++a) w2c[a] = W2[a * EMB + c];
            w2c[50] = 0; w2c[51] = 0;
            const float bc = B2[c];
            const int sk = (c < 50) ? c : c - 50;
            for (int i = 0; i < 50; ++i) {
                int m = mh * 50 + i;
                const float* h1m = smem + m * 52;
                float acc = bc;
#pragma unroll
                for (int q = 0; q < 13; ++q) {
                    float4 hv = ((const float4*)h1m)[q];
                    acc = fmaf(hv.x, w2c[4 * q], acc); acc = fmaf(hv.y, w2c[4 * q + 1], acc);
                    acc = fmaf(hv.z, w2c[4 * q + 2], acc); acc = fmaf(hv.w, w2c[4 * q + 3], acc);
                }
                float g = ftanh(acc) + h1m[sk];
                float4 rm = rn4[j * 100 + m];
                xp0 = fmaf(rm.x, g, xp0); xp1 = fmaf(rm.y, g, xp1);
                xp2 = fmaf(rm.z, g, xp2); xp3 = fmaf(rm.w, g, xp3);
            }
        }
    }
    __syncthreads();
    const float inv = 1.0f / 200.0f;
    if (mh == 0 && c < EMB) {
        xyz[c] = xp0 * inv; xyz[EMB + c] = xp1 * inv;
        xyz[2 * EMB + c] = xp2 * inv; xyz[3 * EMB + c] = xp3 * inv;
    }
    __syncthreads();
    if (mh == 1 && c < EMB) {
        xyz[c] += xp0 * inv; xyz[EMB + c] += xp1 * inv;
        xyz[2 * EMB + c] += xp2 * inv; xyz[3 * EMB + c] += xp3 * inv;
    }
    __syncthreads();
    float* Dld = smem;
    for (int idx = tid; idx < DDIM; idx += 256) {
        int cc = idx >> 4, d = idx & 15;
        Dld[idx] = xyz[cc] * xyz[d] + xyz[EMB + cc] * xyz[EMB + d]
                 + xyz[2 * EMB + cc] * xyz[2 * EMB + d] + xyz[3 * EMB + cc] * xyz[3 * EMB + d];
    }
    __syncthreads();
    float* hA = smem + DDIM; float* hB = hA + FITH; float* h2 = hB + FITH; float* red = h2 + FITH;
    if (tid < FITH) {
        const float* W = fW0 + (size_t)t * DDIM * FITH;
        float acc = fb0[t * FITH + tid];
        for (int f = 0; f < DDIM; f += 4) {
            float4 dv = *(const float4*)(Dld + f);
            acc = fmaf(dv.x, W[f * FITH + tid], acc); acc = fmaf(dv.y, W[(f + 1) * FITH + tid], acc);
            acc = fmaf(dv.z, W[(f + 2) * FITH + tid], acc); acc = fmaf(dv.w, W[(f + 3) * FITH + tid], acc);
        }
        hA[tid] = ftanh(acc);
    }
    __syncthreads();
    if (tid < FITH) {
        const float* W = fW1 + t * FITH * FITH;
        float acc = fb1[t * FITH + tid];
        for (int f = 0; f < FITH; f += 4) {
            float4 hv = *(const float4*)(hA + f);
            acc = fmaf(hv.x, W[f * FITH + tid], acc); acc = fmaf(hv.y, W[(f + 1) * FITH + tid], acc);
            acc = fmaf(hv.z, W[(f + 2) * FITH + tid], acc); acc = fmaf(hv.w, W[(f + 3) * FITH + tid], acc);
        }
        hB[tid] = hA[tid] + ftanh(acc);
    }
    __syncthreads();
    if (tid < FITH) {
        const float* W = fW2 + t * FITH * FITH;
        float acc = fb2[t * FITH + tid];
        for (int f = 0; f < FITH; f += 4) {
            float4 hv = *(const float4*)(hB + f);
            acc = fmaf(hv.x, W[f * FITH + tid], acc); acc = fmaf(hv.y, W[(f + 1) * FITH + tid], acc);
            acc = fmaf(hv.z, W[(f + 2) * FITH + tid], acc); acc = fmaf(hv.w, W[(f + 3) * FITH + tid], acc);
        }
        h2[tid] = hB[tid] + ftanh(acc);
    }
    __syncthreads();
    float p = (tid < FITH) ? h2[tid] * fW3[t * FITH + tid] : 0.0f;
#pragma unroll
    for (int off = 32; off > 0; off >>= 1) p += __shfl_down(p, off, 64);
    if ((tid & 63) == 0) red[tid >> 6] = p;
    __syncthreads();
    if (tid == 0) out[4 + atom] = red[0] + red[1] + red[2] + red[3] + fb3[t] + eshift[t];
}

extern "C" void kernel_launch(void* const* d_in, const int* in_sizes, int n_in,
                              void* d_out, int out_size, void* d_ws, size_t ws_size,
                              hipStream_t stream) {
    const int*   itype   = (const int*)  d_in[1];
    const float* imagedr = (const float*)d_in[3];
    const float* davg    = (const float*)d_in[5];
    const float* dstd    = (const float*)d_in[6];
    const float* eW0     = (const float*)d_in[7];
    const float* eb0     = (const float*)d_in[8];
    const float* eW1     = (const float*)d_in[9];
    const float* eb1     = (const float*)d_in[10];
    const float* eW2     = (const float*)d_in[11];
    const float* eb2     = (const float*)d_in[12];
    const float* fW0     = (const float*)d_in[13];
    const float* fb0     = (const float*)d_in[14];
    const float* fW1     = (const float*)d_in[15];
    const float* fb1     = (const float*)d_in[16];
    const float* fW2     = (const float*)d_in[17];
    const float* fb2     = (const float*)d_in[18];
    const float* fW3     = (const float*)d_in[19];
    const float* fb3     = (const float*)d_in[20];
    const float* eshift  = (const float*)d_in[21];
    float* out = (float*)d_out;
    float* ws  = (float*)d_ws;

    if (ws_size >= WS_NEED) {
        unsigned short* u0 = (unsigned short*)((char*)ws + USH_BYTE);
        const int* wsi = (const int*)ws;
        prep_kernel<<<WT_BLK + TB_BLK + 1, 256, 0, stream>>>(
            fW0, fW1, fW2, fb0, fb1, fb2, fW3, fb3, eshift,
            davg, dstd, eW0, eb0, eW1, eb1, eW2, eb2, itype, ws, out);
        embed_kernel<<<NATOMS, 128, 0, stream>>>(itype, imagedr, davg, dstd, ws);
        fit_kernel<<<dim3(64, 2), 512, 0, stream>>>(
            u0 + D_U, u0 + W0T_U, u0 + W1T_U, u0 + W2T_U,
            ws + BIAS_F, ws + W3C_F, wsi, out);
        etot_kernel<<<BSZ, 256, 0, stream>>>(out);
    } else {
        dp_atom_kernel<<<NATOMS, 256, 0, stream>>>(itype, imagedr, davg, dstd,
            eW0, eb0, eW1, eb1, eW2, eb2,
            fW0, fb0, fW1, fb1, fW2, fb2, fW3, fb3, eshift, out);
        etot_kernel<<<BSZ, 256, 0, stream>>>(out);
    }
}

// Round 6
// 179.870 us; speedup vs baseline: 2.2222x; 1.1404x over previous
//
#include <hip/hip_runtime.h>
#include <math.h>

#define NT 2
#define BSZ 4
#define NAT 512
#define NATOMS 2048
#define NNEI 200
#define EMB 100
#define FITH 240
#define DDIM 1600
#define TBK 1024

// ---- ws layout ----
// float region: [0..8) table ranges; [16..1552) concat biases; [1552..2064) w3c
// int   region: [2064..4128) perm (padded, 2064 slots); [4128..4132) counts
//               (c0, c1, c0p); [4132..6180) inverse perm
#define BIAS_F  16
#define W3C_F   (BIAS_F + 3 * 512)
#define PERM_I  2064
#define CNT_I   (PERM_I + 2064)
#define IPERM_I (CNT_I + 4)
#define USH_BYTE 24832
// ushort region (fragment-packed operands):
#define TBL_U   0                          // 4*1024*100 = 409600
#define W0T_U   409600                     // [32 c16][50 kt][64 lane][8] = 819200
#define W1T_U   (W0T_U + 819200)           // [32][16][64][8] = 262144
#define W2T_U   (W1T_U + 262144)           // 262144
#define D_U     (W2T_U + 262144)           // [129 rb][50 kt][64][8] = 3302400
#define D_SZ    (129 * 50 * 512)
#define USH_END (D_U + D_SZ)
#define WS_NEED ((size_t)USH_BYTE + (size_t)USH_END * 2)   // ~10.1 MB

#define N_W0 819200
#define N_W1 262144
#define N_W2 262144
#define N_B  1536
#define N_W3 512
#define N_EI 2048
#define N_WT (N_W0 + N_W1 + N_W2 + N_B + N_W3 + N_EI)
#define WT_BLK ((N_WT + 255) / 256)
#define TB_BLK 512

#define HPAD 264

typedef short s8v __attribute__((ext_vector_type(8)));
typedef float f4v __attribute__((ext_vector_type(4)));

__device__ __forceinline__ float ftanh(float x) {
    float ax = fabsf(x);
    float e = __expf(2.0f * ax);
    float t = 1.0f - __fdividef(2.0f, e + 1.0f);
    return (x < 0.0f) ? -t : t;
}
__device__ __forceinline__ unsigned short f2bf(float f) {
    unsigned u = __float_as_uint(f);
    u += 0x7FFFu + ((u >> 16) & 1u);
    return (unsigned short)(u >> 16);
}
__device__ __forceinline__ float bf2f(unsigned short s) {
    return __uint_as_float(((unsigned)s) << 16);
}
__device__ __forceinline__ float calc_S(float R) {
    float Rsafe = (R > 1e-5f) ? R : 1.0f;
    float u = (R - 0.5f) * (1.0f / 5.5f);
    float uu = u * u;
    float mid = (u * uu * (-6.0f * uu + 15.0f * u - 10.0f) + 1.0f) / Rsafe;
    float S = 0.0f;
    if (R > 0.0f && R < 0.5f)      S = 1.0f / Rsafe;
    else if (R > 0.5f && R < 6.0f) S = mid;
    return S;
}

// ---------- K1: prep = wtrans (fragment-packed) + table build + type-perm ----------
__global__ void __launch_bounds__(256) prep_kernel(
    const float* __restrict__ fW0, const float* __restrict__ fW1,
    const float* __restrict__ fW2,
    const float* __restrict__ fb0, const float* __restrict__ fb1,
    const float* __restrict__ fb2,
    const float* __restrict__ fW3, const float* __restrict__ fb3,
    const float* __restrict__ eshift,
    const float* __restrict__ davg, const float* __restrict__ dstd,
    const float* __restrict__ eW0, const float* __restrict__ eb0,
    const float* __restrict__ eW1, const float* __restrict__ eb1,
    const float* __restrict__ eW2, const float* __restrict__ eb2,
    const int* __restrict__ itype,
    float* __restrict__ ws, float* __restrict__ out)
{
    __shared__ float los[100], his[100];
    __shared__ float rng[2];
    __shared__ float h0s[8][25];
    __shared__ float h1s[8][50];
    __shared__ int pcnt, poff0, poff1;
    const int tid = threadIdx.x;
    int bxg = blockIdx.x;
    unsigned short* u0 = (unsigned short*)((char*)ws + USH_BYTE);

    if (bxg < WT_BLK) {
        int id = bxg * 256 + tid;
        if (id < N_W0) {
            // fragment layout: id = ((c16*50 + kt)*64 + lane)*8 + e
            int e = id & 7, lane = (id >> 3) & 63;
            int rem = id >> 9;
            int kt = rem % 50, c16 = rem / 50;
            int n = c16 * 16 + (lane & 15);
            int k = kt * 32 + (lane >> 4) * 8 + e;
            float v = 0.0f;
            if (n < 240)                  v = fW0[(size_t)k * 240 + n];
            else if (n >= 256 && n < 496) v = fW0[(size_t)(1600 + k) * 240 + (n - 256)];
            u0[W0T_U + id] = f2bf(v);
            return;
        }
        id -= N_W0;
        if (id < N_W1) {
            int e = id & 7, lane = (id >> 3) & 63;
            int rem = id >> 9;
            int kt = rem & 15, c16 = rem >> 4;
            int n = c16 * 16 + (lane & 15);
            int k = kt * 32 + (lane >> 4) * 8 + e;
            float v = 0.0f;
            if (n < 240 && k < 240)       v = fW1[(size_t)k * 240 + n];
            else if (n >= 256 && n < 496 && k >= 256 && k < 496)
                                          v = fW1[(size_t)(240 + (k - 256)) * 240 + (n - 256)];
            u0[W1T_U + id] = f2bf(v);
            return;
        }
        id -= N_W1;
        if (id < N_W2) {
            int e = id & 7, lane = (id >> 3) & 63;
            int rem = id >> 9;
            int kt = rem & 15, c16 = rem >> 4;
            int n = c16 * 16 + (lane & 15);
            int k = kt * 32 + (lane >> 4) * 8 + e;
            float v = 0.0f;
            if (n < 240 && k < 240)       v = fW2[(size_t)k * 240 + n];
            else if (n >= 256 && n < 496 && k >= 256 && k < 496)
                                          v = fW2[(size_t)(240 + (k - 256)) * 240 + (n - 256)];
            u0[W2T_U + id] = f2bf(v);
            return;
        }
        id -= N_W2;
        if (id < N_B) {
            int l = id / 512, n = id - l * 512;
            const float* fb = (l == 0) ? fb0 : (l == 1) ? fb1 : fb2;
            float v = 0.0f;
            if (n < 240)                  v = fb[n];
            else if (n >= 256 && n < 496) v = fb[240 + (n - 256)];
            ws[BIAS_F + l * 512 + n] = v;
            return;
        }
        id -= N_B;
        if (id < N_W3) {
            int n = id;
            float v = 0.0f;
            if (n < 240)                  v = fW3[n];
            else if (n >= 256 && n < 496) v = fW3[240 + (n - 256)];
            ws[W3C_F + n] = v;
            return;
        }
        id -= N_W3;
        if (id < N_EI) {
            int t = itype[id & (NAT - 1)];
            out[4 + id] = fb3[t] + eshift[t];
        }
        return;
    }
    bxg -= WT_BLK;
    if (bxg < TB_BLK) {
        const int nid = bxg >> 7;
        const int kb  = (bxg & 127) * 8;
        const int t = nid >> 1, j = nid & 1;
        if (tid < 100) {
            int m = j * 100 + tid;
            float av = davg[(t * NNEI + m) * 4];
            float sd = dstd[(t * NNEI + m) * 4];
            float inv = __fdividef(1.0f, sd);
            float a = (0.0f - av) * inv;
            float b = (2.0f - av) * inv;
            los[tid] = fminf(a, b);
            his[tid] = fmaxf(a, b);
        }
        __syncthreads();
        if (tid == 0) {
            float lo = los[0], hi = his[0];
            for (int i = 1; i < 100; ++i) { lo = fminf(lo, los[i]); hi = fmaxf(hi, his[i]); }
            rng[0] = lo; rng[1] = hi - lo;
            if (kb == 0) {
                ws[nid * 2] = lo;
                ws[nid * 2 + 1] = (float)(TBK - 1) / (hi - lo);
            }
        }
        __syncthreads();
        const float smin = rng[0], span = rng[1];
        const float* W0 = eW0 + nid * 25;
        const float* B0 = eb0 + nid * 25;
        if (tid < 200) {
            int q = tid / 25, a = tid % 25;
            float s = smin + span * ((float)(kb + q) * (1.0f / (TBK - 1)));
            h0s[q][a] = ftanh(fmaf(s, W0[a], B0[a]));
        }
        __syncthreads();
        const float* W1 = eW1 + nid * 1250;
        const float* B1 = eb1 + nid * 50;
        for (int idx = tid; idx < 400; idx += 256) {
            int q = idx / 50, cc = idx % 50;
            float acc = B1[cc];
#pragma unroll
            for (int a = 0; a < 25; ++a) acc = fmaf(h0s[q][a], W1[a * 50 + cc], acc);
            h1s[q][cc] = ftanh(acc) + h0s[q][(cc < 25) ? cc : cc - 25];
        }
        __syncthreads();
        const float* W2 = eW2 + nid * 5000;
        const float* B2 = eb2 + nid * 100;
        unsigned short* tblu = u0 + TBL_U;
        for (int idx = tid; idx < 800; idx += 256) {
            int q = idx / 100, c = idx % 100;
            float acc = B2[c];
#pragma unroll
            for (int a = 0; a < 50; ++a) acc = fmaf(h1s[q][a], W2[a * 100 + c], acc);
            float g = ftanh(acc) + h1s[q][(c < 50) ? c : c - 50];
            tblu[(size_t)(nid * TBK + kb + q) * 100 + c] = f2bf(g);
        }
        return;
    }
    // ---- type partition perm (padded: type-1 starts at 16-aligned c0p) ----
    if (tid == 0) { pcnt = 0; poff0 = 0; poff1 = 0; }
    __syncthreads();
    int* wsi = (int*)ws;
    int local0 = 0;
    for (int i = tid; i < NATOMS; i += 256) local0 += (itype[i & (NAT - 1)] == 0);
    atomicAdd(&pcnt, local0);
    __syncthreads();
    const int c0 = pcnt;
    const int c0p = (c0 + 15) & ~15;
    for (int i = tid; i < NATOMS; i += 256) {
        int t = itype[i & (NAT - 1)];
        int pos = (t == 0) ? atomicAdd(&poff0, 1) : (c0p + atomicAdd(&poff1, 1));
        wsi[PERM_I + pos] = i;
        wsi[IPERM_I + i] = pos;
    }
    if (tid == 0) {
        wsi[CNT_I] = c0; wsi[CNT_I + 1] = NATOMS - c0; wsi[CNT_I + 2] = c0p;
    }
}

// ---------- K2: embed -> D bf16, fragment-packed at permuted position ----------
__global__ void __launch_bounds__(128) embed_kernel(
    const int* __restrict__ itype, const float* __restrict__ imagedr,
    const float* __restrict__ davg, const float* __restrict__ dstd,
    float* __restrict__ ws)
{
    __shared__ __align__(16) float4 srn[NNEI];
    __shared__ float sx[NNEI];
    __shared__ float part[2][400];
    const int atom = blockIdx.x;
    const int n = atom & (NAT - 1);
    const int tid = threadIdx.x;
    const int t = itype[n];
    unsigned short* u0 = (unsigned short*)((char*)ws + USH_BYTE);
    const int* wsi = (const int*)ws;

    const float sm0 = ws[(t * 2 + 0) * 2], sc0 = ws[(t * 2 + 0) * 2 + 1];
    const float sm1 = ws[(t * 2 + 1) * 2], sc1 = ws[(t * 2 + 1) * 2 + 1];

    for (int m = tid; m < NNEI; m += 128) {
        float4 dr = ((const float4*)imagedr)[(size_t)atom * NNEI + m];
        float R = dr.x;
        float S = calc_S(R);
        float Rsafe = (R > 1e-5f) ? R : 1.0f;
        float sr = (fabsf(R) > 1e-5f) ? (S / Rsafe) : 0.0f;
        float4 av = ((const float4*)davg)[t * NNEI + m];
        float4 sd = ((const float4*)dstd)[t * NNEI + m];
        float4 rv;
        rv.x = (S         - av.x) / sd.x;
        rv.y = (sr * dr.y - av.y) / sd.y;
        rv.z = (sr * dr.z - av.z) / sd.z;
        rv.w = (sr * dr.w - av.w) / sd.w;
        srn[m] = rv;
        float smin = (m >= 100) ? sm1 : sm0;
        float scal = (m >= 100) ? sc1 : sc0;
        sx[m] = fminf(fmaxf((rv.x - smin) * scal, 0.0f), (float)(TBK - 2) + 0.9999f);
    }
    __syncthreads();

    const int w = tid >> 6, lane = tid & 63;
    const unsigned short* T = u0 + TBL_U + (size_t)(t * 2 + w) * TBK * EMB;
    const bool hi = (lane < 36);
    float xA0 = 0, xA1 = 0, xA2 = 0, xA3 = 0;
    float xB0 = 0, xB1 = 0, xB2 = 0, xB3 = 0;
#pragma unroll 4
    for (int mi = 0; mi < 100; ++mi) {
        int m = w * 100 + mi;
        float4 rv = srn[m];
        float x = sx[m];
        int i = (int)x;
        float f = x - (float)i;
        const unsigned short* Tr = T + (size_t)i * EMB;
        float g0 = bf2f(Tr[lane]);
        float g1 = bf2f(Tr[EMB + lane]);
        float g = fmaf(f, g1 - g0, g0);
        xA0 = fmaf(rv.x, g, xA0); xA1 = fmaf(rv.y, g, xA1);
        xA2 = fmaf(rv.z, g, xA2); xA3 = fmaf(rv.w, g, xA3);
        if (hi) {
            float h0v = bf2f(Tr[64 + lane]);
            float h1v = bf2f(Tr[EMB + 64 + lane]);
            float g2 = fmaf(f, h1v - h0v, h0v);
            xB0 = fmaf(rv.x, g2, xB0); xB1 = fmaf(rv.y, g2, xB1);
            xB2 = fmaf(rv.z, g2, xB2); xB3 = fmaf(rv.w, g2, xB3);
        }
    }
    part[w][0 * 100 + lane] = xA0; part[w][1 * 100 + lane] = xA1;
    part[w][2 * 100 + lane] = xA2; part[w][3 * 100 + lane] = xA3;
    if (hi) {
        part[w][0 * 100 + 64 + lane] = xB0; part[w][1 * 100 + 64 + lane] = xB1;
        part[w][2 * 100 + 64 + lane] = xB2; part[w][3 * 100 + 64 + lane] = xB3;
    }
    __syncthreads();
    const float inv = 1.0f / 200.0f;
    for (int idx = tid; idx < 400; idx += 128)
        part[0][idx] = (part[0][idx] + part[1][idx]) * inv;
    __syncthreads();
    // D row -> fragment-packed position p = iperm[atom]
    const int p = wsi[IPERM_I + atom];
    const int rb = p >> 4, mrp = p & 15;
    unsigned short* Df = u0 + D_U;
    const float* xt = part[0];
    for (int k8 = tid; k8 < 200; k8 += 128) {
        int k = k8 * 8;
        int c = k >> 4, d0 = k & 15;
        int kt = k >> 5, q = (k >> 3) & 3;
        s8v pack;
#pragma unroll
        for (int e = 0; e < 8; ++e) {
            int d = d0 + e;
            float s = xt[c] * xt[d] + xt[100 + c] * xt[100 + d]
                    + xt[200 + c] * xt[200 + d] + xt[300 + c] * xt[300 + d];
            ((unsigned short*)&pack)[e] = f2bf(s);
        }
        *(s8v*)(Df + ((size_t)(rb * 50 + kt) * 64 + q * 16 + mrp) * 8) = pack;
    }
}

// ---------- K3: fused fitting net, fragment-packed coalesced loads ----------
// Round-1 geometry (16 rows x 256 cols, 8 waves = (wc col-tile, h k-half)),
// but every global load is now 64 consecutive 16B chunks (1 KB/wave-instr)
// instead of a 16-way row-gather.
__global__ void __launch_bounds__(512) fit_kernel(
    const unsigned short* __restrict__ Af,    // D frag  [129][50][64][8]
    const unsigned short* __restrict__ W0F,   // [32][50][64][8]
    const unsigned short* __restrict__ W1F,   // [32][16][64][8]
    const unsigned short* __restrict__ W2F,   // [32][16][64][8]
    const float* __restrict__ biases,         // [3][512]
    const float* __restrict__ w3c,            // [512]
    const int* __restrict__ wsi,
    float* __restrict__ out)
{
    __shared__ float lred[4][64][17];
    __shared__ unsigned short Hs0[16 * HPAD];
    __shared__ unsigned short Hs1[16 * HPAD];
    __shared__ float red2[16][4];

    const int z = blockIdx.y;
    const int cnt = wsi[CNT_I + z];
    const int my = blockIdx.x;
    if (my * 16 >= cnt) return;
    const int basep = z ? wsi[CNT_I + 2] : 0;       // 16-aligned partition base
    const int tid = threadIdx.x;
    const int w = tid >> 6, lane = tid & 63;
    const int mr = lane & 15, q = lane >> 4;
    const int wc = w & 3, h = w >> 2;
    const int n0 = z * 256 + wc * 64;
    const int m0 = my * 16;
    const int rb = (basep >> 4) + my;
    const int c16b = z * 16 + wc * 4;               // first col-block of this wave

    // ================= layer 0: K=1600, 2-way k-split =================
    f4v a0 = {0,0,0,0}, a1 = {0,0,0,0}, a2 = {0,0,0,0}, a3 = {0,0,0,0};
    {
        const unsigned short* Ap = Af  + ((size_t)(rb * 50 + h * 25) * 64 + lane) * 8;
        const unsigned short* Bp = W0F + ((size_t)(c16b * 50 + h * 25) * 64 + lane) * 8;
#pragma unroll 5
        for (int kt = 0; kt < 25; ++kt) {
            s8v av = *(const s8v*)(Ap + kt * 512);
            s8v b0 = *(const s8v*)(Bp + kt * 512);
            s8v b1 = *(const s8v*)(Bp + 25600 + kt * 512);
            s8v b2 = *(const s8v*)(Bp + 51200 + kt * 512);
            s8v b3 = *(const s8v*)(Bp + 76800 + kt * 512);
            a0 = __builtin_amdgcn_mfma_f32_16x16x32_bf16(av, b0, a0, 0, 0, 0);
            a1 = __builtin_amdgcn_mfma_f32_16x16x32_bf16(av, b1, a1, 0, 0, 0);
            a2 = __builtin_amdgcn_mfma_f32_16x16x32_bf16(av, b2, a2, 0, 0, 0);
            a3 = __builtin_amdgcn_mfma_f32_16x16x32_bf16(av, b3, a3, 0, 0, 0);
        }
    }
    if (h == 1) {
#pragma unroll
        for (int r = 0; r < 4; ++r) {
            lred[wc][lane][r]      = a0[r];
            lred[wc][lane][4 + r]  = a1[r];
            lred[wc][lane][8 + r]  = a2[r];
            lred[wc][lane][12 + r] = a3[r];
        }
    }
    __syncthreads();
    if (h == 0) {
#pragma unroll
        for (int j = 0; j < 4; ++j) {
            const float bv = biases[n0 + j * 16 + mr];
            f4v* ap = (j == 0) ? &a0 : (j == 1) ? &a1 : (j == 2) ? &a2 : &a3;
            const int col = wc * 64 + j * 16 + mr;
#pragma unroll
            for (int r = 0; r < 4; ++r) {
                float s = (*ap)[r] + lred[wc][lane][j * 4 + r] + bv;
                int row = q * 4 + r;
                Hs0[row * HPAD + col] = f2bf(ftanh(s));
            }
        }
    }
    __syncthreads();

    // ================= layer 1: K=256, residual =================
    {
        const unsigned short* Bp = W1F + ((size_t)(c16b * 16 + z * 8 + h * 4) * 64 + lane) * 8;
        f4v ac[4] = {{0,0,0,0},{0,0,0,0},{0,0,0,0},{0,0,0,0}};
#pragma unroll
        for (int kt = 0; kt < 4; ++kt) {
            s8v av = *(const s8v*)((const char*)Hs0
                     + (size_t)mr * (HPAD * 2) + h * 256 + q * 16 + kt * 64);
            s8v b0 = *(const s8v*)(Bp + kt * 512);
            s8v b1 = *(const s8v*)(Bp + 8192 + kt * 512);
            s8v b2 = *(const s8v*)(Bp + 16384 + kt * 512);
            s8v b3 = *(const s8v*)(Bp + 24576 + kt * 512);
            ac[0] = __builtin_amdgcn_mfma_f32_16x16x32_bf16(av, b0, ac[0], 0, 0, 0);
            ac[1] = __builtin_amdgcn_mfma_f32_16x16x32_bf16(av, b1, ac[1], 0, 0, 0);
            ac[2] = __builtin_amdgcn_mfma_f32_16x16x32_bf16(av, b2, ac[2], 0, 0, 0);
            ac[3] = __builtin_amdgcn_mfma_f32_16x16x32_bf16(av, b3, ac[3], 0, 0, 0);
        }
        if (h == 1) {
#pragma unroll
            for (int j = 0; j < 4; ++j)
#pragma unroll
                for (int r = 0; r < 4; ++r) lred[wc][lane][j * 4 + r] = ac[j][r];
        }
        __syncthreads();
        if (h == 0) {
#pragma unroll
            for (int j = 0; j < 4; ++j) {
                const float bv = biases[512 + n0 + j * 16 + mr];
                const int col = wc * 64 + j * 16 + mr;
#pragma unroll
                for (int r = 0; r < 4; ++r) {
                    float s = ac[j][r] + lred[wc][lane][j * 4 + r] + bv;
                    int row = q * 4 + r;
                    float hv = bf2f(Hs0[row * HPAD + col]) + ftanh(s);
                    Hs1[row * HPAD + col] = f2bf(hv);
                }
            }
        }
        __syncthreads();
    }

    // ================= layer 2 + w3 dot =================
    {
        const unsigned short* Bp = W2F + ((size_t)(c16b * 16 + z * 8 + h * 4) * 64 + lane) * 8;
        f4v ac[4] = {{0,0,0,0},{0,0,0,0},{0,0,0,0},{0,0,0,0}};
#pragma unroll
        for (int kt = 0; kt < 4; ++kt) {
            s8v av = *(const s8v*)((const char*)Hs1
                     + (size_t)mr * (HPAD * 2) + h * 256 + q * 16 + kt * 64);
            s8v b0 = *(const s8v*)(Bp + kt * 512);
            s8v b1 = *(const s8v*)(Bp + 8192 + kt * 512);
            s8v b2 = *(const s8v*)(Bp + 16384 + kt * 512);
            s8v b3 = *(const s8v*)(Bp + 24576 + kt * 512);
            ac[0] = __builtin_amdgcn_mfma_f32_16x16x32_bf16(av, b0, ac[0], 0, 0, 0);
            ac[1] = __builtin_amdgcn_mfma_f32_16x16x32_bf16(av, b1, ac[1], 0, 0, 0);
            ac[2] = __builtin_amdgcn_mfma_f32_16x16x32_bf16(av, b2, ac[2], 0, 0, 0);
            ac[3] = __builtin_amdgcn_mfma_f32_16x16x32_bf16(av, b3, ac[3], 0, 0, 0);
        }
        if (h == 1) {
#pragma unroll
            for (int j = 0; j < 4; ++j)
#pragma unroll
                for (int r = 0; r < 4; ++r) lred[wc][lane][j * 4 + r] = ac[j][r];
        }
        __syncthreads();
        if (h == 0) {
            float pr[4] = {0, 0, 0, 0};
#pragma unroll
            for (int j = 0; j < 4; ++j) {
                const int col = n0 + j * 16 + mr;
                const float bv = biases[1024 + col];
                const float wv = w3c[col];
                const int coll = wc * 64 + j * 16 + mr;
#pragma unroll
                for (int r = 0; r < 4; ++r) {
                    float s = ac[j][r] + lred[wc][lane][j * 4 + r] + bv;
                    int row = q * 4 + r;
                    float hv = bf2f(Hs1[row * HPAD + coll]) + ftanh(s);
                    pr[r] = fmaf(hv, wv, pr[r]);
                }
            }
#pragma unroll
            for (int r = 0; r < 4; ++r) {
                float p = pr[r];
                p += __shfl_xor(p, 1, 16);
                p += __shfl_xor(p, 2, 16);
                p += __shfl_xor(p, 4, 16);
                p += __shfl_xor(p, 8, 16);
                if (mr == 0) red2[q * 4 + r][wc] = p;
            }
        }
        __syncthreads();
        if (tid < 16 && m0 + tid < cnt) {
            const int orow = wsi[PERM_I + basep + m0 + tid];
            out[4 + orow] += red2[tid][0] + red2[tid][1] + red2[tid][2] + red2[tid][3];
        }
    }
}

// ---------- K4: Etot over Ei ----------
__global__ void etot_kernel(float* __restrict__ out) {
    const int b = blockIdx.x;
    float s = 0.0f;
    for (int n = threadIdx.x; n < NAT; n += 256) s += out[4 + b * NAT + n];
#pragma unroll
    for (int off = 32; off > 0; off >>= 1) s += __shfl_down(s, off, 64);
    __shared__ float rr[4];
    if ((threadIdx.x & 63) == 0) rr[threadIdx.x >> 6] = s;
    __syncthreads();
    if (threadIdx.x == 0) out[b] = rr[0] + rr[1] + rr[2] + rr[3];
}

// ================= fallback (small ws): monolithic per-atom =================
__global__ void dp_atom_kernel(
    const int* __restrict__ itype, const float* __restrict__ imagedr,
    const float* __restrict__ davg, const float* __restrict__ dstd,
    const float* __restrict__ eW0, const float* __restrict__ eb0,
    const float* __restrict__ eW1, const float* __restrict__ eb1,
    const float* __restrict__ eW2, const float* __restrict__ eb2,
    const float* __restrict__ fW0, const float* __restrict__ fb0,
    const float* __restrict__ fW1, const float* __restrict__ fb1,
    const float* __restrict__ fW2, const float* __restrict__ fb2,
    const float* __restrict__ fW3, const float* __restrict__ fb3,
    const float* __restrict__ eshift, float* __restrict__ out)
{
    __shared__ __align__(16) float4 rn4[NNEI];
    __shared__ __align__(16) float  xyz[4 * EMB];
    __shared__ __align__(16) float  h0s[100 * 25];
    __shared__ __align__(16) float  smem[100 * 52];
    const int atom = blockIdx.x;
    const int n = atom & (NAT - 1);
    const int tid = threadIdx.x;
    const int t = itype[n];
    for (int m = tid; m < NNEI; m += 256) {
        float4 dr = ((const float4*)imagedr)[(size_t)atom * NNEI + m];
        float R = dr.x;
        float S = calc_S(R);
        float Rsafe = (R > 1e-5f) ? R : 1.0f;
        float sr = (fabsf(R) > 1e-5f) ? (S / Rsafe) : 0.0f;
        float4 av = ((const float4*)davg)[t * NNEI + m];
        float4 sd = ((const float4*)dstd)[t * NNEI + m];
        float4 rv;
        rv.x = (S - av.x) / sd.x; rv.y = (sr * dr.y - av.y) / sd.y;
        rv.z = (sr * dr.z - av.z) / sd.z; rv.w = (sr * dr.w - av.w) / sd.w;
        rn4[m] = rv;
    }
    const int c = tid & 127; const int mh = tid >> 7;
    float xp0 = 0, xp1 = 0, xp2 = 0, xp3 = 0;
    for (int j = 0; j < NT; ++j) {
        const int wb = t * NT + j;
        const float* W0 = eW0 + wb * 25; const float* B0 = eb0 + wb * 25;
        const float* W1 = eW1 + wb * 1250; const float* B1 = eb1 + wb * 50;
        const float* W2 = eW2 + wb * 5000; const float* B2 = eb2 + wb * 100;
        __syncthreads();
        for (int idx = tid; idx < 2500; idx += 256) {
            int m = idx / 25, a = idx - m * 25;
            h0s[idx] = ftanh(fmaf(rn4[j * 100 + m].x, W0[a], B0[a]));
        }
        __syncthreads();
        for (int idx = tid; idx < 5000; idx += 256) {
            int m = idx / 50, cc = idx - m * 50;
            const float* h0m = h0s + m * 25;
            float acc = B1[cc];
#pragma unroll
            for (int a = 0; a < 25; ++a) acc = fmaf(h0m[a], W1[a * 50 + cc], acc);
            smem[m * 52 + cc] = ftanh(acc) + h0m[(cc < 25) ? cc : cc - 25];
        }
        for (int idx = tid; idx < 200; idx += 256)
            smem[(idx >> 1) * 52 + 50 + (idx & 1)] = 0.0f;
        __syncthreads();
        if (c < EMB) {
            float w2c[52];
#pragma unroll
            for (int a = 0; a < 50; ++a) w2c[a] = W2[a * EMB + c];
            w2c[50] = 0; w2c[51] = 0;
            const float bc = B2[c];
            const int sk = (c < 50) ? c : c - 50;
            for (int i = 0; i < 50; ++i) {
                int m = mh * 50 + i;
                const float* h1m = smem + m * 52;
                float acc = bc;
#pragma unroll
                for (int q = 0; q < 13; ++q) {
                    float4 hv = ((const float4*)h1m)[q];
                    acc = fmaf(hv.x, w2c[4 * q], acc); acc = fmaf(hv.y, w2c[4 * q + 1], acc);
                    acc = fmaf(hv.z, w2c[4 * q + 2], acc); acc = fmaf(hv.w, w2c[4 * q + 3], acc);
                }
                float g = ftanh(acc) + h1m[sk];
                float4 rm = rn4[j * 100 + m];
                xp0 = fmaf(rm.x, g, xp0); xp1 = fmaf(rm.y, g, xp1);
                xp2 = fmaf(rm.z, g, xp2); xp3 = fmaf(rm.w, g, xp3);
            }
        }
    }
    __syncthreads();
    const float inv = 1.0f / 200.0f;
    if (mh == 0 && c < EMB) {
        xyz[c] = xp0 * inv; xyz[EMB + c] = xp1 * inv;
        xyz[2 * EMB + c] = xp2 * inv; xyz[3 * EMB + c] = xp3 * inv;
    }
    __syncthreads();
    if (mh == 1 && c < EMB) {
        xyz[c] += xp0 * inv; xyz[EMB + c] += xp1 * inv;
        xyz[2 * EMB + c] += xp2 * inv; xyz[3 * EMB + c] += xp3 * inv;
    }
    __syncthreads();
    float* Dld = smem;
    for (int idx = tid; idx < DDIM; idx += 256) {
        int cc = idx >> 4, d = idx & 15;
        Dld[idx] = xyz[cc] * xyz[d] + xyz[EMB + cc] * xyz[EMB + d]
                 + xyz[2 * EMB + cc] * xyz[2 * EMB + d] + xyz[3 * EMB + cc] * xyz[3 * EMB + d];
    }
    __syncthreads();
    float* hA = smem + DDIM; float* hB = hA + FITH; float* h2 = hB + FITH; float* red = h2 + FITH;
    if (tid < FITH) {
        const float* W = fW0 + (size_t)t * DDIM * FITH;
        float acc = fb0[t * FITH + tid];
        for (int f = 0; f < DDIM; f += 4) {
            float4 dv = *(const float4*)(Dld + f);
            acc = fmaf(dv.x, W[f * FITH + tid], acc); acc = fmaf(dv.y, W[(f + 1) * FITH + tid], acc);
            acc = fmaf(dv.z, W[(f + 2) * FITH + tid], acc); acc = fmaf(dv.w, W[(f + 3) * FITH + tid], acc);
        }
        hA[tid] = ftanh(acc);
    }
    __syncthreads();
    if (tid < FITH) {
        const float* W = fW1 + t * FITH * FITH;
        float acc = fb1[t * FITH + tid];
        for (int f = 0; f < FITH; f += 4) {
            float4 hv = *(const float4*)(hA + f);
            acc = fmaf(hv.x, W[f * FITH + tid], acc); acc = fmaf(hv.y, W[(f + 1) * FITH + tid], acc);
            acc = fmaf(hv.z, W[(f + 2) * FITH + tid], acc); acc = fmaf(hv.w, W[(f + 3) * FITH + tid], acc);
        }
        hB[tid] = hA[tid] + ftanh(acc);
    }
    __syncthreads();
    if (tid < FITH) {
        const float* W = fW2 + t * FITH * FITH;
        float acc = fb2[t * FITH + tid];
        for (int f = 0; f < FITH; f += 4) {
            float4 hv = *(const float4*)(hB + f);
            acc = fmaf(hv.x, W[f * FITH + tid], acc); acc = fmaf(hv.y, W[(f + 1) * FITH + tid], acc);
            acc = fmaf(hv.z, W[(f + 2) * FITH + tid], acc); acc = fmaf(hv.w, W[(f + 3) * FITH + tid], acc);
        }
        h2[tid] = hB[tid] + ftanh(acc);
    }
    __syncthreads();
    float p = (tid < FITH) ? h2[tid] * fW3[t * FITH + tid] : 0.0f;
#pragma unroll
    for (int off = 32; off > 0; off >>= 1) p += __shfl_down(p, off, 64);
    if ((tid & 63) == 0) red[tid >> 6] = p;
    __syncthreads();
    if (tid == 0) out[4 + atom] = red[0] + red[1] + red[2] + red[3] + fb3[t] + eshift[t];
}

extern "C" void kernel_launch(void* const* d_in, const int* in_sizes, int n_in,
                              void* d_out, int out_size, void* d_ws, size_t ws_size,
                              hipStream_t stream) {
    const int*   itype   = (const int*)  d_in[1];
    const float* imagedr = (const float*)d_in[3];
    const float* davg    = (const float*)d_in[5];
    const float* dstd    = (const float*)d_in[6];
    const float* eW0     = (const float*)d_in[7];
    const float* eb0     = (const float*)d_in[8];
    const float* eW1     = (const float*)d_in[9];
    const float* eb1     = (const float*)d_in[10];
    const float* eW2     = (const float*)d_in[11];
    const float* eb2     = (const float*)d_in[12];
    const float* fW0     = (const float*)d_in[13];
    const float* fb0     = (const float*)d_in[14];
    const float* fW1     = (const float*)d_in[15];
    const float* fb1     = (const float*)d_in[16];
    const float* fW2     = (const float*)d_in[17];
    const float* fb2     = (const float*)d_in[18];
    const float* fW3     = (const float*)d_in[19];
    const float* fb3     = (const float*)d_in[20];
    const float* eshift  = (const float*)d_in[21];
    float* out = (float*)d_out;
    float* ws  = (float*)d_ws;

    if (ws_size >= WS_NEED) {
        unsigned short* u0 = (unsigned short*)((char*)ws + USH_BYTE);
        const int* wsi = (const int*)ws;
        prep_kernel<<<WT_BLK + TB_BLK + 1, 256, 0, stream>>>(
            fW0, fW1, fW2, fb0, fb1, fb2, fW3, fb3, eshift,
            davg, dstd, eW0, eb0, eW1, eb1, eW2, eb2, itype, ws, out);
        embed_kernel<<<NATOMS, 128, 0, stream>>>(itype, imagedr, davg, dstd, ws);
        fit_kernel<<<dim3(128, 2), 512, 0, stream>>>(
            u0 + D_U, u0 + W0T_U, u0 + W1T_U, u0 + W2T_U,
            ws + BIAS_F, ws + W3C_F, wsi, out);
        etot_kernel<<<BSZ, 256, 0, stream>>>(out);
    } else {
        dp_atom_kernel<<<NATOMS, 256, 0, stream>>>(itype, imagedr, davg, dstd,
            eW0, eb0, eW1, eb1, eW2, eb2,
            fW0, fb0, fW1, fb1, fW2, fb2, fW3, fb3, eshift, out);
        etot_kernel<<<BSZ, 256, 0, stream>>>(out);
    }
}

// Round 7
// 168.421 us; speedup vs baseline: 2.3733x; 1.0680x over previous
//
#include <hip/hip_runtime.h>
#include <math.h>

#define NT 2
#define BSZ 4
#define NAT 512
#define NATOMS 2048
#define NNEI 200
#define EMB 100
#define FITH 240
#define DDIM 1600
#define TBK 1024

// ---- ws layout ----
// float region: [0..8) table ranges; [16..1552) concat biases; [1552..2064) w3c
// int   region: [2064..4128) perm (padded); [4128..4132) counts (c0,c1,c0p);
//               [4132..6180) inverse perm; [6180] fit done-counter
#define BIAS_F  16
#define W3C_F   (BIAS_F + 3 * 512)
#define PERM_I  2064
#define CNT_I   (PERM_I + 2064)
#define IPERM_I (CNT_I + 4)
#define DONE_I  (IPERM_I + 2048)
#define USH_BYTE 24832
// ushort region (fragment-packed operands):
#define TBL_U   0                          // 4*1024*100 = 409600
#define W0T_U   409600                     // [32 c16][50 kt][64 lane][8] = 819200
#define W1T_U   (W0T_U + 819200)           // [32][16][64][8] = 262144
#define W2T_U   (W1T_U + 262144)           // 262144
#define D_U     (W2T_U + 262144)           // [129 rb][50 kt][64][8]
#define D_SZ    (129 * 50 * 512)
#define USH_END (D_U + D_SZ)
#define WS_NEED ((size_t)USH_BYTE + (size_t)USH_END * 2)   // ~10.1 MB

#define N_W0 819200
#define N_W1 262144
#define N_W2 262144
#define N_B  1536
#define N_W3 512
#define N_EI 2048
#define N_WT (N_W0 + N_W1 + N_W2 + N_B + N_W3 + N_EI)
#define WT_BLK ((N_WT + 255) / 256)
#define TB_BLK 512

#define HPAD 264
#define FIT_NBLK 256

typedef short s8v __attribute__((ext_vector_type(8)));
typedef float f4v __attribute__((ext_vector_type(4)));

__device__ __forceinline__ float ftanh(float x) {
    float ax = fabsf(x);
    float e = __expf(2.0f * ax);
    float t = 1.0f - __fdividef(2.0f, e + 1.0f);
    return (x < 0.0f) ? -t : t;
}
__device__ __forceinline__ unsigned short f2bf(float f) {
    unsigned u = __float_as_uint(f);
    u += 0x7FFFu + ((u >> 16) & 1u);
    return (unsigned short)(u >> 16);
}
__device__ __forceinline__ float bf2f(unsigned short s) {
    return __uint_as_float(((unsigned)s) << 16);
}
__device__ __forceinline__ float calc_S(float R) {
    float Rsafe = (R > 1e-5f) ? R : 1.0f;
    float u = (R - 0.5f) * (1.0f / 5.5f);
    float uu = u * u;
    float mid = (u * uu * (-6.0f * uu + 15.0f * u - 10.0f) + 1.0f) / Rsafe;
    float S = 0.0f;
    if (R > 0.0f && R < 0.5f)      S = 1.0f / Rsafe;
    else if (R > 0.5f && R < 6.0f) S = mid;
    return S;
}

// ---------- K1: prep = wtrans (fragment-packed) + table build + type-perm ----------
__global__ void __launch_bounds__(256) prep_kernel(
    const float* __restrict__ fW0, const float* __restrict__ fW1,
    const float* __restrict__ fW2,
    const float* __restrict__ fb0, const float* __restrict__ fb1,
    const float* __restrict__ fb2,
    const float* __restrict__ fW3, const float* __restrict__ fb3,
    const float* __restrict__ eshift,
    const float* __restrict__ davg, const float* __restrict__ dstd,
    const float* __restrict__ eW0, const float* __restrict__ eb0,
    const float* __restrict__ eW1, const float* __restrict__ eb1,
    const float* __restrict__ eW2, const float* __restrict__ eb2,
    const int* __restrict__ itype,
    float* __restrict__ ws, float* __restrict__ out)
{
    __shared__ float los[100], his[100];
    __shared__ float rng[2];
    __shared__ float h0s[8][25];
    __shared__ float h1s[8][50];
    __shared__ int pcnt, poff0, poff1;
    const int tid = threadIdx.x;
    int bxg = blockIdx.x;
    unsigned short* u0 = (unsigned short*)((char*)ws + USH_BYTE);

    if (bxg < WT_BLK) {
        int id = bxg * 256 + tid;
        if (id < N_W0) {
            // fragment layout: id = ((c16*50 + kt)*64 + lane)*8 + e
            int e = id & 7, lane = (id >> 3) & 63;
            int rem = id >> 9;
            int kt = rem % 50, c16 = rem / 50;
            int n = c16 * 16 + (lane & 15);
            int k = kt * 32 + (lane >> 4) * 8 + e;
            float v = 0.0f;
            if (n < 240)                  v = fW0[(size_t)k * 240 + n];
            else if (n >= 256 && n < 496) v = fW0[(size_t)(1600 + k) * 240 + (n - 256)];
            u0[W0T_U + id] = f2bf(v);
            return;
        }
        id -= N_W0;
        if (id < N_W1) {
            int e = id & 7, lane = (id >> 3) & 63;
            int rem = id >> 9;
            int kt = rem & 15, c16 = rem >> 4;
            int n = c16 * 16 + (lane & 15);
            int k = kt * 32 + (lane >> 4) * 8 + e;
            float v = 0.0f;
            if (n < 240 && k < 240)       v = fW1[(size_t)k * 240 + n];
            else if (n >= 256 && n < 496 && k >= 256 && k < 496)
                                          v = fW1[(size_t)(240 + (k - 256)) * 240 + (n - 256)];
            u0[W1T_U + id] = f2bf(v);
            return;
        }
        id -= N_W1;
        if (id < N_W2) {
            int e = id & 7, lane = (id >> 3) & 63;
            int rem = id >> 9;
            int kt = rem & 15, c16 = rem >> 4;
            int n = c16 * 16 + (lane & 15);
            int k = kt * 32 + (lane >> 4) * 8 + e;
            float v = 0.0f;
            if (n < 240 && k < 240)       v = fW2[(size_t)k * 240 + n];
            else if (n >= 256 && n < 496 && k >= 256 && k < 496)
                                          v = fW2[(size_t)(240 + (k - 256)) * 240 + (n - 256)];
            u0[W2T_U + id] = f2bf(v);
            return;
        }
        id -= N_W2;
        if (id < N_B) {
            int l = id / 512, n = id - l * 512;
            const float* fb = (l == 0) ? fb0 : (l == 1) ? fb1 : fb2;
            float v = 0.0f;
            if (n < 240)                  v = fb[n];
            else if (n >= 256 && n < 496) v = fb[240 + (n - 256)];
            ws[BIAS_F + l * 512 + n] = v;
            return;
        }
        id -= N_B;
        if (id < N_W3) {
            int n = id;
            float v = 0.0f;
            if (n < 240)                  v = fW3[n];
            else if (n >= 256 && n < 496) v = fW3[240 + (n - 256)];
            ws[W3C_F + n] = v;
            return;
        }
        id -= N_W3;
        if (id < N_EI) {
            int t = itype[id & (NAT - 1)];
            out[4 + id] = fb3[t] + eshift[t];
        }
        return;
    }
    bxg -= WT_BLK;
    if (bxg < TB_BLK) {
        const int nid = bxg >> 7;
        const int kb  = (bxg & 127) * 8;
        const int t = nid >> 1, j = nid & 1;
        if (tid < 100) {
            int m = j * 100 + tid;
            float av = davg[(t * NNEI + m) * 4];
            float sd = dstd[(t * NNEI + m) * 4];
            float inv = __fdividef(1.0f, sd);
            float a = (0.0f - av) * inv;
            float b = (2.0f - av) * inv;
            los[tid] = fminf(a, b);
            his[tid] = fmaxf(a, b);
        }
        __syncthreads();
        if (tid == 0) {
            float lo = los[0], hi = his[0];
            for (int i = 1; i < 100; ++i) { lo = fminf(lo, los[i]); hi = fmaxf(hi, his[i]); }
            rng[0] = lo; rng[1] = hi - lo;
            if (kb == 0) {
                ws[nid * 2] = lo;
                ws[nid * 2 + 1] = (float)(TBK - 1) / (hi - lo);
            }
        }
        __syncthreads();
        const float smin = rng[0], span = rng[1];
        const float* W0 = eW0 + nid * 25;
        const float* B0 = eb0 + nid * 25;
        if (tid < 200) {
            int q = tid / 25, a = tid % 25;
            float s = smin + span * ((float)(kb + q) * (1.0f / (TBK - 1)));
            h0s[q][a] = ftanh(fmaf(s, W0[a], B0[a]));
        }
        __syncthreads();
        const float* W1 = eW1 + nid * 1250;
        const float* B1 = eb1 + nid * 50;
        for (int idx = tid; idx < 400; idx += 256) {
            int q = idx / 50, cc = idx % 50;
            float acc = B1[cc];
#pragma unroll
            for (int a = 0; a < 25; ++a) acc = fmaf(h0s[q][a], W1[a * 50 + cc], acc);
            h1s[q][cc] = ftanh(acc) + h0s[q][(cc < 25) ? cc : cc - 25];
        }
        __syncthreads();
        const float* W2 = eW2 + nid * 5000;
        const float* B2 = eb2 + nid * 100;
        unsigned short* tblu = u0 + TBL_U;
        for (int idx = tid; idx < 800; idx += 256) {
            int q = idx / 100, c = idx % 100;
            float acc = B2[c];
#pragma unroll
            for (int a = 0; a < 50; ++a) acc = fmaf(h1s[q][a], W2[a * 100 + c], acc);
            float g = ftanh(acc) + h1s[q][(c < 50) ? c : c - 50];
            tblu[(size_t)(nid * TBK + kb + q) * 100 + c] = f2bf(g);
        }
        return;
    }
    // ---- type partition perm (padded: type-1 starts at 16-aligned c0p) ----
    if (tid == 0) { pcnt = 0; poff0 = 0; poff1 = 0; }
    __syncthreads();
    int* wsi = (int*)ws;
    int local0 = 0;
    for (int i = tid; i < NATOMS; i += 256) local0 += (itype[i & (NAT - 1)] == 0);
    atomicAdd(&pcnt, local0);
    __syncthreads();
    const int c0 = pcnt;
    const int c0p = (c0 + 15) & ~15;
    for (int i = tid; i < NATOMS; i += 256) {
        int t = itype[i & (NAT - 1)];
        int pos = (t == 0) ? atomicAdd(&poff0, 1) : (c0p + atomicAdd(&poff1, 1));
        wsi[PERM_I + pos] = i;
        wsi[IPERM_I + i] = pos;
    }
    if (tid == 0) {
        wsi[CNT_I] = c0; wsi[CNT_I + 1] = NATOMS - c0; wsi[CNT_I + 2] = c0p;
        wsi[DONE_I] = 0;
    }
}

// ---------- K2: embed -> D bf16, fragment-packed; 4 waves split the gather chain ----------
__global__ void __launch_bounds__(256) embed_kernel(
    const int* __restrict__ itype, const float* __restrict__ imagedr,
    const float* __restrict__ davg, const float* __restrict__ dstd,
    float* __restrict__ ws)
{
    __shared__ __align__(16) float4 srn[NNEI];
    __shared__ float sx[NNEI];
    __shared__ float part[4][400];
    const int atom = blockIdx.x;
    const int n = atom & (NAT - 1);
    const int tid = threadIdx.x;
    const int t = itype[n];
    unsigned short* u0 = (unsigned short*)((char*)ws + USH_BYTE);
    const int* wsi = (const int*)ws;

    const float sm0 = ws[(t * 2 + 0) * 2], sc0 = ws[(t * 2 + 0) * 2 + 1];
    const float sm1 = ws[(t * 2 + 1) * 2], sc1 = ws[(t * 2 + 1) * 2 + 1];

    for (int m = tid; m < NNEI; m += 256) {
        float4 dr = ((const float4*)imagedr)[(size_t)atom * NNEI + m];
        float R = dr.x;
        float S = calc_S(R);
        float Rsafe = (R > 1e-5f) ? R : 1.0f;
        float sr = (fabsf(R) > 1e-5f) ? (S / Rsafe) : 0.0f;
        float4 av = ((const float4*)davg)[t * NNEI + m];
        float4 sd = ((const float4*)dstd)[t * NNEI + m];
        float4 rv;
        rv.x = (S         - av.x) / sd.x;
        rv.y = (sr * dr.y - av.y) / sd.y;
        rv.z = (sr * dr.z - av.z) / sd.z;
        rv.w = (sr * dr.w - av.w) / sd.w;
        srn[m] = rv;
        float smin = (m >= 100) ? sm1 : sm0;
        float scal = (m >= 100) ? sc1 : sc0;
        sx[m] = fminf(fmaxf((rv.x - smin) * scal, 0.0f), (float)(TBK - 2) + 0.9999f);
    }
    __syncthreads();

    const int v = tid >> 6, lane = tid & 63;
    const int w = v >> 1;                 // neighbor half (table id)
    const int seg = v & 1;                // mi segment (halves the serial chain)
    const unsigned short* T = u0 + TBL_U + (size_t)(t * 2 + w) * TBK * EMB;
    const bool hi = (lane < 36);
    float xA0 = 0, xA1 = 0, xA2 = 0, xA3 = 0;
    float xB0 = 0, xB1 = 0, xB2 = 0, xB3 = 0;
#pragma unroll 5
    for (int mi = seg * 50; mi < seg * 50 + 50; ++mi) {
        int m = w * 100 + mi;
        float4 rv = srn[m];
        float x = sx[m];
        int i = (int)x;
        float f = x - (float)i;
        const unsigned short* Tr = T + (size_t)i * EMB;
        float g0 = bf2f(Tr[lane]);
        float g1 = bf2f(Tr[EMB + lane]);
        float g = fmaf(f, g1 - g0, g0);
        xA0 = fmaf(rv.x, g, xA0); xA1 = fmaf(rv.y, g, xA1);
        xA2 = fmaf(rv.z, g, xA2); xA3 = fmaf(rv.w, g, xA3);
        if (hi) {
            float h0v = bf2f(Tr[64 + lane]);
            float h1v = bf2f(Tr[EMB + 64 + lane]);
            float g2 = fmaf(f, h1v - h0v, h0v);
            xB0 = fmaf(rv.x, g2, xB0); xB1 = fmaf(rv.y, g2, xB1);
            xB2 = fmaf(rv.z, g2, xB2); xB3 = fmaf(rv.w, g2, xB3);
        }
    }
    part[v][0 * 100 + lane] = xA0; part[v][1 * 100 + lane] = xA1;
    part[v][2 * 100 + lane] = xA2; part[v][3 * 100 + lane] = xA3;
    if (hi) {
        part[v][0 * 100 + 64 + lane] = xB0; part[v][1 * 100 + 64 + lane] = xB1;
        part[v][2 * 100 + 64 + lane] = xB2; part[v][3 * 100 + 64 + lane] = xB3;
    }
    __syncthreads();
    const float inv = 1.0f / 200.0f;
    for (int idx = tid; idx < 400; idx += 256)
        part[0][idx] = (part[0][idx] + part[1][idx] + part[2][idx] + part[3][idx]) * inv;
    __syncthreads();
    // D row -> fragment-packed position p = iperm[atom]
    const int p = wsi[IPERM_I + atom];
    const int rb = p >> 4, mrp = p & 15;
    unsigned short* Df = u0 + D_U;
    const float* xt = part[0];
    for (int k8 = tid; k8 < 200; k8 += 256) {
        int k = k8 * 8;
        int c = k >> 4, d0 = k & 15;
        int kt = k >> 5, q = (k >> 3) & 3;
        s8v pack;
#pragma unroll
        for (int e = 0; e < 8; ++e) {
            int d = d0 + e;
            float s = xt[c] * xt[d] + xt[100 + c] * xt[100 + d]
                    + xt[200 + c] * xt[200 + d] + xt[300 + c] * xt[300 + d];
            ((unsigned short*)&pack)[e] = f2bf(s);
        }
        *(s8v*)(Df + ((size_t)(rb * 50 + kt) * 64 + q * 16 + mrp) * 8) = pack;
    }
}

// ---------- K3: fused fitting net + Etot (last-block reduction) ----------
// launch_bounds(512,2): 1 block/CU (grid=256), 256-VGPR budget so the compiler
// can deeply pipeline the fully-unrolled coalesced K-loop.
__global__ void __launch_bounds__(512, 2) fit_kernel(
    const unsigned short* __restrict__ Af,    // D frag  [129][50][64][8]
    const unsigned short* __restrict__ W0F,   // [32][50][64][8]
    const unsigned short* __restrict__ W1F,   // [32][16][64][8]
    const unsigned short* __restrict__ W2F,   // [32][16][64][8]
    const float* __restrict__ biases,         // [3][512]
    const float* __restrict__ w3c,            // [512]
    int* __restrict__ wsi,
    float* __restrict__ out)
{
    __shared__ float lred[4][64][17];
    __shared__ unsigned short Hs0[16 * HPAD];
    __shared__ unsigned short Hs1[16 * HPAD];
    __shared__ float red2[16][4];
    __shared__ int lastFlag;
    __shared__ float er[8];

    const int z = blockIdx.y;
    const int cnt = wsi[CNT_I + z];
    const int my = blockIdx.x;
    const int tid = threadIdx.x;
    const bool work = (my * 16 < cnt);
    if (work) {
        const int basep = z ? wsi[CNT_I + 2] : 0;
        const int w = tid >> 6, lane = tid & 63;
        const int mr = lane & 15, q = lane >> 4;
        const int wc = w & 3, h = w >> 2;
        const int n0 = z * 256 + wc * 64;
        const int m0 = my * 16;
        const int rb = (basep >> 4) + my;
        const int c16b = z * 16 + wc * 4;

        // ================= layer 0: K=1600, 2-way k-split =================
        f4v a0 = {0,0,0,0}, a1 = {0,0,0,0}, a2 = {0,0,0,0}, a3 = {0,0,0,0};
        {
            const unsigned short* Ap = Af  + ((size_t)(rb * 50 + h * 25) * 64 + lane) * 8;
            const unsigned short* Bp = W0F + ((size_t)(c16b * 50 + h * 25) * 64 + lane) * 8;
#pragma unroll
            for (int kt = 0; kt < 25; ++kt) {
                s8v av = *(const s8v*)(Ap + kt * 512);
                s8v b0 = *(const s8v*)(Bp + kt * 512);
                s8v b1 = *(const s8v*)(Bp + 25600 + kt * 512);
                s8v b2 = *(const s8v*)(Bp + 51200 + kt * 512);
                s8v b3 = *(const s8v*)(Bp + 76800 + kt * 512);
                a0 = __builtin_amdgcn_mfma_f32_16x16x32_bf16(av, b0, a0, 0, 0, 0);
                a1 = __builtin_amdgcn_mfma_f32_16x16x32_bf16(av, b1, a1, 0, 0, 0);
                a2 = __builtin_amdgcn_mfma_f32_16x16x32_bf16(av, b2, a2, 0, 0, 0);
                a3 = __builtin_amdgcn_mfma_f32_16x16x32_bf16(av, b3, a3, 0, 0, 0);
            }
        }
        if (h == 1) {
#pragma unroll
            for (int r = 0; r < 4; ++r) {
                lred[wc][lane][r]      = a0[r];
                lred[wc][lane][4 + r]  = a1[r];
                lred[wc][lane][8 + r]  = a2[r];
                lred[wc][lane][12 + r] = a3[r];
            }
        }
        __syncthreads();
        if (h == 0) {
#pragma unroll
            for (int j = 0; j < 4; ++j) {
                const float bv = biases[n0 + j * 16 + mr];
                f4v* ap = (j == 0) ? &a0 : (j == 1) ? &a1 : (j == 2) ? &a2 : &a3;
                const int col = wc * 64 + j * 16 + mr;
#pragma unroll
                for (int r = 0; r < 4; ++r) {
                    float s = (*ap)[r] + lred[wc][lane][j * 4 + r] + bv;
                    int row = q * 4 + r;
                    Hs0[row * HPAD + col] = f2bf(ftanh(s));
                }
            }
        }
        __syncthreads();

        // ================= layer 1: K=256, residual =================
        {
            const unsigned short* Bp = W1F + ((size_t)(c16b * 16 + z * 8 + h * 4) * 64 + lane) * 8;
            f4v ac[4] = {{0,0,0,0},{0,0,0,0},{0,0,0,0},{0,0,0,0}};
#pragma unroll
            for (int kt = 0; kt < 4; ++kt) {
                s8v av = *(const s8v*)((const char*)Hs0
                         + (size_t)mr * (HPAD * 2) + h * 256 + q * 16 + kt * 64);
                s8v b0 = *(const s8v*)(Bp + kt * 512);
                s8v b1 = *(const s8v*)(Bp + 8192 + kt * 512);
                s8v b2 = *(const s8v*)(Bp + 16384 + kt * 512);
                s8v b3 = *(const s8v*)(Bp + 24576 + kt * 512);
                ac[0] = __builtin_amdgcn_mfma_f32_16x16x32_bf16(av, b0, ac[0], 0, 0, 0);
                ac[1] = __builtin_amdgcn_mfma_f32_16x16x32_bf16(av, b1, ac[1], 0, 0, 0);
                ac[2] = __builtin_amdgcn_mfma_f32_16x16x32_bf16(av, b2, ac[2], 0, 0, 0);
                ac[3] = __builtin_amdgcn_mfma_f32_16x16x32_bf16(av, b3, ac[3], 0, 0, 0);
            }
            if (h == 1) {
#pragma unroll
                for (int j = 0; j < 4; ++j)
#pragma unroll
                    for (int r = 0; r < 4; ++r) lred[wc][lane][j * 4 + r] = ac[j][r];
            }
            __syncthreads();
            if (h == 0) {
#pragma unroll
                for (int j = 0; j < 4; ++j) {
                    const float bv = biases[512 + n0 + j * 16 + mr];
                    const int col = wc * 64 + j * 16 + mr;
#pragma unroll
                    for (int r = 0; r < 4; ++r) {
                        float s = ac[j][r] + lred[wc][lane][j * 4 + r] + bv;
                        int row = q * 4 + r;
                        float hv = bf2f(Hs0[row * HPAD + col]) + ftanh(s);
                        Hs1[row * HPAD + col] = f2bf(hv);
                    }
                }
            }
            __syncthreads();
        }

        // ================= layer 2 + w3 dot =================
        {
            const unsigned short* Bp = W2F + ((size_t)(c16b * 16 + z * 8 + h * 4) * 64 + lane) * 8;
            f4v ac[4] = {{0,0,0,0},{0,0,0,0},{0,0,0,0},{0,0,0,0}};
#pragma unroll
            for (int kt = 0; kt < 4; ++kt) {
                s8v av = *(const s8v*)((const char*)Hs1
                         + (size_t)mr * (HPAD * 2) + h * 256 + q * 16 + kt * 64);
                s8v b0 = *(const s8v*)(Bp + kt * 512);
                s8v b1 = *(const s8v*)(Bp + 8192 + kt * 512);
                s8v b2 = *(const s8v*)(Bp + 16384 + kt * 512);
                s8v b3 = *(const s8v*)(Bp + 24576 + kt * 512);
                ac[0] = __builtin_amdgcn_mfma_f32_16x16x32_bf16(av, b0, ac[0], 0, 0, 0);
                ac[1] = __builtin_amdgcn_mfma_f32_16x16x32_bf16(av, b1, ac[1], 0, 0, 0);
                ac[2] = __builtin_amdgcn_mfma_f32_16x16x32_bf16(av, b2, ac[2], 0, 0, 0);
                ac[3] = __builtin_amdgcn_mfma_f32_16x16x32_bf16(av, b3, ac[3], 0, 0, 0);
            }
            if (h == 1) {
#pragma unroll
                for (int j = 0; j < 4; ++j)
#pragma unroll
                    for (int r = 0; r < 4; ++r) lred[wc][lane][j * 4 + r] = ac[j][r];
            }
            __syncthreads();
            if (h == 0) {
                float pr[4] = {0, 0, 0, 0};
#pragma unroll
                for (int j = 0; j < 4; ++j) {
                    const int col = n0 + j * 16 + mr;
                    const float bv = biases[1024 + col];
                    const float wv = w3c[col];
                    const int coll = wc * 64 + j * 16 + mr;
#pragma unroll
                    for (int r = 0; r < 4; ++r) {
                        float s = ac[j][r] + lred[wc][lane][j * 4 + r] + bv;
                        int row = q * 4 + r;
                        float hv = bf2f(Hs1[row * HPAD + coll]) + ftanh(s);
                        pr[r] = fmaf(hv, wv, pr[r]);
                    }
                }
#pragma unroll
                for (int r = 0; r < 4; ++r) {
                    float p = pr[r];
                    p += __shfl_xor(p, 1, 16);
                    p += __shfl_xor(p, 2, 16);
                    p += __shfl_xor(p, 4, 16);
                    p += __shfl_xor(p, 8, 16);
                    if (mr == 0) red2[q * 4 + r][wc] = p;
                }
            }
            __syncthreads();
            if (tid < 16 && m0 + tid < cnt) {
                const int orow = wsi[PERM_I + basep + m0 + tid];
                out[4 + orow] += red2[tid][0] + red2[tid][1] + red2[tid][2] + red2[tid][3];
            }
        }
    }

    // ---------- fused Etot: last finished block reduces ----------
    __syncthreads();
    if (tid == 0) {
        __threadfence();
        int prev = atomicAdd(&wsi[DONE_I], 1);
        lastFlag = (prev == FIT_NBLK - 1);
    }
    __syncthreads();
    if (lastFlag) {
        __threadfence();
        const int g = tid >> 7, l = tid & 127;
        float s = 0.0f;
        for (int nn = l; nn < NAT; nn += 128) s += out[4 + g * NAT + nn];
#pragma unroll
        for (int off = 32; off > 0; off >>= 1) s += __shfl_down(s, off, 64);
        if ((l & 63) == 0) er[g * 2 + (l >> 6)] = s;
        __syncthreads();
        if (tid < 4) out[tid] = er[tid * 2] + er[tid * 2 + 1];
    }
}

// ---------- etot (fallback path only) ----------
__global__ void etot_kernel(float* __restrict__ out) {
    const int b = blockIdx.x;
    float s = 0.0f;
    for (int n = threadIdx.x; n < NAT; n += 256) s += out[4 + b * NAT + n];
#pragma unroll
    for (int off = 32; off > 0; off >>= 1) s += __shfl_down(s, off, 64);
    __shared__ float rr[4];
    if ((threadIdx.x & 63) == 0) rr[threadIdx.x >> 6] = s;
    __syncthreads();
    if (threadIdx.x == 0) out[b] = rr[0] + rr[1] + rr[2] + rr[3];
}

// ================= fallback (small ws): monolithic per-atom =================
__global__ void dp_atom_kernel(
    const int* __restrict__ itype, const float* __restrict__ imagedr,
    const float* __restrict__ davg, const float* __restrict__ dstd,
    const float* __restrict__ eW0, const float* __restrict__ eb0,
    const float* __restrict__ eW1, const float* __restrict__ eb1,
    const float* __restrict__ eW2, const float* __restrict__ eb2,
    const float* __restrict__ fW0, const float* __restrict__ fb0,
    const float* __restrict__ fW1, const float* __restrict__ fb1,
    const float* __restrict__ fW2, const float* __restrict__ fb2,
    const float* __restrict__ fW3, const float* __restrict__ fb3,
    const float* __restrict__ eshift, float* __restrict__ out)
{
    __shared__ __align__(16) float4 rn4[NNEI];
    __shared__ __align__(16) float  xyz[4 * EMB];
    __shared__ __align__(16) float  h0s[100 * 25];
    __shared__ __align__(16) float  smem[100 * 52];
    const int atom = blockIdx.x;
    const int n = atom & (NAT - 1);
    const int tid = threadIdx.x;
    const int t = itype[n];
    for (int m = tid; m < NNEI; m += 256) {
        float4 dr = ((const float4*)imagedr)[(size_t)atom * NNEI + m];
        float R = dr.x;
        float S = calc_S(R);
        float Rsafe = (R > 1e-5f) ? R : 1.0f;
        float sr = (fabsf(R) > 1e-5f) ? (S / Rsafe) : 0.0f;
        float4 av = ((const float4*)davg)[t * NNEI + m];
        float4 sd = ((const float4*)dstd)[t * NNEI + m];
        float4 rv;
        rv.x = (S - av.x) / sd.x; rv.y = (sr * dr.y - av.y) / sd.y;
        rv.z = (sr * dr.z - av.z) / sd.z; rv.w = (sr * dr.w - av.w) / sd.w;
        rn4[m] = rv;
    }
    const int c = tid & 127; const int mh = tid >> 7;
    float xp0 = 0, xp1 = 0, xp2 = 0, xp3 = 0;
    for (int j = 0; j < NT; ++j) {
        const int wb = t * NT + j;
        const float* W0 = eW0 + wb * 25; const float* B0 = eb0 + wb * 25;
        const float* W1 = eW1 + wb * 1250; const float* B1 = eb1 + wb * 50;
        const float* W2 = eW2 + wb * 5000; const float* B2 = eb2 + wb * 100;
        __syncthreads();
        for (int idx = tid; idx < 2500; idx += 256) {
            int m = idx / 25, a = idx - m * 25;
            h0s[idx] = ftanh(fmaf(rn4[j * 100 + m].x, W0[a], B0[a]));
        }
        __syncthreads();
        for (int idx = tid; idx < 5000; idx += 256) {
            int m = idx / 50, cc = idx - m * 50;
            const float* h0m = h0s + m * 25;
            float acc = B1[cc];
#pragma unroll
            for (int a = 0; a < 25; ++a) acc = fmaf(h0m[a], W1[a * 50 + cc], acc);
            smem[m * 52 + cc] = ftanh(acc) + h0m[(cc < 25) ? cc : cc - 25];
        }
        for (int idx = tid; idx < 200; idx += 256)
            smem[(idx >> 1) * 52 + 50 + (idx & 1)] = 0.0f;
        __syncthreads();
        if (c < EMB) {
            float w2c[52];
#pragma unroll
            for (int a = 0; a < 50; ++a) w2c[a] = W2[a * EMB + c];
            w2c[50] = 0; w2c[51] = 0;
            const float bc = B2[c];
            const int sk = (c < 50) ? c : c - 50;
            for (int i = 0; i < 50; ++i) {
                int m = mh * 50 + i;
                const float* h1m = smem + m * 52;
                float acc = bc;
#pragma unroll
                for (int q = 0; q < 13; ++q) {
                    float4 hv = ((const float4*)h1m)[q];
                    acc = fmaf(hv.x, w2c[4 * q], acc); acc = fmaf(hv.y, w2c[4 * q + 1], acc);
                    acc = fmaf(hv.z, w2c[4 * q + 2], acc); acc = fmaf(hv.w, w2c[4 * q + 3], acc);
                }
                float g = ftanh(acc) + h1m[sk];
                float4 rm = rn4[j * 100 + m];
                xp0 = fmaf(rm.x, g, xp0); xp1 = fmaf(rm.y, g, xp1);
                xp2 = fmaf(rm.z, g, xp2); xp3 = fmaf(rm.w, g, xp3);
            }
        }
    }
    __syncthreads();
    const float inv = 1.0f / 200.0f;
    if (mh == 0 && c < EMB) {
        xyz[c] = xp0 * inv; xyz[EMB + c] = xp1 * inv;
        xyz[2 * EMB + c] = xp2 * inv; xyz[3 * EMB + c] = xp3 * inv;
    }
    __syncthreads();
    if (mh == 1 && c < EMB) {
        xyz[c] += xp0 * inv; xyz[EMB + c] += xp1 * inv;
        xyz[2 * EMB + c] += xp2 * inv; xyz[3 * EMB + c] += xp3 * inv;
    }
    __syncthreads();
    float* Dld = smem;
    for (int idx = tid; idx < DDIM; idx += 256) {
        int cc = idx >> 4, d = idx & 15;
        Dld[idx] = xyz[cc] * xyz[d] + xyz[EMB + cc] * xyz[EMB + d]
                 + xyz[2 * EMB + cc] * xyz[2 * EMB + d] + xyz[3 * EMB + cc] * xyz[3 * EMB + d];
    }
    __syncthreads();
    float* hA = smem + DDIM; float* hB = hA + FITH; float* h2 = hB + FITH; float* red = h2 + FITH;
    if (tid < FITH) {
        const float* W = fW0 + (size_t)t * DDIM * FITH;
        float acc = fb0[t * FITH + tid];
        for (int f = 0; f < DDIM; f += 4) {
            float4 dv = *(const float4*)(Dld + f);
            acc = fmaf(dv.x, W[f * FITH + tid], acc); acc = fmaf(dv.y, W[(f + 1) * FITH + tid], acc);
            acc = fmaf(dv.z, W[(f + 2) * FITH + tid], acc); acc = fmaf(dv.w, W[(f + 3) * FITH + tid], acc);
        }
        hA[tid] = ftanh(acc);
    }
    __syncthreads();
    if (tid < FITH) {
        const float* W = fW1 + t * FITH * FITH;
        float acc = fb1[t * FITH + tid];
        for (int f = 0; f < FITH; f += 4) {
            float4 hv = *(const float4*)(hA + f);
            acc = fmaf(hv.x, W[f * FITH + tid], acc); acc = fmaf(hv.y, W[(f + 1) * FITH + tid], acc);
            acc = fmaf(hv.z, W[(f + 2) * FITH + tid], acc); acc = fmaf(hv.w, W[(f + 3) * FITH + tid], acc);
        }
        hB[tid] = hA[tid] + ftanh(acc);
    }
    __syncthreads();
    if (tid < FITH) {
        const float* W = fW2 + t * FITH * FITH;
        float acc = fb2[t * FITH + tid];
        for (int f = 0; f < FITH; f += 4) {
            float4 hv = *(const float4*)(hB + f);
            acc = fmaf(hv.x, W[f * FITH + tid], acc); acc = fmaf(hv.y, W[(f + 1) * FITH + tid], acc);
            acc = fmaf(hv.z, W[(f + 2) * FITH + tid], acc); acc = fmaf(hv.w, W[(f + 3) * FITH + tid], acc);
        }
        h2[tid] = hB[tid] + ftanh(acc);
    }
    __syncthreads();
    float p = (tid < FITH) ? h2[tid] * fW3[t * FITH + tid] : 0.0f;
#pragma unroll
    for (int off = 32; off > 0; off >>= 1) p += __shfl_down(p, off, 64);
    if ((tid & 63) == 0) red[tid >> 6] = p;
    __syncthreads();
    if (tid == 0) out[4 + atom] = red[0] + red[1] + red[2] + red[3] + fb3[t] + eshift[t];
}

extern "C" void kernel_launch(void* const* d_in, const int* in_sizes, int n_in,
                              void* d_out, int out_size, void* d_ws, size_t ws_size,
                              hipStream_t stream) {
    const int*   itype   = (const int*)  d_in[1];
    const float* imagedr = (const float*)d_in[3];
    const float* davg    = (const float*)d_in[5];
    const float* dstd    = (const float*)d_in[6];
    const float* eW0     = (const float*)d_in[7];
    const float* eb0     = (const float*)d_in[8];
    const float* eW1     = (const float*)d_in[9];
    const float* eb1     = (const float*)d_in[10];
    const float* eW2     = (const float*)d_in[11];
    const float* eb2     = (const float*)d_in[12];
    const float* fW0     = (const float*)d_in[13];
    const float* fb0     = (const float*)d_in[14];
    const float* fW1     = (const float*)d_in[15];
    const float* fb1     = (const float*)d_in[16];
    const float* fW2     = (const float*)d_in[17];
    const float* fb2     = (const float*)d_in[18];
    const float* fW3     = (const float*)d_in[19];
    const float* fb3     = (const float*)d_in[20];
    const float* eshift  = (const float*)d_in[21];
    float* out = (float*)d_out;
    float* ws  = (float*)d_ws;

    if (ws_size >= WS_NEED) {
        unsigned short* u0 = (unsigned short*)((char*)ws + USH_BYTE);
        int* wsi = (int*)ws;
        prep_kernel<<<WT_BLK + TB_BLK + 1, 256, 0, stream>>>(
            fW0, fW1, fW2, fb0, fb1, fb2, fW3, fb3, eshift,
            davg, dstd, eW0, eb0, eW1, eb1, eW2, eb2, itype, ws, out);
        embed_kernel<<<NATOMS, 256, 0, stream>>>(itype, imagedr, davg, dstd, ws);
        fit_kernel<<<dim3(128, 2), 512, 0, stream>>>(
            u0 + D_U, u0 + W0T_U, u0 + W1T_U, u0 + W2T_U,
            ws + BIAS_F, ws + W3C_F, wsi, out);
    } else {
        dp_atom_kernel<<<NATOMS, 256, 0, stream>>>(itype, imagedr, davg, dstd,
            eW0, eb0, eW1, eb1, eW2, eb2,
            fW0, fb0, fW1, fb1, fW2, fb2, fW3, fb3, eshift, out);
        etot_kernel<<<BSZ, 256, 0, stream>>>(out);
    }
}

// Round 8
// 167.262 us; speedup vs baseline: 2.3897x; 1.0069x over previous
//
#include <hip/hip_runtime.h>
#include <math.h>

#define NT 2
#define BSZ 4
#define NAT 512
#define NATOMS 2048
#define NNEI 200
#define EMB 100
#define FITH 240
#define DDIM 1600
#define TBK 1024

// ---- ws layout ----
// float region: [0..8) table ranges; [16..1552) concat biases; [1552..2064) w3c
// int   region: [2064..4128) perm (padded); [4128..4132) counts (c0,c1,c0p);
//               [4132..6180) inverse perm; [6180] fit done-counter
#define BIAS_F  16
#define W3C_F   (BIAS_F + 3 * 512)
#define PERM_I  2064
#define CNT_I   (PERM_I + 2064)
#define IPERM_I (CNT_I + 4)
#define DONE_I  (IPERM_I + 2048)
#define USH_BYTE 24832
// ushort region (fragment-packed operands):
#define TBL_U   0                          // 4*1024*100 = 409600
#define W0T_U   409600                     // [32 c16][50 kt][64 lane][8] = 819200
#define W1T_U   (W0T_U + 819200)           // [32][16][64][8] = 262144
#define W2T_U   (W1T_U + 262144)           // 262144
#define D_U     (W2T_U + 262144)           // [129 rb][50 kt][64][8]
#define D_SZ    (129 * 50 * 512)
#define USH_END (D_U + D_SZ)
#define WS_NEED ((size_t)USH_BYTE + (size_t)USH_END * 2)   // ~10.1 MB

#define N_W0 819200
#define N_W1 262144
#define N_W2 262144
#define N_B  1536
#define N_W3 512
#define N_EI 2048
#define N_WT (N_W0 + N_W1 + N_W2 + N_B + N_W3 + N_EI)
#define WT_BLK ((N_WT + 255) / 256)
#define TB_BLK 512

#define HPAD 264
#define FIT_NBLK 256

typedef short s8v __attribute__((ext_vector_type(8)));
typedef float f4v __attribute__((ext_vector_type(4)));

__device__ __forceinline__ float ftanh(float x) {
    float ax = fabsf(x);
    float e = __expf(2.0f * ax);
    float t = 1.0f - __fdividef(2.0f, e + 1.0f);
    return (x < 0.0f) ? -t : t;
}
__device__ __forceinline__ unsigned short f2bf(float f) {
    unsigned u = __float_as_uint(f);
    u += 0x7FFFu + ((u >> 16) & 1u);
    return (unsigned short)(u >> 16);
}
__device__ __forceinline__ float bf2f(unsigned short s) {
    return __uint_as_float(((unsigned)s) << 16);
}
__device__ __forceinline__ float calc_S(float R) {
    float Rsafe = (R > 1e-5f) ? R : 1.0f;
    float u = (R - 0.5f) * (1.0f / 5.5f);
    float uu = u * u;
    float mid = (u * uu * (-6.0f * uu + 15.0f * u - 10.0f) + 1.0f) / Rsafe;
    float S = 0.0f;
    if (R > 0.0f && R < 0.5f)      S = 1.0f / Rsafe;
    else if (R > 0.5f && R < 6.0f) S = mid;
    return S;
}

// ---------- K1: prep = wtrans (fragment-packed) + table build + type-perm ----------
__global__ void __launch_bounds__(256) prep_kernel(
    const float* __restrict__ fW0, const float* __restrict__ fW1,
    const float* __restrict__ fW2,
    const float* __restrict__ fb0, const float* __restrict__ fb1,
    const float* __restrict__ fb2,
    const float* __restrict__ fW3, const float* __restrict__ fb3,
    const float* __restrict__ eshift,
    const float* __restrict__ davg, const float* __restrict__ dstd,
    const float* __restrict__ eW0, const float* __restrict__ eb0,
    const float* __restrict__ eW1, const float* __restrict__ eb1,
    const float* __restrict__ eW2, const float* __restrict__ eb2,
    const int* __restrict__ itype,
    float* __restrict__ ws, float* __restrict__ out)
{
    __shared__ float los[100], his[100];
    __shared__ float rng[2];
    __shared__ float h0s[8][25];
    __shared__ float h1s[8][50];
    __shared__ int pcnt, poff0, poff1;
    const int tid = threadIdx.x;
    int bxg = blockIdx.x;
    unsigned short* u0 = (unsigned short*)((char*)ws + USH_BYTE);

    if (bxg < WT_BLK) {
        int id = bxg * 256 + tid;
        if (id < N_W0) {
            // fragment layout: id = ((c16*50 + kt)*64 + lane)*8 + e
            int e = id & 7, lane = (id >> 3) & 63;
            int rem = id >> 9;
            int kt = rem % 50, c16 = rem / 50;
            int n = c16 * 16 + (lane & 15);
            int k = kt * 32 + (lane >> 4) * 8 + e;
            float v = 0.0f;
            if (n < 240)                  v = fW0[(size_t)k * 240 + n];
            else if (n >= 256 && n < 496) v = fW0[(size_t)(1600 + k) * 240 + (n - 256)];
            u0[W0T_U + id] = f2bf(v);
            return;
        }
        id -= N_W0;
        if (id < N_W1) {
            int e = id & 7, lane = (id >> 3) & 63;
            int rem = id >> 9;
            int kt = rem & 15, c16 = rem >> 4;
            int n = c16 * 16 + (lane & 15);
            int k = kt * 32 + (lane >> 4) * 8 + e;
            float v = 0.0f;
            if (n < 240 && k < 240)       v = fW1[(size_t)k * 240 + n];
            else if (n >= 256 && n < 496 && k >= 256 && k < 496)
                                          v = fW1[(size_t)(240 + (k - 256)) * 240 + (n - 256)];
            u0[W1T_U + id] = f2bf(v);
            return;
        }
        id -= N_W1;
        if (id < N_W2) {
            int e = id & 7, lane = (id >> 3) & 63;
            int rem = id >> 9;
            int kt = rem & 15, c16 = rem >> 4;
            int n = c16 * 16 + (lane & 15);
            int k = kt * 32 + (lane >> 4) * 8 + e;
            float v = 0.0f;
            if (n < 240 && k < 240)       v = fW2[(size_t)k * 240 + n];
            else if (n >= 256 && n < 496 && k >= 256 && k < 496)
                                          v = fW2[(size_t)(240 + (k - 256)) * 240 + (n - 256)];
            u0[W2T_U + id] = f2bf(v);
            return;
        }
        id -= N_W2;
        if (id < N_B) {
            int l = id / 512, n = id - l * 512;
            const float* fb = (l == 0) ? fb0 : (l == 1) ? fb1 : fb2;
            float v = 0.0f;
            if (n < 240)                  v = fb[n];
            else if (n >= 256 && n < 496) v = fb[240 + (n - 256)];
            ws[BIAS_F + l * 512 + n] = v;
            return;
        }
        id -= N_B;
        if (id < N_W3) {
            int n = id;
            float v = 0.0f;
            if (n < 240)                  v = fW3[n];
            else if (n >= 256 && n < 496) v = fW3[240 + (n - 256)];
            ws[W3C_F + n] = v;
            return;
        }
        id -= N_W3;
        if (id < N_EI) {
            int t = itype[id & (NAT - 1)];
            out[4 + id] = fb3[t] + eshift[t];
        }
        return;
    }
    bxg -= WT_BLK;
    if (bxg < TB_BLK) {
        const int nid = bxg >> 7;
        const int kb  = (bxg & 127) * 8;
        const int t = nid >> 1, j = nid & 1;
        if (tid < 100) {
            int m = j * 100 + tid;
            float av = davg[(t * NNEI + m) * 4];
            float sd = dstd[(t * NNEI + m) * 4];
            float inv = __fdividef(1.0f, sd);
            float a = (0.0f - av) * inv;
            float b = (2.0f - av) * inv;
            los[tid] = fminf(a, b);
            his[tid] = fmaxf(a, b);
        }
        __syncthreads();
        if (tid == 0) {
            float lo = los[0], hi = his[0];
            for (int i = 1; i < 100; ++i) { lo = fminf(lo, los[i]); hi = fmaxf(hi, his[i]); }
            rng[0] = lo; rng[1] = hi - lo;
            if (kb == 0) {
                ws[nid * 2] = lo;
                ws[nid * 2 + 1] = (float)(TBK - 1) / (hi - lo);
            }
        }
        __syncthreads();
        const float smin = rng[0], span = rng[1];
        const float* W0 = eW0 + nid * 25;
        const float* B0 = eb0 + nid * 25;
        if (tid < 200) {
            int q = tid / 25, a = tid % 25;
            float s = smin + span * ((float)(kb + q) * (1.0f / (TBK - 1)));
            h0s[q][a] = ftanh(fmaf(s, W0[a], B0[a]));
        }
        __syncthreads();
        const float* W1 = eW1 + nid * 1250;
        const float* B1 = eb1 + nid * 50;
        for (int idx = tid; idx < 400; idx += 256) {
            int q = idx / 50, cc = idx % 50;
            float acc = B1[cc];
#pragma unroll
            for (int a = 0; a < 25; ++a) acc = fmaf(h0s[q][a], W1[a * 50 + cc], acc);
            h1s[q][cc] = ftanh(acc) + h0s[q][(cc < 25) ? cc : cc - 25];
        }
        __syncthreads();
        const float* W2 = eW2 + nid * 5000;
        const float* B2 = eb2 + nid * 100;
        unsigned short* tblu = u0 + TBL_U;
        for (int idx = tid; idx < 800; idx += 256) {
            int q = idx / 100, c = idx % 100;
            float acc = B2[c];
#pragma unroll
            for (int a = 0; a < 50; ++a) acc = fmaf(h1s[q][a], W2[a * 100 + c], acc);
            float g = ftanh(acc) + h1s[q][(c < 50) ? c : c - 50];
            tblu[(size_t)(nid * TBK + kb + q) * 100 + c] = f2bf(g);
        }
        return;
    }
    // ---- type partition perm (padded: type-1 starts at 16-aligned c0p) ----
    if (tid == 0) { pcnt = 0; poff0 = 0; poff1 = 0; }
    __syncthreads();
    int* wsi = (int*)ws;
    int local0 = 0;
    for (int i = tid; i < NATOMS; i += 256) local0 += (itype[i & (NAT - 1)] == 0);
    atomicAdd(&pcnt, local0);
    __syncthreads();
    const int c0 = pcnt;
    const int c0p = (c0 + 15) & ~15;
    for (int i = tid; i < NATOMS; i += 256) {
        int t = itype[i & (NAT - 1)];
        int pos = (t == 0) ? atomicAdd(&poff0, 1) : (c0p + atomicAdd(&poff1, 1));
        wsi[PERM_I + pos] = i;
        wsi[IPERM_I + i] = pos;
    }
    if (tid == 0) {
        wsi[CNT_I] = c0; wsi[CNT_I + 1] = NATOMS - c0; wsi[CNT_I + 2] = c0p;
        wsi[DONE_I] = 0;
    }
}

// ---------- K2: embed -> D bf16, fragment-packed ----------
// 512 threads = 8 waves: (table-half w, mi-segment seg of 25). Each active
// lane (l<50) reads a uint = 2 bf16 cols per table row -> gather transactions
// halved vs per-col ushort reads; per-column math order unchanged.
__global__ void __launch_bounds__(512) embed_kernel(
    const int* __restrict__ itype, const float* __restrict__ imagedr,
    const float* __restrict__ davg, const float* __restrict__ dstd,
    float* __restrict__ ws)
{
    __shared__ __align__(16) float4 srn[NNEI];
    __shared__ float sx[NNEI];
    __shared__ float part[8][400];
    const int atom = blockIdx.x;
    const int n = atom & (NAT - 1);
    const int tid = threadIdx.x;
    const int t = itype[n];
    unsigned short* u0 = (unsigned short*)((char*)ws + USH_BYTE);
    const int* wsi = (const int*)ws;

    const float sm0 = ws[(t * 2 + 0) * 2], sc0 = ws[(t * 2 + 0) * 2 + 1];
    const float sm1 = ws[(t * 2 + 1) * 2], sc1 = ws[(t * 2 + 1) * 2 + 1];

    for (int m = tid; m < NNEI; m += 512) {
        float4 dr = ((const float4*)imagedr)[(size_t)atom * NNEI + m];
        float R = dr.x;
        float S = calc_S(R);
        float Rsafe = (R > 1e-5f) ? R : 1.0f;
        float sr = (fabsf(R) > 1e-5f) ? (S / Rsafe) : 0.0f;
        float4 av = ((const float4*)davg)[t * NNEI + m];
        float4 sd = ((const float4*)dstd)[t * NNEI + m];
        float4 rv;
        rv.x = (S         - av.x) / sd.x;
        rv.y = (sr * dr.y - av.y) / sd.y;
        rv.z = (sr * dr.z - av.z) / sd.z;
        rv.w = (sr * dr.w - av.w) / sd.w;
        srn[m] = rv;
        float smin = (m >= 100) ? sm1 : sm0;
        float scal = (m >= 100) ? sc1 : sc0;
        sx[m] = fminf(fmaxf((rv.x - smin) * scal, 0.0f), (float)(TBK - 2) + 0.9999f);
    }
    __syncthreads();

    const int v = tid >> 6, lane = tid & 63;
    const int w = v >> 2;                 // neighbor half (table id)
    const int seg = v & 3;                // mi segment of 25 (quarters the chain)
    const unsigned short* T = u0 + TBL_U + (size_t)(t * 2 + w) * TBK * EMB;
    const bool act = (lane < 50);         // lane covers cols 2*lane, 2*lane+1
    float xE0 = 0, xE1 = 0, xE2 = 0, xE3 = 0;   // even col
    float xO0 = 0, xO1 = 0, xO2 = 0, xO3 = 0;   // odd col
#pragma unroll 5
    for (int mi = seg * 25; mi < seg * 25 + 25; ++mi) {
        int m = w * 100 + mi;
        float4 rv = srn[m];
        float x = sx[m];
        int i = (int)x;
        float f = x - (float)i;
        const unsigned short* Tr = T + (size_t)i * EMB;
        unsigned r0 = act ? *(const unsigned*)(Tr + 2 * lane) : 0u;
        unsigned r1 = act ? *(const unsigned*)(Tr + EMB + 2 * lane) : 0u;
        float g0e = bf2f((unsigned short)(r0 & 0xFFFFu));
        float g0o = bf2f((unsigned short)(r0 >> 16));
        float g1e = bf2f((unsigned short)(r1 & 0xFFFFu));
        float g1o = bf2f((unsigned short)(r1 >> 16));
        float ge = fmaf(f, g1e - g0e, g0e);
        float go = fmaf(f, g1o - g0o, g0o);
        xE0 = fmaf(rv.x, ge, xE0); xE1 = fmaf(rv.y, ge, xE1);
        xE2 = fmaf(rv.z, ge, xE2); xE3 = fmaf(rv.w, ge, xE3);
        xO0 = fmaf(rv.x, go, xO0); xO1 = fmaf(rv.y, go, xO1);
        xO2 = fmaf(rv.z, go, xO2); xO3 = fmaf(rv.w, go, xO3);
    }
    if (act) {
        const int c = 2 * lane;
        part[v][0 * 100 + c] = xE0; part[v][0 * 100 + c + 1] = xO0;
        part[v][1 * 100 + c] = xE1; part[v][1 * 100 + c + 1] = xO1;
        part[v][2 * 100 + c] = xE2; part[v][2 * 100 + c + 1] = xO2;
        part[v][3 * 100 + c] = xE3; part[v][3 * 100 + c + 1] = xO3;
    }
    __syncthreads();
    const float inv = 1.0f / 200.0f;
    for (int idx = tid; idx < 400; idx += 512) {
        float s = 0.0f;
#pragma unroll
        for (int pv = 0; pv < 8; ++pv) s += part[pv][idx];
        part[0][idx] = s * inv;
    }
    __syncthreads();
    // D row -> fragment-packed position p = iperm[atom]
    const int p = wsi[IPERM_I + atom];
    const int rb = p >> 4, mrp = p & 15;
    unsigned short* Df = u0 + D_U;
    const float* xt = part[0];
    for (int k8 = tid; k8 < 200; k8 += 512) {
        int k = k8 * 8;
        int c = k >> 4, d0 = k & 15;
        int kt = k >> 5, q = (k >> 3) & 3;
        s8v pack;
#pragma unroll
        for (int e = 0; e < 8; ++e) {
            int d = d0 + e;
            float s = xt[c] * xt[d] + xt[100 + c] * xt[100 + d]
                    + xt[200 + c] * xt[200 + d] + xt[300 + c] * xt[300 + d];
            ((unsigned short*)&pack)[e] = f2bf(s);
        }
        *(s8v*)(Df + ((size_t)(rb * 50 + kt) * 64 + q * 16 + mrp) * 8) = pack;
    }
}

// ---------- K3: fused fitting net + Etot (last-block reduction) ----------
// launch_bounds(512,2): 256-VGPR budget so the compiler can pipeline the
// fully-unrolled coalesced K-loop.
__global__ void __launch_bounds__(512, 2) fit_kernel(
    const unsigned short* __restrict__ Af,    // D frag  [129][50][64][8]
    const unsigned short* __restrict__ W0F,   // [32][50][64][8]
    const unsigned short* __restrict__ W1F,   // [32][16][64][8]
    const unsigned short* __restrict__ W2F,   // [32][16][64][8]
    const float* __restrict__ biases,         // [3][512]
    const float* __restrict__ w3c,            // [512]
    int* __restrict__ wsi,
    float* __restrict__ out)
{
    __shared__ float lred[4][64][17];
    __shared__ unsigned short Hs0[16 * HPAD];
    __shared__ unsigned short Hs1[16 * HPAD];
    __shared__ float red2[16][4];
    __shared__ int lastFlag;
    __shared__ float er[8];

    const int z = blockIdx.y;
    const int cnt = wsi[CNT_I + z];
    const int my = blockIdx.x;
    const int tid = threadIdx.x;
    const bool work = (my * 16 < cnt);
    if (work) {
        const int basep = z ? wsi[CNT_I + 2] : 0;
        const int w = tid >> 6, lane = tid & 63;
        const int mr = lane & 15, q = lane >> 4;
        const int wc = w & 3, h = w >> 2;
        const int n0 = z * 256 + wc * 64;
        const int m0 = my * 16;
        const int rb = (basep >> 4) + my;
        const int c16b = z * 16 + wc * 4;

        // ================= layer 0: K=1600, 2-way k-split =================
        f4v a0 = {0,0,0,0}, a1 = {0,0,0,0}, a2 = {0,0,0,0}, a3 = {0,0,0,0};
        {
            const unsigned short* Ap = Af  + ((size_t)(rb * 50 + h * 25) * 64 + lane) * 8;
            const unsigned short* Bp = W0F + ((size_t)(c16b * 50 + h * 25) * 64 + lane) * 8;
#pragma unroll
            for (int kt = 0; kt < 25; ++kt) {
                s8v av = *(const s8v*)(Ap + kt * 512);
                s8v b0 = *(const s8v*)(Bp + kt * 512);
                s8v b1 = *(const s8v*)(Bp + 25600 + kt * 512);
                s8v b2 = *(const s8v*)(Bp + 51200 + kt * 512);
                s8v b3 = *(const s8v*)(Bp + 76800 + kt * 512);
                a0 = __builtin_amdgcn_mfma_f32_16x16x32_bf16(av, b0, a0, 0, 0, 0);
                a1 = __builtin_amdgcn_mfma_f32_16x16x32_bf16(av, b1, a1, 0, 0, 0);
                a2 = __builtin_amdgcn_mfma_f32_16x16x32_bf16(av, b2, a2, 0, 0, 0);
                a3 = __builtin_amdgcn_mfma_f32_16x16x32_bf16(av, b3, a3, 0, 0, 0);
            }
        }
        if (h == 1) {
#pragma unroll
            for (int r = 0; r < 4; ++r) {
                lred[wc][lane][r]      = a0[r];
                lred[wc][lane][4 + r]  = a1[r];
                lred[wc][lane][8 + r]  = a2[r];
                lred[wc][lane][12 + r] = a3[r];
            }
        }
        __syncthreads();
        if (h == 0) {
#pragma unroll
            for (int j = 0; j < 4; ++j) {
                const float bv = biases[n0 + j * 16 + mr];
                f4v* ap = (j == 0) ? &a0 : (j == 1) ? &a1 : (j == 2) ? &a2 : &a3;
                const int col = wc * 64 + j * 16 + mr;
#pragma unroll
                for (int r = 0; r < 4; ++r) {
                    float s = (*ap)[r] + lred[wc][lane][j * 4 + r] + bv;
                    int row = q * 4 + r;
                    Hs0[row * HPAD + col] = f2bf(ftanh(s));
                }
            }
        }
        __syncthreads();

        // ================= layer 1: K=256, residual =================
        {
            const unsigned short* Bp = W1F + ((size_t)(c16b * 16 + z * 8 + h * 4) * 64 + lane) * 8;
            f4v ac[4] = {{0,0,0,0},{0,0,0,0},{0,0,0,0},{0,0,0,0}};
#pragma unroll
            for (int kt = 0; kt < 4; ++kt) {
                s8v av = *(const s8v*)((const char*)Hs0
                         + (size_t)mr * (HPAD * 2) + h * 256 + q * 16 + kt * 64);
                s8v b0 = *(const s8v*)(Bp + kt * 512);
                s8v b1 = *(const s8v*)(Bp + 8192 + kt * 512);
                s8v b2 = *(const s8v*)(Bp + 16384 + kt * 512);
                s8v b3 = *(const s8v*)(Bp + 24576 + kt * 512);
                ac[0] = __builtin_amdgcn_mfma_f32_16x16x32_bf16(av, b0, ac[0], 0, 0, 0);
                ac[1] = __builtin_amdgcn_mfma_f32_16x16x32_bf16(av, b1, ac[1], 0, 0, 0);
                ac[2] = __builtin_amdgcn_mfma_f32_16x16x32_bf16(av, b2, ac[2], 0, 0, 0);
                ac[3] = __builtin_amdgcn_mfma_f32_16x16x32_bf16(av, b3, ac[3], 0, 0, 0);
            }
            if (h == 1) {
#pragma unroll
                for (int j = 0; j < 4; ++j)
#pragma unroll
                    for (int r = 0; r < 4; ++r) lred[wc][lane][j * 4 + r] = ac[j][r];
            }
            __syncthreads();
            if (h == 0) {
#pragma unroll
                for (int j = 0; j < 4; ++j) {
                    const float bv = biases[512 + n0 + j * 16 + mr];
                    const int col = wc * 64 + j * 16 + mr;
#pragma unroll
                    for (int r = 0; r < 4; ++r) {
                        float s = ac[j][r] + lred[wc][lane][j * 4 + r] + bv;
                        int row = q * 4 + r;
                        float hv = bf2f(Hs0[row * HPAD + col]) + ftanh(s);
                        Hs1[row * HPAD + col] = f2bf(hv);
                    }
                }
            }
            __syncthreads();
        }

        // ================= layer 2 + w3 dot =================
        {
            const unsigned short* Bp = W2F + ((size_t)(c16b * 16 + z * 8 + h * 4) * 64 + lane) * 8;
            f4v ac[4] = {{0,0,0,0},{0,0,0,0},{0,0,0,0},{0,0,0,0}};
#pragma unroll
            for (int kt = 0; kt < 4; ++kt) {
                s8v av = *(const s8v*)((const char*)Hs1
                         + (size_t)mr * (HPAD * 2) + h * 256 + q * 16 + kt * 64);
                s8v b0 = *(const s8v*)(Bp + kt * 512);
                s8v b1 = *(const s8v*)(Bp + 8192 + kt * 512);
                s8v b2 = *(const s8v*)(Bp + 16384 + kt * 512);
                s8v b3 = *(const s8v*)(Bp + 24576 + kt * 512);
                ac[0] = __builtin_amdgcn_mfma_f32_16x16x32_bf16(av, b0, ac[0], 0, 0, 0);
                ac[1] = __builtin_amdgcn_mfma_f32_16x16x32_bf16(av, b1, ac[1], 0, 0, 0);
                ac[2] = __builtin_amdgcn_mfma_f32_16x16x32_bf16(av, b2, ac[2], 0, 0, 0);
                ac[3] = __builtin_amdgcn_mfma_f32_16x16x32_bf16(av, b3, ac[3], 0, 0, 0);
            }
            if (h == 1) {
#pragma unroll
                for (int j = 0; j < 4; ++j)
#pragma unroll
                    for (int r = 0; r < 4; ++r) lred[wc][lane][j * 4 + r] = ac[j][r];
            }
            __syncthreads();
            if (h == 0) {
                float pr[4] = {0, 0, 0, 0};
#pragma unroll
                for (int j = 0; j < 4; ++j) {
                    const int col = n0 + j * 16 + mr;
                    const float bv = biases[1024 + col];
                    const float wv = w3c[col];
                    const int coll = wc * 64 + j * 16 + mr;
#pragma unroll
                    for (int r = 0; r < 4; ++r) {
                        float s = ac[j][r] + lred[wc][lane][j * 4 + r] + bv;
                        int row = q * 4 + r;
                        float hv = bf2f(Hs1[row * HPAD + coll]) + ftanh(s);
                        pr[r] = fmaf(hv, wv, pr[r]);
                    }
                }
#pragma unroll
                for (int r = 0; r < 4; ++r) {
                    float p = pr[r];
                    p += __shfl_xor(p, 1, 16);
                    p += __shfl_xor(p, 2, 16);
                    p += __shfl_xor(p, 4, 16);
                    p += __shfl_xor(p, 8, 16);
                    if (mr == 0) red2[q * 4 + r][wc] = p;
                }
            }
            __syncthreads();
            if (tid < 16 && m0 + tid < cnt) {
                const int orow = wsi[PERM_I + basep + m0 + tid];
                out[4 + orow] += red2[tid][0] + red2[tid][1] + red2[tid][2] + red2[tid][3];
            }
        }
    }

    // ---------- fused Etot: last finished block reduces ----------
    __syncthreads();
    if (tid == 0) {
        __threadfence();
        int prev = atomicAdd(&wsi[DONE_I], 1);
        lastFlag = (prev == FIT_NBLK - 1);
    }
    __syncthreads();
    if (lastFlag) {
        __threadfence();
        const int g = tid >> 7, l = tid & 127;
        float s = 0.0f;
        for (int nn = l; nn < NAT; nn += 128) s += out[4 + g * NAT + nn];
#pragma unroll
        for (int off = 32; off > 0; off >>= 1) s += __shfl_down(s, off, 64);
        if ((l & 63) == 0) er[g * 2 + (l >> 6)] = s;
        __syncthreads();
        if (tid < 4) out[tid] = er[tid * 2] + er[tid * 2 + 1];
    }
}

// ---------- etot (fallback path only) ----------
__global__ void etot_kernel(float* __restrict__ out) {
    const int b = blockIdx.x;
    float s = 0.0f;
    for (int n = threadIdx.x; n < NAT; n += 256) s += out[4 + b * NAT + n];
#pragma unroll
    for (int off = 32; off > 0; off >>= 1) s += __shfl_down(s, off, 64);
    __shared__ float rr[4];
    if ((threadIdx.x & 63) == 0) rr[threadIdx.x >> 6] = s;
    __syncthreads();
    if (threadIdx.x == 0) out[b] = rr[0] + rr[1] + rr[2] + rr[3];
}

// ================= fallback (small ws): monolithic per-atom =================
__global__ void dp_atom_kernel(
    const int* __restrict__ itype, const float* __restrict__ imagedr,
    const float* __restrict__ davg, const float* __restrict__ dstd,
    const float* __restrict__ eW0, const float* __restrict__ eb0,
    const float* __restrict__ eW1, const float* __restrict__ eb1,
    const float* __restrict__ eW2, const float* __restrict__ eb2,
    const float* __restrict__ fW0, const float* __restrict__ fb0,
    const float* __restrict__ fW1, const float* __restrict__ fb1,
    const float* __restrict__ fW2, const float* __restrict__ fb2,
    const float* __restrict__ fW3, const float* __restrict__ fb3,
    const float* __restrict__ eshift, float* __restrict__ out)
{
    __shared__ __align__(16) float4 rn4[NNEI];
    __shared__ __align__(16) float  xyz[4 * EMB];
    __shared__ __align__(16) float  h0s[100 * 25];
    __shared__ __align__(16) float  smem[100 * 52];
    const int atom = blockIdx.x;
    const int n = atom & (NAT - 1);
    const int tid = threadIdx.x;
    const int t = itype[n];
    for (int m = tid; m < NNEI; m += 256) {
        float4 dr = ((const float4*)imagedr)[(size_t)atom * NNEI + m];
        float R = dr.x;
        float S = calc_S(R);
        float Rsafe = (R > 1e-5f) ? R : 1.0f;
        float sr = (fabsf(R) > 1e-5f) ? (S / Rsafe) : 0.0f;
        float4 av = ((const float4*)davg)[t * NNEI + m];
        float4 sd = ((const float4*)dstd)[t * NNEI + m];
        float4 rv;
        rv.x = (S - av.x) / sd.x; rv.y = (sr * dr.y - av.y) / sd.y;
        rv.z = (sr * dr.z - av.z) / sd.z; rv.w = (sr * dr.w - av.w) / sd.w;
        rn4[m] = rv;
    }
    const int c = tid & 127; const int mh = tid >> 7;
    float xp0 = 0, xp1 = 0, xp2 = 0, xp3 = 0;
    for (int j = 0; j < NT; ++j) {
        const int wb = t * NT + j;
        const float* W0 = eW0 + wb * 25; const float* B0 = eb0 + wb * 25;
        const float* W1 = eW1 + wb * 1250; const float* B1 = eb1 + wb * 50;
        const float* W2 = eW2 + wb * 5000; const float* B2 = eb2 + wb * 100;
        __syncthreads();
        for (int idx = tid; idx < 2500; idx += 256) {
            int m = idx / 25, a = idx - m * 25;
            h0s[idx] = ftanh(fmaf(rn4[j * 100 + m].x, W0[a], B0[a]));
        }
        __syncthreads();
        for (int idx = tid; idx < 5000; idx += 256) {
            int m = idx / 50, cc = idx - m * 50;
            const float* h0m = h0s + m * 25;
            float acc = B1[cc];
#pragma unroll
            for (int a = 0; a < 25; ++a) acc = fmaf(h0m[a], W1[a * 50 + cc], acc);
            smem[m * 52 + cc] = ftanh(acc) + h0m[(cc < 25) ? cc : cc - 25];
        }
        for (int idx = tid; idx < 200; idx += 256)
            smem[(idx >> 1) * 52 + 50 + (idx & 1)] = 0.0f;
        __syncthreads();
        if (c < EMB) {
            float w2c[52];
#pragma unroll
            for (int a = 0; a < 50; ++a) w2c[a] = W2[a * EMB + c];
            w2c[50] = 0; w2c[51] = 0;
            const float bc = B2[c];
            const int sk = (c < 50) ? c : c - 50;
            for (int i = 0; i < 50; ++i) {
                int m = mh * 50 + i;
                const float* h1m = smem + m * 52;
                float acc = bc;
#pragma unroll
                for (int q = 0; q < 13; ++q) {
                    float4 hv = ((const float4*)h1m)[q];
                    acc = fmaf(hv.x, w2c[4 * q], acc); acc = fmaf(hv.y, w2c[4 * q + 1], acc);
                    acc = fmaf(hv.z, w2c[4 * q + 2], acc); acc = fmaf(hv.w, w2c[4 * q + 3], acc);
                }
                float g = ftanh(acc) + h1m[sk];
                float4 rm = rn4[j * 100 + m];
                xp0 = fmaf(rm.x, g, xp0); xp1 = fmaf(rm.y, g, xp1);
                xp2 = fmaf(rm.z, g, xp2); xp3 = fmaf(rm.w, g, xp3);
            }
        }
    }
    __syncthreads();
    const float inv = 1.0f / 200.0f;
    if (mh == 0 && c < EMB) {
        xyz[c] = xp0 * inv; xyz[EMB + c] = xp1 * inv;
        xyz[2 * EMB + c] = xp2 * inv; xyz[3 * EMB + c] = xp3 * inv;
    }
    __syncthreads();
    if (mh == 1 && c < EMB) {
        xyz[c] += xp0 * inv; xyz[EMB + c] += xp1 * inv;
        xyz[2 * EMB + c] += xp2 * inv; xyz[3 * EMB + c] += xp3 * inv;
    }
    __syncthreads();
    float* Dld = smem;
    for (int idx = tid; idx < DDIM; idx += 256) {
        int cc = idx >> 4, d = idx & 15;
        Dld[idx] = xyz[cc] * xyz[d] + xyz[EMB + cc] * xyz[EMB + d]
                 + xyz[2 * EMB + cc] * xyz[2 * EMB + d] + xyz[3 * EMB + cc] * xyz[3 * EMB + d];
    }
    __syncthreads();
    float* hA = smem + DDIM; float* hB = hA + FITH; float* h2 = hB + FITH; float* red = h2 + FITH;
    if (tid < FITH) {
        const float* W = fW0 + (size_t)t * DDIM * FITH;
        float acc = fb0[t * FITH + tid];
        for (int f = 0; f < DDIM; f += 4) {
            float4 dv = *(const float4*)(Dld + f);
            acc = fmaf(dv.x, W[f * FITH + tid], acc); acc = fmaf(dv.y, W[(f + 1) * FITH + tid], acc);
            acc = fmaf(dv.z, W[(f + 2) * FITH + tid], acc); acc = fmaf(dv.w, W[(f + 3) * FITH + tid], acc);
        }
        hA[tid] = ftanh(acc);
    }
    __syncthreads();
    if (tid < FITH) {
        const float* W = fW1 + t * FITH * FITH;
        float acc = fb1[t * FITH + tid];
        for (int f = 0; f < FITH; f += 4) {
            float4 hv = *(const float4*)(hA + f);
            acc = fmaf(hv.x, W[f * FITH + tid], acc); acc = fmaf(hv.y, W[(f + 1) * FITH + tid], acc);
            acc = fmaf(hv.z, W[(f + 2) * FITH + tid], acc); acc = fmaf(hv.w, W[(f + 3) * FITH + tid], acc);
        }
        hB[tid] = hA[tid] + ftanh(acc);
    }
    __syncthreads();
    if (tid < FITH) {
        const float* W = fW2 + t * FITH * FITH;
        float acc = fb2[t * FITH + tid];
        for (int f = 0; f < FITH; f += 4) {
            float4 hv = *(const float4*)(hB + f);
            acc = fmaf(hv.x, W[f * FITH + tid], acc); acc = fmaf(hv.y, W[(f + 1) * FITH + tid], acc);
            acc = fmaf(hv.z, W[(f + 2) * FITH + tid], acc); acc = fmaf(hv.w, W[(f + 3) * FITH + tid], acc);
        }
        h2[tid] = hB[tid] + ftanh(acc);
    }
    __syncthreads();
    float p = (tid < FITH) ? h2[tid] * fW3[t * FITH + tid] : 0.0f;
#pragma unroll
    for (int off = 32; off > 0; off >>= 1) p += __shfl_down(p, off, 64);
    if ((tid & 63) == 0) red[tid >> 6] = p;
    __syncthreads();
    if (tid == 0) out[4 + atom] = red[0] + red[1] + red[2] + red[3] + fb3[t] + eshift[t];
}

extern "C" void kernel_launch(void* const* d_in, const int* in_sizes, int n_in,
                              void* d_out, int out_size, void* d_ws, size_t ws_size,
                              hipStream_t stream) {
    const int*   itype   = (const int*)  d_in[1];
    const float* imagedr = (const float*)d_in[3];
    const float* davg    = (const float*)d_in[5];
    const float* dstd    = (const float*)d_in[6];
    const float* eW0     = (const float*)d_in[7];
    const float* eb0     = (const float*)d_in[8];
    const float* eW1     = (const float*)d_in[9];
    const float* eb1     = (const float*)d_in[10];
    const float* eW2     = (const float*)d_in[11];
    const float* eb2     = (const float*)d_in[12];
    const float* fW0     = (const float*)d_in[13];
    const float* fb0     = (const float*)d_in[14];
    const float* fW1     = (const float*)d_in[15];
    const float* fb1     = (const float*)d_in[16];
    const float* fW2     = (const float*)d_in[17];
    const float* fb2     = (const float*)d_in[18];
    const float* fW3     = (const float*)d_in[19];
    const float* fb3     = (const float*)d_in[20];
    const float* eshift  = (const float*)d_in[21];
    float* out = (float*)d_out;
    float* ws  = (float*)d_ws;

    if (ws_size >= WS_NEED) {
        unsigned short* u0 = (unsigned short*)((char*)ws + USH_BYTE);
        int* wsi = (int*)ws;
        prep_kernel<<<WT_BLK + TB_BLK + 1, 256, 0, stream>>>(
            fW0, fW1, fW2, fb0, fb1, fb2, fW3, fb3, eshift,
            davg, dstd, eW0, eb0, eW1, eb1, eW2, eb2, itype, ws, out);
        embed_kernel<<<NATOMS, 512, 0, stream>>>(itype, imagedr, davg, dstd, ws);
        fit_kernel<<<dim3(128, 2), 512, 0, stream>>>(
            u0 + D_U, u0 + W0T_U, u0 + W1T_U, u0 + W2T_U,
            ws + BIAS_F, ws + W3C_F, wsi, out);
    } else {
        dp_atom_kernel<<<NATOMS, 256, 0, stream>>>(itype, imagedr, davg, dstd,
            eW0, eb0, eW1, eb1, eW2, eb2,
            fW0, fb0, fW1, fb1, fW2, fb2, fW3, fb3, eshift, out);
        etot_kernel<<<BSZ, 256, 0, stream>>>(out);
    }
}